// Round 11
// baseline (1001.278 us; speedup 1.0000x reference)
//
#include <hip/hip_runtime.h>

#define S_LEN 2048
#define DMODEL 2048
#define NH 16
#define NKV 4
#define HD 128
#define NE 8
#define FF 2048
#define QKV_N 3072   // (H + 2*KV) * HD

typedef __attribute__((ext_vector_type(8))) short short8;
typedef __attribute__((ext_vector_type(4))) float f32x4;

__device__ inline unsigned short f2bf(float f) {
  unsigned int u = __builtin_bit_cast(unsigned int, f);
  u += 0x7fffu + ((u >> 16) & 1u);
  return (unsigned short)(u >> 16);
}
__device__ inline float bf2f(unsigned short h) {
  unsigned int u = ((unsigned int)h) << 16;
  return __builtin_bit_cast(float, u);
}
__device__ inline void split2(float v, unsigned short& h, unsigned short& l) {
  h = f2bf(v);
  l = f2bf(v - bf2f(h));
}

// ======== chunk format (verified r3-r10): 8KB = 128 rows x 32 k bf16 ========
// element (row, k=8q+j) at ushort off row*32 + ((q ^ s(row))<<3) + j, s=(row^(row>>2))&3

__device__ inline void gload16(const void* g, void* l) {
  __builtin_amdgcn_global_load_lds((const __attribute__((address_space(1))) unsigned int*)g,
                                   (__attribute__((address_space(3))) unsigned int*)l,
                                   16, 0, 0);
}
__device__ inline void stageB_chunk(const unsigned short* __restrict__ chunk,
                                    unsigned short* __restrict__ lds) {
  int w = threadIdx.x >> 6, l = threadIdx.x & 63;
  const unsigned short* s = chunk + w * 1024 + l * 8;
  unsigned short* d = lds + w * 1024;
  gload16(s, d);
  gload16(s + 512, d + 512);
}

#define WVM0  asm volatile("s_waitcnt vmcnt(0)" ::: "memory")
#define WVM4  asm volatile("s_waitcnt vmcnt(4)" ::: "memory")
#define WVM6  asm volatile("s_waitcnt vmcnt(6)" ::: "memory")
#define WVM8  asm volatile("s_waitcnt vmcnt(8)" ::: "memory")
#define WAIT_ALL  asm volatile("s_waitcnt vmcnt(0) lgkmcnt(0)" ::: "memory")
#define WAIT_LDS  asm volatile("s_waitcnt lgkmcnt(0)" ::: "memory")
#define SCHEDBAR  __builtin_amdgcn_sched_barrier(0)
#define BAR       __builtin_amdgcn_s_barrier()

// ---------------- MFMA cores (256-thread GEMMs) ----------------

__device__ inline void mma16(const unsigned short* As, const unsigned short* Bs,
                             int wr, int wc, f32x4 acc[4][4]) {
  int l = threadIdx.x & 63;
  int lr = l & 15, lg = l >> 4;
  int qoff = ((lg ^ ((lr ^ (lr >> 2)) & 3)) << 3);
  short8 a[4], b[4];
#pragma unroll
  for (int m = 0; m < 4; m++)
    a[m] = *(const short8*)(As + (wr + m * 16 + lr) * 32 + qoff);
#pragma unroll
  for (int n = 0; n < 4; n++)
    b[n] = *(const short8*)(Bs + (wc + n * 16 + lr) * 32 + qoff);
#pragma unroll
  for (int m = 0; m < 4; m++)
#pragma unroll
    for (int n = 0; n < 4; n++)
      acc[m][n] = __builtin_amdgcn_mfma_f32_16x16x32_bf16(a[m], b[n], acc[m][n], 0, 0, 0);
}

__device__ inline void mma16_dualB(const unsigned short* As, const unsigned short* Bs1,
                                   const unsigned short* Bs2, int wr, int wc,
                                   f32x4 acc1[4][4], f32x4 acc2[4][4]) {
  int l = threadIdx.x & 63;
  int lr = l & 15, lg = l >> 4;
  int qoff = ((lg ^ ((lr ^ (lr >> 2)) & 3)) << 3);
  short8 a[4], b1[4], b2[4];
#pragma unroll
  for (int m = 0; m < 4; m++)
    a[m] = *(const short8*)(As + (wr + m * 16 + lr) * 32 + qoff);
#pragma unroll
  for (int n = 0; n < 4; n++) {
    b1[n] = *(const short8*)(Bs1 + (wc + n * 16 + lr) * 32 + qoff);
    b2[n] = *(const short8*)(Bs2 + (wc + n * 16 + lr) * 32 + qoff);
  }
#pragma unroll
  for (int m = 0; m < 4; m++)
#pragma unroll
    for (int n = 0; n < 4; n++) {
      acc1[m][n] = __builtin_amdgcn_mfma_f32_16x16x32_bf16(a[m], b1[n], acc1[m][n], 0, 0, 0);
      acc2[m][n] = __builtin_amdgcn_mfma_f32_16x16x32_bf16(a[m], b2[n], acc2[m][n], 0, 0, 0);
    }
}

__device__ inline void mma16_split_reg(const unsigned short* Ash, const unsigned short* Asl,
                                       const unsigned short* Bsh, const unsigned short* Bsl,
                                       int wr, int wc, f32x4 acc[4][4]) {
  int l = threadIdx.x & 63;
  int lr = l & 15, lg = l >> 4;
  int qoff = ((lg ^ ((lr ^ (lr >> 2)) & 3)) << 3);
  short8 ah[4], al[4], bh[4], bl[4];
#pragma unroll
  for (int m = 0; m < 4; m++) {
    ah[m] = *(const short8*)(Ash + (wr + m * 16 + lr) * 32 + qoff);
    al[m] = *(const short8*)(Asl + (wr + m * 16 + lr) * 32 + qoff);
  }
#pragma unroll
  for (int n = 0; n < 4; n++) {
    bh[n] = *(const short8*)(Bsh + (wc + n * 16 + lr) * 32 + qoff);
    bl[n] = *(const short8*)(Bsl + (wc + n * 16 + lr) * 32 + qoff);
  }
#pragma unroll
  for (int m = 0; m < 4; m++)
#pragma unroll
    for (int n = 0; n < 4; n++) {
      acc[m][n] = __builtin_amdgcn_mfma_f32_16x16x32_bf16(ah[m], bh[n], acc[m][n], 0, 0, 0);
      acc[m][n] = __builtin_amdgcn_mfma_f32_16x16x32_bf16(ah[m], bl[n], acc[m][n], 0, 0, 0);
      acc[m][n] = __builtin_amdgcn_mfma_f32_16x16x32_bf16(al[m], bh[n], acc[m][n], 0, 0, 0);
    }
}

// ---------------- pack kernels: f32 [K][N] -> pre-swizzled 8KB bf16 chunks ----------------

__global__ __launch_bounds__(256) void k_pack1(const float* __restrict__ src, long ld,
                                               long zs, int nc,
                                               unsigned short* __restrict__ dst) {
  __shared__ float tile[32][132];
  const float* Sp = src + (long)blockIdx.z * zs;
  int c = blockIdx.x, t = threadIdx.x;
  for (int i = 0; i < 4; i++) {
    int kt = blockIdx.y * 4 + i;
    long k0 = (long)kt * 32, n0 = (long)c * 128;
    {
      int k = t >> 3, nn = (t & 7) * 16;
      const float4* p = (const float4*)(Sp + (k0 + k) * ld + n0 + nn);
#pragma unroll
      for (int j = 0; j < 4; j++) *(float4*)&tile[k][nn + j * 4] = p[j];
    }
    __syncthreads();
    size_t cbase = ((size_t)(blockIdx.z * nc + c) * 64 + kt) * 4096;
#pragma unroll
    for (int uu = 0; uu < 2; uu++) {
      int u = t * 2 + uu;
      int n = u >> 2, qp = u & 3;
      int q = qp ^ ((n ^ (n >> 2)) & 3);
      unsigned short hb[8] __attribute__((aligned(16)));
#pragma unroll
      for (int j = 0; j < 8; j++) hb[j] = f2bf(tile[8 * q + j][n]);
      *(uint4*)(dst + cbase + u * 8) = *(const uint4*)hb;
    }
    __syncthreads();
  }
}

__global__ __launch_bounds__(256) void k_pack2(const float* __restrict__ src, long ld,
                                               long zs, int nc,
                                               unsigned short* __restrict__ dh,
                                               unsigned short* __restrict__ dl) {
  __shared__ float tile[32][132];
  const float* Sp = src + (long)blockIdx.z * zs;
  int c = blockIdx.x, t = threadIdx.x;
  for (int i = 0; i < 4; i++) {
    int kt = blockIdx.y * 4 + i;
    long k0 = (long)kt * 32, n0 = (long)c * 128;
    {
      int k = t >> 3, nn = (t & 7) * 16;
      const float4* p = (const float4*)(Sp + (k0 + k) * ld + n0 + nn);
#pragma unroll
      for (int j = 0; j < 4; j++) *(float4*)&tile[k][nn + j * 4] = p[j];
    }
    __syncthreads();
    size_t cbase = ((size_t)(blockIdx.z * nc + c) * 64 + kt) * 4096;
#pragma unroll
    for (int uu = 0; uu < 2; uu++) {
      int u = t * 2 + uu;
      int n = u >> 2, qp = u & 3;
      int q = qp ^ ((n ^ (n >> 2)) & 3);
      unsigned short hb[8] __attribute__((aligned(16)));
      unsigned short lb[8] __attribute__((aligned(16)));
#pragma unroll
      for (int j = 0; j < 8; j++) split2(tile[8 * q + j][n], hb[j], lb[j]);
      *(uint4*)(dh + cbase + u * 8) = *(const uint4*)hb;
      *(uint4*)(dl + cbase + u * 8) = *(const uint4*)lb;
    }
    __syncthreads();
  }
}

// pack bf16 [z][S][HD] -> chunks [z][64][4096]
__global__ __launch_bounds__(256) void k_packbf(const unsigned short* __restrict__ src,
                                                unsigned short* __restrict__ dst) {
  int ttile = blockIdx.x;
  int z = blockIdx.y;
  const unsigned short* Sp = src + ((size_t)z * S_LEN + (size_t)ttile * 128) * HD;
  size_t ob = ((size_t)z * 64 + (size_t)ttile * 4) * 4096;
  int t = threadIdx.x;
#pragma unroll
  for (int kst = 0; kst < 4; kst++) {
#pragma unroll
    for (int uu = 0; uu < 2; uu++) {
      int u = t * 2 + uu;
      int n = u >> 2, qp = u & 3;
      int q = qp ^ ((n ^ (n >> 2)) & 3);
      *(uint4*)(dst + ob + (size_t)kst * 4096 + u * 8) =
          *(const uint4*)(Sp + (size_t)n * HD + kst * 32 + q * 8);
    }
  }
}

// gather routed token rows (bf16 [S][D]) into per-tile A-chunks
__global__ __launch_bounds__(256) void k_gpack(const unsigned short* __restrict__ h2b,
                                               const int* __restrict__ ptok,
                                               const int* __restrict__ meta,
                                               unsigned short* __restrict__ hAP) {
  int ty = blockIdx.x;
  if (ty >= meta[25]) return;
  int tt = meta[26 + ty];
  int e = tt & 7, m0 = tt >> 3;
  int nvalid = min(128, meta[e] - m0);
  const int* toks = ptok + meta[16 + e] + m0;
  int t = threadIdx.x;
  int r = t >> 2, q = t & 3;
  int s = (r ^ (r >> 2)) & 3;
  for (int kt = blockIdx.y * 8; kt < blockIdx.y * 8 + 8; kt++) {
    unsigned short* dst = hAP + ((size_t)ty * 64 + kt) * 4096;
#pragma unroll
    for (int rr = 0; rr < 2; rr++) {
      int row = r + rr * 64;
      uint4 v = make_uint4(0, 0, 0, 0);
      if (row < nvalid)
        v = *(const uint4*)(h2b + (size_t)toks[row] * DMODEL + kt * 32 + q * 8);
      *(uint4*)(dst + row * 32 + ((q ^ s) << 3)) = v;
    }
  }
}

// ---------------- qkv / wo GEMMs (fp32-emulated, counted-vmcnt depth-2) ----------------

__global__ __launch_bounds__(256) void k_qkv_s(const unsigned short* __restrict__ APh,
                                               const unsigned short* __restrict__ APl,
                                               const unsigned short* __restrict__ BPh,
                                               const unsigned short* __restrict__ BPl,
                                               float* __restrict__ C) {
  __shared__ unsigned short Ash[2 * 4096], Asl[2 * 4096], Bsh[2 * 4096], Bsl[2 * 4096];
  size_t ab = (size_t)blockIdx.y * 64 * 4096;
  size_t cb = (size_t)blockIdx.x * 64 * 4096;
  int w = threadIdx.x >> 6;
  int wr = (w >> 1) * 64, wc = (w & 1) * 64;
  // prologue: stage step 0 -> buf0, step 1 -> buf1
  stageB_chunk(APh + ab, Ash);
  stageB_chunk(APl + ab, Asl);
  stageB_chunk(BPh + cb, Bsh);
  stageB_chunk(BPl + cb, Bsl);
  stageB_chunk(APh + ab + 4096, Ash + 4096);
  stageB_chunk(APl + ab + 4096, Asl + 4096);
  stageB_chunk(BPh + cb + 4096, Bsh + 4096);
  stageB_chunk(BPl + cb + 4096, Bsl + 4096);
  WVM8;  // step-0 set (8 ops) complete; step-1 still in flight
  BAR;
  f32x4 acc[4][4] = {};
  for (int kt = 0; kt < 64; kt++) {
    int cur = (kt & 1) << 12;
    SCHEDBAR;
    mma16_split_reg(Ash + cur, Asl + cur, Bsh + cur, Bsl + cur, wr, wc, acc);
    SCHEDBAR;
    BAR;  // all waves done reading cur
    if (kt + 2 < 64) {
      size_t o = (size_t)(kt + 2) * 4096;
      stageB_chunk(APh + ab + o, Ash + cur);
      stageB_chunk(APl + ab + o, Asl + cur);
      stageB_chunk(BPh + cb + o, Bsh + cur);
      stageB_chunk(BPl + cb + o, Bsl + cur);
      WVM8;  // (kt+1) loads complete; (kt+2) in flight
    } else {
      WVM0;
    }
    BAR;
  }
  int row0 = blockIdx.y * 128, col0 = blockIdx.x * 128;
  int l = threadIdx.x & 63;
  int er = wr + ((l >> 4) << 2), ec = wc + (l & 15);
#pragma unroll
  for (int m = 0; m < 4; m++)
#pragma unroll
    for (int n = 0; n < 4; n++)
#pragma unroll
      for (int r = 0; r < 4; r++) {
        float v = acc[m][n][r];
        v = fminf(fmaxf(v, -8.f), 8.f);
        C[(size_t)(row0 + er + m * 16 + r) * QKV_N + col0 + ec + n * 16] = v;
      }
}

__global__ __launch_bounds__(256) void k_wo_s(const unsigned short* __restrict__ APh,
                                              const unsigned short* __restrict__ APl,
                                              const unsigned short* __restrict__ BPh,
                                              const unsigned short* __restrict__ BPl,
                                              const float* __restrict__ resid,
                                              float* __restrict__ x1) {
  __shared__ unsigned short Ash[2 * 4096], Asl[2 * 4096], Bsh[2 * 4096], Bsl[2 * 4096];
  size_t ab = (size_t)blockIdx.y * 64 * 4096;
  size_t cb = (size_t)blockIdx.x * 64 * 4096;
  int w = threadIdx.x >> 6;
  int wr = (w >> 1) * 64, wc = (w & 1) * 64;
  stageB_chunk(APh + ab, Ash);
  stageB_chunk(APl + ab, Asl);
  stageB_chunk(BPh + cb, Bsh);
  stageB_chunk(BPl + cb, Bsl);
  stageB_chunk(APh + ab + 4096, Ash + 4096);
  stageB_chunk(APl + ab + 4096, Asl + 4096);
  stageB_chunk(BPh + cb + 4096, Bsh + 4096);
  stageB_chunk(BPl + cb + 4096, Bsl + 4096);
  WVM8;
  BAR;
  f32x4 acc[4][4] = {};
  for (int kt = 0; kt < 64; kt++) {
    int cur = (kt & 1) << 12;
    SCHEDBAR;
    mma16_split_reg(Ash + cur, Asl + cur, Bsh + cur, Bsl + cur, wr, wc, acc);
    SCHEDBAR;
    BAR;
    if (kt + 2 < 64) {
      size_t o = (size_t)(kt + 2) * 4096;
      stageB_chunk(APh + ab + o, Ash + cur);
      stageB_chunk(APl + ab + o, Asl + cur);
      stageB_chunk(BPh + cb + o, Bsh + cur);
      stageB_chunk(BPl + cb + o, Bsl + cur);
      WVM8;
    } else {
      WVM0;
    }
    BAR;
  }
  int row0 = blockIdx.y * 128, col0 = blockIdx.x * 128;
  int l = threadIdx.x & 63;
  int er = wr + ((l >> 4) << 2), ec = wc + (l & 15);
#pragma unroll
  for (int m = 0; m < 4; m++)
#pragma unroll
    for (int n = 0; n < 4; n++)
#pragma unroll
      for (int r = 0; r < 4; r++) {
        size_t idx = (size_t)(row0 + er + m * 16 + r) * DMODEL + col0 + ec + n * 16;
        x1[idx] = resid[idx] + acc[m][n][r];
      }
}

// ---------------- flash attention (r8-verified core; chunk-layout epilogue) ----------------

__global__ __launch_bounds__(128) void k_flash(const unsigned short* __restrict__ qh,
                                               const unsigned short* __restrict__ ql,
                                               const unsigned short* __restrict__ kPh,
                                               const unsigned short* __restrict__ kPl,
                                               const unsigned short* __restrict__ vPh,
                                               const unsigned short* __restrict__ vPl,
                                               unsigned short* __restrict__ atPh,
                                               unsigned short* __restrict__ atPl) {
  int bid = blockIdx.x;
  int h = (bid & 7) | ((bid >> 8) << 3);
  int rt = (bid >> 3) & 31;
  int kv = h >> 2;
  int ntiles = (rt >> 1) + 1;
  __shared__ float Pds[2][32 * 132];
  int t = threadIdx.x;
  int w = t >> 6, l = t & 63;
  int lr = l & 15, lg = l >> 4;
  int qoff = ((lg ^ ((lr ^ (lr >> 2)) & 3)) << 3);
  int wrow0 = rt * 64 + w * 32;
  const unsigned short* Qbh = qh + (size_t)h * S_LEN * HD;
  const unsigned short* Qbl = ql + (size_t)h * S_LEN * HD;
  const unsigned short* Kch = kPh + (size_t)kv * 64 * 4096;
  const unsigned short* Kcl = kPl + (size_t)kv * 64 * 4096;
  const unsigned short* Vch = vPh + (size_t)kv * 64 * 4096;
  const unsigned short* Vcl = vPl + (size_t)kv * 64 * 4096;
  float* Pw = &Pds[w][0];
  float mrun[2][4], lrun[2][4];
  f32x4 Oc[2][8];
#pragma unroll
  for (int m = 0; m < 2; m++)
#pragma unroll
    for (int r = 0; r < 4; r++) { mrun[m][r] = -3.4e38f; lrun[m][r] = 0.f; }
#pragma unroll
  for (int m = 0; m < 2; m++)
#pragma unroll
    for (int n = 0; n < 8; n++)
#pragma unroll
      for (int r = 0; r < 4; r++) Oc[m][n][r] = 0.f;
  const float scale = 0.08838834764831845f;

  for (int kt = 0; kt < ntiles; kt++) {
    f32x4 Sa[2][8];
#pragma unroll
    for (int m = 0; m < 2; m++)
#pragma unroll
      for (int n = 0; n < 8; n++)
#pragma unroll
        for (int r = 0; r < 4; r++) Sa[m][n][r] = 0.f;
#pragma unroll
    for (int kst = 0; kst < 4; kst++) {
      short8 qfh[2], qfl[2];
#pragma unroll
      for (int m = 0; m < 2; m++) {
        size_t o = (size_t)(wrow0 + m * 16 + lr) * HD + kst * 32 + lg * 8;
        qfh[m] = *(const short8*)(Qbh + o);
        qfl[m] = *(const short8*)(Qbl + o);
      }
      const unsigned short* Kh = Kch + (size_t)(kt * 4 + kst) * 4096;
      const unsigned short* Kl = Kcl + (size_t)(kt * 4 + kst) * 4096;
      short8 bh[8], bl[8];
#pragma unroll
      for (int n = 0; n < 8; n++) {
        bh[n] = *(const short8*)(Kh + (n * 16 + lr) * 32 + qoff);
        bl[n] = *(const short8*)(Kl + (n * 16 + lr) * 32 + qoff);
      }
#pragma unroll
      for (int m = 0; m < 2; m++)
#pragma unroll
        for (int n = 0; n < 8; n++) {
          Sa[m][n] = __builtin_amdgcn_mfma_f32_16x16x32_bf16(qfh[m], bh[n], Sa[m][n], 0, 0, 0);
          Sa[m][n] = __builtin_amdgcn_mfma_f32_16x16x32_bf16(qfh[m], bl[n], Sa[m][n], 0, 0, 0);
          Sa[m][n] = __builtin_amdgcn_mfma_f32_16x16x32_bf16(qfl[m], bh[n], Sa[m][n], 0, 0, 0);
        }
    }
#pragma unroll
    for (int m = 0; m < 2; m++)
#pragma unroll
      for (int r = 0; r < 4; r++) {
        int row = wrow0 + m * 16 + lg * 4 + r;
        float mx = mrun[m][r];
#pragma unroll
        for (int n = 0; n < 8; n++) {
          float v = Sa[m][n][r] * scale;
          int col = kt * 128 + n * 16 + lr;
          v = (col <= row) ? v : -3.4e38f;
          Sa[m][n][r] = v;
          mx = fmaxf(mx, v);
        }
        mx = fmaxf(mx, __shfl_xor(mx, 1));
        mx = fmaxf(mx, __shfl_xor(mx, 2));
        mx = fmaxf(mx, __shfl_xor(mx, 4));
        mx = fmaxf(mx, __shfl_xor(mx, 8));
        float al_ = expf(mrun[m][r] - mx);
        float sum = 0.f;
#pragma unroll
        for (int n = 0; n < 8; n++) {
          float v = Sa[m][n][r];
          float e = (v > -1.0e37f) ? expf(v - mx) : 0.f;
          Sa[m][n][r] = e;
          sum += e;
        }
        sum += __shfl_xor(sum, 1);
        sum += __shfl_xor(sum, 2);
        sum += __shfl_xor(sum, 4);
        sum += __shfl_xor(sum, 8);
        lrun[m][r] = lrun[m][r] * al_ + sum;
        mrun[m][r] = mx;
#pragma unroll
        for (int n = 0; n < 8; n++) Oc[m][n][r] *= al_;
      }
    WAIT_LDS;
    SCHEDBAR;
#pragma unroll
    for (int m = 0; m < 2; m++)
#pragma unroll
      for (int n = 0; n < 8; n++)
#pragma unroll
        for (int r = 0; r < 4; r++)
          Pw[(m * 16 + lg * 4 + r) * 132 + n * 16 + lr] = Sa[m][n][r];
    WAIT_LDS;
    SCHEDBAR;
#pragma unroll
    for (int kst = 0; kst < 4; kst++) {
      const unsigned short* Vh = Vch + (size_t)(kt * 4 + kst) * 4096;
      const unsigned short* Vl = Vcl + (size_t)(kt * 4 + kst) * 4096;
      short8 bh[8], bl[8];
#pragma unroll
      for (int n = 0; n < 8; n++) {
        bh[n] = *(const short8*)(Vh + (n * 16 + lr) * 32 + qoff);
        bl[n] = *(const short8*)(Vl + (n * 16 + lr) * 32 + qoff);
      }
#pragma unroll
      for (int m = 0; m < 2; m++) {
        const float* pp = &Pw[(m * 16 + lr) * 132 + kst * 32 + lg * 8];
        unsigned short ahb[8] __attribute__((aligned(16)));
        unsigned short alb[8] __attribute__((aligned(16)));
#pragma unroll
        for (int j = 0; j < 8; j++) split2(pp[j], ahb[j], alb[j]);
        short8 ah = *(const short8*)ahb;
        short8 al_ = *(const short8*)alb;
#pragma unroll
        for (int n = 0; n < 8; n++) {
          Oc[m][n] = __builtin_amdgcn_mfma_f32_16x16x32_bf16(ah, bh[n], Oc[m][n], 0, 0, 0);
          Oc[m][n] = __builtin_amdgcn_mfma_f32_16x16x32_bf16(ah, bl[n], Oc[m][n], 0, 0, 0);
          Oc[m][n] = __builtin_amdgcn_mfma_f32_16x16x32_bf16(al_, bh[n], Oc[m][n], 0, 0, 0);
        }
      }
    }
  }
#pragma unroll
  for (int m = 0; m < 2; m++)
#pragma unroll
    for (int r = 0; r < 4; r++) {
      int row = wrow0 + m * 16 + lg * 4 + r;
      int rtc = row >> 7, rl = row & 127;
      int sr = (rl ^ (rl >> 2)) & 3;
      float lv = lrun[m][r];
#pragma unroll
      for (int n = 0; n < 8; n++) {
        int col = h * HD + n * 16 + lr;
        size_t off = ((size_t)(rtc * 64 + (col >> 5))) * 4096 + rl * 32 +
                     ((((col & 31) >> 3) ^ sr) << 3) + (col & 7);
        unsigned short hh, ll;
        split2(Oc[m][n][r] / lv, hh, ll);
        atPh[off] = hh;
        atPl[off] = ll;
      }
    }
}

// ---------------- MoE GEMMs: all-chunk, counted-vmcnt depth-2 ----------------

// g(chunks) = silu(h2 @ w1[e]) * (h2 @ v1[e])
__global__ __launch_bounds__(256) void k_moe1f(const unsigned short* __restrict__ hAP,
                                               const unsigned short* __restrict__ wPa,
                                               const unsigned short* __restrict__ wPb,
                                               const int* __restrict__ meta,
                                               unsigned short* __restrict__ g) {
  int ty = blockIdx.y;
  if (ty >= meta[25]) return;
  int tt = meta[26 + ty];
  int e = tt & 7, m0 = tt >> 3;
  int nvalid = min(128, meta[e] - m0);
  const unsigned short* Ab = hAP + (size_t)ty * 64 * 4096;
  const unsigned short* B1 = wPa + (size_t)(e * 16 + blockIdx.x) * 64 * 4096;
  const unsigned short* B2 = wPb + (size_t)(e * 16 + blockIdx.x) * 64 * 4096;
  __shared__ unsigned short As[2 * 4096], Bs1[2 * 4096], Bs2[2 * 4096];
  int w = threadIdx.x >> 6;
  int wr = (w >> 1) * 64, wc = (w & 1) * 64;
  stageB_chunk(Ab, As);
  stageB_chunk(B1, Bs1);
  stageB_chunk(B2, Bs2);
  stageB_chunk(Ab + 4096, As + 4096);
  stageB_chunk(B1 + 4096, Bs1 + 4096);
  stageB_chunk(B2 + 4096, Bs2 + 4096);
  WVM6;
  BAR;
  f32x4 acc1[4][4] = {}, acc2[4][4] = {};
  for (int kt = 0; kt < 64; kt++) {
    int cur = (kt & 1) << 12;
    SCHEDBAR;
    mma16_dualB(As + cur, Bs1 + cur, Bs2 + cur, wr, wc, acc1, acc2);
    SCHEDBAR;
    BAR;
    if (kt + 2 < 64) {
      size_t o = (size_t)(kt + 2) * 4096;
      stageB_chunk(Ab + o, As + cur);
      stageB_chunk(B1 + o, Bs1 + cur);
      stageB_chunk(B2 + o, Bs2 + cur);
      WVM6;
    } else {
      WVM0;
    }
    BAR;
  }
  int l = threadIdx.x & 63;
  int er = wr + ((l >> 4) << 2), ec = wc + (l & 15);
  int ktf0 = blockIdx.x * 4;
#pragma unroll
  for (int m = 0; m < 4; m++)
#pragma unroll
    for (int n = 0; n < 4; n++)
#pragma unroll
      for (int r = 0; r < 4; r++) {
        int rl = er + m * 16 + r;
        int cc = ec + n * 16;
        float a = acc1[m][n][r];
        float s = a / (1.f + expf(-a));
        unsigned short val = (rl < nvalid) ? f2bf(s * acc2[m][n][r]) : (unsigned short)0;
        int srl = (rl ^ (rl >> 2)) & 3;
        g[((size_t)(ty * 64 + ktf0 + (cc >> 5))) * 4096 + rl * 32 +
          ((((cc & 31) >> 3) ^ srl) << 3) + (cc & 7)] = val;
      }
}

// out[tok] += gate * (g @ w2[e])   (out already holds x1)
__global__ __launch_bounds__(256) void k_moe2(const unsigned short* __restrict__ gP,
                                              const unsigned short* __restrict__ wP,
                                              const int* __restrict__ ptok,
                                              const float* __restrict__ pw,
                                              const int* __restrict__ meta,
                                              float* __restrict__ out) {
  int ty = blockIdx.y;
  if (ty >= meta[25]) return;
  int tt = meta[26 + ty];
  int e = tt & 7, m0 = tt >> 3;
  int nvalid = min(128, meta[e] - m0);
  long pbase = (long)meta[16 + e] + m0;
  const unsigned short* Ab = gP + (size_t)ty * 64 * 4096;
  const unsigned short* Bb = wP + (size_t)(e * 16 + blockIdx.x) * 64 * 4096;
  __shared__ unsigned short As[2 * 4096], Bs[2 * 4096];
  int w = threadIdx.x >> 6;
  int wr = (w >> 1) * 64, wc = (w & 1) * 64;
  stageB_chunk(Ab, As);
  stageB_chunk(Bb, Bs);
  stageB_chunk(Ab + 4096, As + 4096);
  stageB_chunk(Bb + 4096, Bs + 4096);
  WVM4;
  BAR;
  f32x4 acc[4][4] = {};
  for (int kt = 0; kt < 64; kt++) {
    int cur = (kt & 1) << 12;
    SCHEDBAR;
    mma16(As + cur, Bs + cur, wr, wc, acc);
    SCHEDBAR;
    BAR;
    if (kt + 2 < 64) {
      size_t o = (size_t)(kt + 2) * 4096;
      stageB_chunk(Ab + o, As + cur);
      stageB_chunk(Bb + o, Bs + cur);
      WVM4;
    } else {
      WVM0;
    }
    BAR;
  }
  int col0 = blockIdx.x * 128;
  int l = threadIdx.x & 63;
  int er = wr + ((l >> 4) << 2), ec = wc + (l & 15);
#pragma unroll
  for (int m = 0; m < 4; m++)
#pragma unroll
    for (int n = 0; n < 4; n++)
#pragma unroll
      for (int r = 0; r < 4; r++) {
        int rl = er + m * 16 + r;
        if (rl < nvalid) {
          long p = pbase + rl;
          int tk = ptok[p];
          atomicAdd(&out[(size_t)tk * DMODEL + col0 + ec + n * 16], acc[m][n][r] * pw[p]);
        }
      }
}

// ---------------- small kernels ----------------

// mode 0: row-major hi/lo + f32. mode 1: chunk-layout hi/lo.
__global__ __launch_bounds__(256) void k_ln(const float* __restrict__ x,
                                            const float* __restrict__ w,
                                            unsigned short* __restrict__ obh,
                                            unsigned short* __restrict__ obl,
                                            float* __restrict__ of, int mode) {
  int row = blockIdx.x;
  const float* xr = x + (size_t)row * DMODEL;
  float s = 0.f, ss = 0.f;
  for (int c = threadIdx.x; c < DMODEL; c += 256) {
    float v = xr[c];
    s += v; ss += v * v;
  }
#pragma unroll
  for (int o = 32; o; o >>= 1) { s += __shfl_down(s, o); ss += __shfl_down(ss, o); }
  __shared__ float rs[4], rss[4], mu_s, inv_s;
  int wid = threadIdx.x >> 6;
  if ((threadIdx.x & 63) == 0) { rs[wid] = s; rss[wid] = ss; }
  __syncthreads();
  if (threadIdx.x == 0) {
    float S1 = rs[0] + rs[1] + rs[2] + rs[3];
    float S2 = rss[0] + rss[1] + rss[2] + rss[3];
    float mu = S1 / DMODEL;
    mu_s = mu;
    inv_s = rsqrtf(S2 / DMODEL - mu * mu + 1e-5f);
  }
  __syncthreads();
  float mu = mu_s, inv = inv_s;
  int rt = row >> 7, rl = row & 127;
  int sw = (rl ^ (rl >> 2)) & 3;
  for (int c = threadIdx.x; c < DMODEL; c += 256) {
    float v = (xr[c] - mu) * inv * w[c];
    unsigned short hh, ll;
    split2(v, hh, ll);
    if (mode) {
      size_t off = ((size_t)(rt * 64 + (c >> 5))) * 4096 + rl * 32 +
                   ((((c & 31) >> 3) ^ sw) << 3) + (c & 7);
      obh[off] = hh;
      obl[off] = ll;
    } else {
      obh[(size_t)row * DMODEL + c] = hh;
      obl[(size_t)row * DMODEL + c] = ll;
      of[(size_t)row * DMODEL + c] = v;
    }
  }
}

__global__ void k_rope2(const float* __restrict__ qkv, unsigned short* __restrict__ qh,
                        unsigned short* __restrict__ ql, unsigned short* __restrict__ kh,
                        unsigned short* __restrict__ kl) {
  int t = blockIdx.x;
  int d = threadIdx.x;
  float pf = (float)pow(500000.0, (double)d * (1.0 / 64.0));
  float invf = 1.0f / pf;
  float ang = (float)t * invf;
  float cs = (float)cos((double)ang);
  float sn = (float)sin((double)ang);
  const float* row = qkv + (size_t)t * QKV_N;
  unsigned short hh, ll;
#pragma unroll
  for (int hq = 0; hq < NH; hq++) {
    float a = row[hq * HD + d], b = row[hq * HD + d + 64];
    size_t base = ((size_t)hq * S_LEN + t) * HD;
    split2(a * cs - b * sn, hh, ll); qh[base + d] = hh; ql[base + d] = ll;
    split2(b * cs + a * sn, hh, ll); qh[base + d + 64] = hh; ql[base + d + 64] = ll;
  }
#pragma unroll
  for (int kv = 0; kv < NKV; kv++) {
    float a = row[NH * HD + kv * HD + d], b = row[NH * HD + kv * HD + d + 64];
    size_t base = ((size_t)kv * S_LEN + t) * HD;
    split2(a * cs - b * sn, hh, ll); kh[base + d] = hh; kl[base + d] = ll;
    split2(b * cs + a * sn, hh, ll); kh[base + d + 64] = hh; kl[base + d + 64] = ll;
  }
}

__global__ __launch_bounds__(256) void k_router(const float* __restrict__ h2,
                                                const float* __restrict__ rw,
                                                int* __restrict__ topi,
                                                float* __restrict__ topw,
                                                int* __restrict__ cnt) {
  int t = blockIdx.x;
  __shared__ float hs[DMODEL];
  __shared__ float lg[NE];
  for (int c = threadIdx.x; c < DMODEL; c += 256) hs[c] = h2[(size_t)t * DMODEL + c];
  __syncthreads();
  int grp = threadIdx.x >> 5;
  int ln = threadIdx.x & 31;
  float p = 0.f;
  for (int c = ln; c < DMODEL; c += 32) p += hs[c] * rw[(size_t)grp * DMODEL + c];
#pragma unroll
  for (int o = 16; o; o >>= 1) p += __shfl_down(p, o, 32);
  if (ln == 0) lg[grp] = p;
  __syncthreads();
  if (threadIdx.x == 0) {
    float l0 = -3.4e38f; int i0 = 0;
    for (int e = 0; e < NE; e++)
      if (lg[e] > l0) { l0 = lg[e]; i0 = e; }
    float l1 = -3.4e38f; int i1 = 0;
    for (int e = 0; e < NE; e++)
      if (e != i0 && lg[e] > l1) { l1 = lg[e]; i1 = e; }
    float z = expf(l1 - l0);
    topi[t * 2] = i0; topi[t * 2 + 1] = i1;
    topw[t * 2] = 1.f / (1.f + z); topw[t * 2 + 1] = z / (1.f + z);
    atomicAdd(&cnt[i0], 1);
    atomicAdd(&cnt[i1], 1);
  }
}

__global__ void k_scan(int* __restrict__ meta) {
  if (threadIdx.x == 0 && blockIdx.x == 0) {
    int o = 0, nt = 0;
    for (int e = 0; e < NE; e++) {
      meta[16 + e] = o;
      for (int m0 = 0; m0 < meta[e]; m0 += 128) meta[26 + nt++] = (m0 << 3) | e;
      o += meta[e];
    }
    meta[24] = o;
    meta[25] = nt;
  }
}

__global__ void k_fill(const int* __restrict__ topi, const float* __restrict__ topw,
                       int* __restrict__ meta, int* __restrict__ ptok,
                       float* __restrict__ pw) {
  int t = blockIdx.x * blockDim.x + threadIdx.x;
  if (t >= S_LEN) return;
#pragma unroll
  for (int j = 0; j < 2; j++) {
    int e = topi[t * 2 + j];
    int p = atomicAdd(&meta[8 + e], 1);
    ptok[meta[16 + e] + p] = t;
    pw[meta[16 + e] + p] = topw[t * 2 + j];
  }
}

// ---------------- launch ----------------

extern "C" void kernel_launch(void* const* d_in, const int* in_sizes, int n_in,
                              void* d_out, int out_size, void* d_ws, size_t ws_size,
                              hipStream_t stream) {
  (void)in_sizes; (void)n_in; (void)out_size; (void)ws_size;
  const float* x = (const float*)d_in[0];
  const float* ln1w = (const float*)d_in[2];
  const float* ln2w = (const float*)d_in[3];
  const float* wqkv = (const float*)d_in[4];
  const float* wo = (const float*)d_in[5];
  const float* rw = (const float*)d_in[6];
  const float* w1 = (const float*)d_in[7];
  const float* v1 = (const float*)d_in[8];
  const float* w2 = (const float*)d_in[9];
  float* out = (float*)d_out;  // x1 after k_wo_s; MoE adds in place

  char* wsb = (char*)d_ws;
  const size_t MiB = 1u << 20;
  // ---- attention phase ----
  unsigned short* h1Ph = (unsigned short*)(wsb + 0 * MiB);     // 8 (chunks)
  unsigned short* h1Pl = (unsigned short*)(wsb + 8 * MiB);     // 8
  float* qkvb = (float*)(wsb + 16 * MiB);                      // 24
  unsigned short* qh = (unsigned short*)(wsb + 40 * MiB);      // 8
  unsigned short* ql = (unsigned short*)(wsb + 48 * MiB);      // 8
  unsigned short* kh = (unsigned short*)(wsb + 56 * MiB);      // 2
  unsigned short* kl = (unsigned short*)(wsb + 58 * MiB);      // 2
  unsigned short* vPh = (unsigned short*)(wsb + 60 * MiB);     // 2
  unsigned short* vPl = (unsigned short*)(wsb + 62 * MiB);     // 2
  unsigned short* kPh = (unsigned short*)(wsb + 64 * MiB);     // 2
  unsigned short* kPl = (unsigned short*)(wsb + 66 * MiB);     // 2
  unsigned short* atPh = (unsigned short*)(wsb + 68 * MiB);    // 8 (chunks)
  unsigned short* atPl = (unsigned short*)(wsb + 76 * MiB);    // 8
  unsigned short* wqkvPh = (unsigned short*)(wsb + 84 * MiB);  // 12
  unsigned short* wqkvPl = (unsigned short*)(wsb + 96 * MiB);  // 12
  unsigned short* woPh = (unsigned short*)(wsb + 108 * MiB);   // 8
  unsigned short* woPl = (unsigned short*)(wsb + 116 * MiB);   // 8
  // ---- MoE phase (overlays; producers run after the overlapped consumers) ----
  unsigned short* hAP = (unsigned short*)(wsb + 0 * MiB);      // 20 (over h1P)
  unsigned short* g = (unsigned short*)(wsb + 20 * MiB);       // 20 (over qkvb)
  float* h2f = (float*)(wsb + 40 * MiB);                       // 16 (over qh/ql)
  unsigned short* h2b = (unsigned short*)(wsb + 56 * MiB);     // 8 (over kh..vP)
  unsigned short* h2lo = (unsigned short*)(wsb + 20 * MiB);    // scratch (lo never read)
  unsigned short* wPa = (unsigned short*)(wsb + 40 * MiB);     // 64 (after router/gpack)
  unsigned short* wPb = (unsigned short*)(wsb + 104 * MiB);    // 64
  char* small = wsb + 168 * MiB;
  int* topi = (int*)small;
  float* topw = (float*)(small + 16384);
  int* ptok = (int*)(small + 32768);
  float* pw = (float*)(small + 49152);
  int* meta = (int*)(small + 65536);  // 128 ints

  // ---- pack attention weights ----
  k_pack2<<<dim3(QKV_N / 128, 16, 1), 256, 0, stream>>>(wqkv, QKV_N, 0, QKV_N / 128,
                                                        wqkvPh, wqkvPl);
  k_pack2<<<dim3(DMODEL / 128, 16, 1), 256, 0, stream>>>(wo, DMODEL, 0, DMODEL / 128,
                                                         woPh, woPl);

  // ---- attention sublayer (fp32-emulated) ----
  k_ln<<<S_LEN, 256, 0, stream>>>(x, ln1w, h1Ph, h1Pl, (float*)nullptr, 1);
  k_qkv_s<<<dim3(QKV_N / 128, S_LEN / 128), 256, 0, stream>>>(h1Ph, h1Pl, wqkvPh, wqkvPl,
                                                              qkvb);
  k_rope2<<<S_LEN, 64, 0, stream>>>(qkvb, qh, ql, kh, kl);
  k_pack2<<<dim3(1, 16, NKV), 256, 0, stream>>>(qkvb + (NH + NKV) * HD, QKV_N, HD, 1,
                                                vPh, vPl);
  k_packbf<<<dim3(16, NKV), 256, 0, stream>>>(kh, kPh);
  k_packbf<<<dim3(16, NKV), 256, 0, stream>>>(kl, kPl);
  k_flash<<<512, 128, 0, stream>>>(qh, ql, kPh, kPl, vPh, vPl, atPh, atPl);
  k_wo_s<<<dim3(16, 16), 256, 0, stream>>>(atPh, atPl, woPh, woPl, x, out);

  // ---- MoE sublayer ----
  k_ln<<<S_LEN, 256, 0, stream>>>(out, ln2w, h2b, h2lo, h2f, 0);
  hipMemsetAsync(meta, 0, 512, stream);
  k_router<<<S_LEN, 256, 0, stream>>>(h2f, rw, topi, topw, meta);
  k_scan<<<1, 64, 0, stream>>>(meta);
  k_fill<<<8, 256, 0, stream>>>(topi, topw, meta, ptok, pw);
  k_gpack<<<dim3(40, 8), 256, 0, stream>>>(h2b, ptok, meta, hAP);
  k_pack1<<<dim3(16, 16, NE), 256, 0, stream>>>(w1, FF, (long)DMODEL * FF, 16, wPa);
  k_pack1<<<dim3(16, 16, NE), 256, 0, stream>>>(v1, FF, (long)DMODEL * FF, 16, wPb);
  k_moe1f<<<dim3(16, 40), 256, 0, stream>>>(hAP, wPa, wPb, meta, g);
  k_pack1<<<dim3(16, 16, NE), 256, 0, stream>>>(w2, DMODEL, (long)FF * DMODEL, 16, wPa);
  k_moe2<<<dim3(16, 40), 256, 0, stream>>>(g, wPa, ptok, pw, meta, out);
}

// Round 12
// 970.452 us; speedup vs baseline: 1.0318x; 1.0318x over previous
//
#include <hip/hip_runtime.h>

#define S_LEN 2048
#define DMODEL 2048
#define NH 16
#define NKV 4
#define HD 128
#define NE 8
#define FF 2048
#define QKV_N 3072   // (H + 2*KV) * HD

typedef __attribute__((ext_vector_type(8))) short short8;
typedef __attribute__((ext_vector_type(4))) float f32x4;

__device__ inline unsigned short f2bf(float f) {
  unsigned int u = __builtin_bit_cast(unsigned int, f);
  u += 0x7fffu + ((u >> 16) & 1u);
  return (unsigned short)(u >> 16);
}
__device__ inline float bf2f(unsigned short h) {
  unsigned int u = ((unsigned int)h) << 16;
  return __builtin_bit_cast(float, u);
}
__device__ inline void split2(float v, unsigned short& h, unsigned short& l) {
  h = f2bf(v);
  l = f2bf(v - bf2f(h));
}

// ======== chunk format (verified r3-r11): 8KB = 128 rows x 32 k bf16 ========
// element (row, k=8q+j) at ushort off row*32 + ((q ^ s(row))<<3) + j, s=(row^(row>>2))&3
// NOTE: s(row) depends only on row&15 bits 0-3 -> s(base+lr)=s(lr) for base mult of 16.

__device__ inline void gload16(const void* g, void* l) {
  __builtin_amdgcn_global_load_lds((const __attribute__((address_space(1))) unsigned int*)g,
                                   (__attribute__((address_space(3))) unsigned int*)l,
                                   16, 0, 0);
}
// full 8KB chunk, 4 waves cooperative (used by qkv/wo)
__device__ inline void stageB_chunk(const unsigned short* __restrict__ chunk,
                                    unsigned short* __restrict__ lds) {
  int w = threadIdx.x >> 6, l = threadIdx.x & 63;
  const unsigned short* s = chunk + w * 1024 + l * 8;
  unsigned short* d = lds + w * 1024;
  gload16(s, d);
  gload16(s + 512, d + 512);
}
// 4KB half-chunk, single wave (barrier-free per-wave GEMMs)
__device__ inline void stage_half4(const unsigned short* __restrict__ srch,
                                   unsigned short* __restrict__ lds) {
  int l = threadIdx.x & 63;
  const unsigned short* s = srch + l * 8;
  gload16(s, lds);
  gload16(s + 512, lds + 512);
  gload16(s + 1024, lds + 1024);
  gload16(s + 1536, lds + 1536);
}

#define WVM0   asm volatile("s_waitcnt vmcnt(0)" ::: "memory")
#define WVM8   asm volatile("s_waitcnt vmcnt(8)" ::: "memory")
#define WVM24  asm volatile("s_waitcnt vmcnt(24)" ::: "memory")
#define WAIT_ALL  asm volatile("s_waitcnt vmcnt(0) lgkmcnt(0)" ::: "memory")
#define WAIT_LDS  asm volatile("s_waitcnt lgkmcnt(0)" ::: "memory")
#define SCHEDBAR  __builtin_amdgcn_sched_barrier(0)
#define BAR       __builtin_amdgcn_s_barrier()

// ---------------- MFMA cores ----------------

__device__ inline void mma16(const unsigned short* As, const unsigned short* Bs,
                             int wr, int wc, f32x4 acc[4][4]) {
  int l = threadIdx.x & 63;
  int lr = l & 15, lg = l >> 4;
  int qoff = ((lg ^ ((lr ^ (lr >> 2)) & 3)) << 3);
  short8 a[4], b[4];
#pragma unroll
  for (int m = 0; m < 4; m++)
    a[m] = *(const short8*)(As + (wr + m * 16 + lr) * 32 + qoff);
#pragma unroll
  for (int n = 0; n < 4; n++)
    b[n] = *(const short8*)(Bs + (wc + n * 16 + lr) * 32 + qoff);
#pragma unroll
  for (int m = 0; m < 4; m++)
#pragma unroll
    for (int n = 0; n < 4; n++)
      acc[m][n] = __builtin_amdgcn_mfma_f32_16x16x32_bf16(a[m], b[n], acc[m][n], 0, 0, 0);
}

// local-buffer (per-wave 64-row halves) variants
__device__ inline void mma16_loc(const unsigned short* As, const unsigned short* Bs,
                                 f32x4 acc[4][4]) {
  int l = threadIdx.x & 63;
  int lr = l & 15, lg = l >> 4;
  int qoff = ((lg ^ ((lr ^ (lr >> 2)) & 3)) << 3);
  short8 a[4], b[4];
#pragma unroll
  for (int m = 0; m < 4; m++)
    a[m] = *(const short8*)(As + (m * 16 + lr) * 32 + qoff);
#pragma unroll
  for (int n = 0; n < 4; n++)
    b[n] = *(const short8*)(Bs + (n * 16 + lr) * 32 + qoff);
#pragma unroll
  for (int m = 0; m < 4; m++)
#pragma unroll
    for (int n = 0; n < 4; n++)
      acc[m][n] = __builtin_amdgcn_mfma_f32_16x16x32_bf16(a[m], b[n], acc[m][n], 0, 0, 0);
}

__device__ inline void mma16_dualB_loc(const unsigned short* As, const unsigned short* Bs1,
                                       const unsigned short* Bs2,
                                       f32x4 acc1[4][4], f32x4 acc2[4][4]) {
  int l = threadIdx.x & 63;
  int lr = l & 15, lg = l >> 4;
  int qoff = ((lg ^ ((lr ^ (lr >> 2)) & 3)) << 3);
  short8 a[4], b1[4], b2[4];
#pragma unroll
  for (int m = 0; m < 4; m++)
    a[m] = *(const short8*)(As + (m * 16 + lr) * 32 + qoff);
#pragma unroll
  for (int n = 0; n < 4; n++) {
    b1[n] = *(const short8*)(Bs1 + (n * 16 + lr) * 32 + qoff);
    b2[n] = *(const short8*)(Bs2 + (n * 16 + lr) * 32 + qoff);
  }
#pragma unroll
  for (int m = 0; m < 4; m++)
#pragma unroll
    for (int n = 0; n < 4; n++) {
      acc1[m][n] = __builtin_amdgcn_mfma_f32_16x16x32_bf16(a[m], b1[n], acc1[m][n], 0, 0, 0);
      acc2[m][n] = __builtin_amdgcn_mfma_f32_16x16x32_bf16(a[m], b2[n], acc2[m][n], 0, 0, 0);
    }
}

__device__ inline void mma16_split_reg(const unsigned short* Ash, const unsigned short* Asl,
                                       const unsigned short* Bsh, const unsigned short* Bsl,
                                       int wr, int wc, f32x4 acc[4][4]) {
  int l = threadIdx.x & 63;
  int lr = l & 15, lg = l >> 4;
  int qoff = ((lg ^ ((lr ^ (lr >> 2)) & 3)) << 3);
  short8 ah[4], al[4], bh[4], bl[4];
#pragma unroll
  for (int m = 0; m < 4; m++) {
    ah[m] = *(const short8*)(Ash + (wr + m * 16 + lr) * 32 + qoff);
    al[m] = *(const short8*)(Asl + (wr + m * 16 + lr) * 32 + qoff);
  }
#pragma unroll
  for (int n = 0; n < 4; n++) {
    bh[n] = *(const short8*)(Bsh + (wc + n * 16 + lr) * 32 + qoff);
    bl[n] = *(const short8*)(Bsl + (wc + n * 16 + lr) * 32 + qoff);
  }
#pragma unroll
  for (int m = 0; m < 4; m++)
#pragma unroll
    for (int n = 0; n < 4; n++) {
      acc[m][n] = __builtin_amdgcn_mfma_f32_16x16x32_bf16(ah[m], bh[n], acc[m][n], 0, 0, 0);
      acc[m][n] = __builtin_amdgcn_mfma_f32_16x16x32_bf16(ah[m], bl[n], acc[m][n], 0, 0, 0);
      acc[m][n] = __builtin_amdgcn_mfma_f32_16x16x32_bf16(al[m], bh[n], acc[m][n], 0, 0, 0);
    }
}

// ---------------- pack kernels ----------------

__global__ __launch_bounds__(256) void k_pack1(const float* __restrict__ src, long ld,
                                               long zs, int nc,
                                               unsigned short* __restrict__ dst) {
  __shared__ float tile[32][132];
  const float* Sp = src + (long)blockIdx.z * zs;
  int c = blockIdx.x, t = threadIdx.x;
  for (int i = 0; i < 4; i++) {
    int kt = blockIdx.y * 4 + i;
    long k0 = (long)kt * 32, n0 = (long)c * 128;
    {
      int k = t >> 3, nn = (t & 7) * 16;
      const float4* p = (const float4*)(Sp + (k0 + k) * ld + n0 + nn);
#pragma unroll
      for (int j = 0; j < 4; j++) *(float4*)&tile[k][nn + j * 4] = p[j];
    }
    __syncthreads();
    size_t cbase = ((size_t)(blockIdx.z * nc + c) * 64 + kt) * 4096;
#pragma unroll
    for (int uu = 0; uu < 2; uu++) {
      int u = t * 2 + uu;
      int n = u >> 2, qp = u & 3;
      int q = qp ^ ((n ^ (n >> 2)) & 3);
      unsigned short hb[8] __attribute__((aligned(16)));
#pragma unroll
      for (int j = 0; j < 8; j++) hb[j] = f2bf(tile[8 * q + j][n]);
      *(uint4*)(dst + cbase + u * 8) = *(const uint4*)hb;
    }
    __syncthreads();
  }
}

__global__ __launch_bounds__(256) void k_pack2(const float* __restrict__ src, long ld,
                                               long zs, int nc,
                                               unsigned short* __restrict__ dh,
                                               unsigned short* __restrict__ dl) {
  __shared__ float tile[32][132];
  const float* Sp = src + (long)blockIdx.z * zs;
  int c = blockIdx.x, t = threadIdx.x;
  for (int i = 0; i < 4; i++) {
    int kt = blockIdx.y * 4 + i;
    long k0 = (long)kt * 32, n0 = (long)c * 128;
    {
      int k = t >> 3, nn = (t & 7) * 16;
      const float4* p = (const float4*)(Sp + (k0 + k) * ld + n0 + nn);
#pragma unroll
      for (int j = 0; j < 4; j++) *(float4*)&tile[k][nn + j * 4] = p[j];
    }
    __syncthreads();
    size_t cbase = ((size_t)(blockIdx.z * nc + c) * 64 + kt) * 4096;
#pragma unroll
    for (int uu = 0; uu < 2; uu++) {
      int u = t * 2 + uu;
      int n = u >> 2, qp = u & 3;
      int q = qp ^ ((n ^ (n >> 2)) & 3);
      unsigned short hb[8] __attribute__((aligned(16)));
      unsigned short lb[8] __attribute__((aligned(16)));
#pragma unroll
      for (int j = 0; j < 8; j++) split2(tile[8 * q + j][n], hb[j], lb[j]);
      *(uint4*)(dh + cbase + u * 8) = *(const uint4*)hb;
      *(uint4*)(dl + cbase + u * 8) = *(const uint4*)lb;
    }
    __syncthreads();
  }
}

__global__ __launch_bounds__(256) void k_packbf(const unsigned short* __restrict__ src,
                                                unsigned short* __restrict__ dst) {
  int ttile = blockIdx.x;
  int z = blockIdx.y;
  const unsigned short* Sp = src + ((size_t)z * S_LEN + (size_t)ttile * 128) * HD;
  size_t ob = ((size_t)z * 64 + (size_t)ttile * 4) * 4096;
  int t = threadIdx.x;
#pragma unroll
  for (int kst = 0; kst < 4; kst++) {
#pragma unroll
    for (int uu = 0; uu < 2; uu++) {
      int u = t * 2 + uu;
      int n = u >> 2, qp = u & 3;
      int q = qp ^ ((n ^ (n >> 2)) & 3);
      *(uint4*)(dst + ob + (size_t)kst * 4096 + u * 8) =
          *(const uint4*)(Sp + (size_t)n * HD + kst * 32 + q * 8);
    }
  }
}

__global__ __launch_bounds__(256) void k_gpack(const unsigned short* __restrict__ h2b,
                                               const int* __restrict__ ptok,
                                               const int* __restrict__ meta,
                                               unsigned short* __restrict__ hAP) {
  int ty = blockIdx.x;
  if (ty >= meta[25]) return;
  int tt = meta[26 + ty];
  int e = tt & 7, m0 = tt >> 3;
  int nvalid = min(128, meta[e] - m0);
  const int* toks = ptok + meta[16 + e] + m0;
  int t = threadIdx.x;
  int r = t >> 2, q = t & 3;
  int s = (r ^ (r >> 2)) & 3;
  for (int kt = blockIdx.y * 8; kt < blockIdx.y * 8 + 8; kt++) {
    unsigned short* dst = hAP + ((size_t)ty * 64 + kt) * 4096;
#pragma unroll
    for (int rr = 0; rr < 2; rr++) {
      int row = r + rr * 64;
      uint4 v = make_uint4(0, 0, 0, 0);
      if (row < nvalid)
        v = *(const uint4*)(h2b + (size_t)toks[row] * DMODEL + kt * 32 + q * 8);
      *(uint4*)(dst + row * 32 + ((q ^ s) << 3)) = v;
    }
  }
}

// ---------------- qkv / wo GEMMs (r10-proven 2-phase) ----------------

__global__ __launch_bounds__(256) void k_qkv_s(const unsigned short* __restrict__ APh,
                                               const unsigned short* __restrict__ APl,
                                               const unsigned short* __restrict__ BPh,
                                               const unsigned short* __restrict__ BPl,
                                               float* __restrict__ C) {
  __shared__ unsigned short Ash[2 * 4096], Asl[2 * 4096], Bsh[2 * 4096], Bsl[2 * 4096];
  size_t ab = (size_t)blockIdx.y * 64 * 4096;
  size_t cb = (size_t)blockIdx.x * 64 * 4096;
  int w = threadIdx.x >> 6;
  int wr = (w >> 1) * 64, wc = (w & 1) * 64;
  stageB_chunk(APh + ab, Ash);
  stageB_chunk(APl + ab, Asl);
  stageB_chunk(BPh + cb, Bsh);
  stageB_chunk(BPl + cb, Bsl);
  WAIT_ALL;
  BAR;
  f32x4 acc[4][4] = {};
  for (int kt = 0; kt < 64; kt++) {
    int cur = (kt & 1) << 12, nxt = 4096 - cur;
    if (kt + 1 < 64) {
      size_t o = (size_t)(kt + 1) * 4096;
      stageB_chunk(APh + ab + o, Ash + nxt);
      stageB_chunk(APl + ab + o, Asl + nxt);
      stageB_chunk(BPh + cb + o, Bsh + nxt);
      stageB_chunk(BPl + cb + o, Bsl + nxt);
    }
    SCHEDBAR;
    mma16_split_reg(Ash + cur, Asl + cur, Bsh + cur, Bsl + cur, wr, wc, acc);
    SCHEDBAR;
    WAIT_ALL;
    BAR;
  }
  int row0 = blockIdx.y * 128, col0 = blockIdx.x * 128;
  int l = threadIdx.x & 63;
  int er = wr + ((l >> 4) << 2), ec = wc + (l & 15);
#pragma unroll
  for (int m = 0; m < 4; m++)
#pragma unroll
    for (int n = 0; n < 4; n++)
#pragma unroll
      for (int r = 0; r < 4; r++) {
        float v = acc[m][n][r];
        v = fminf(fmaxf(v, -8.f), 8.f);
        C[(size_t)(row0 + er + m * 16 + r) * QKV_N + col0 + ec + n * 16] = v;
      }
}

__global__ __launch_bounds__(256) void k_wo_s(const unsigned short* __restrict__ APh,
                                              const unsigned short* __restrict__ APl,
                                              const unsigned short* __restrict__ BPh,
                                              const unsigned short* __restrict__ BPl,
                                              const float* __restrict__ resid,
                                              float* __restrict__ x1) {
  __shared__ unsigned short Ash[2 * 4096], Asl[2 * 4096], Bsh[2 * 4096], Bsl[2 * 4096];
  size_t ab = (size_t)blockIdx.y * 64 * 4096;
  size_t cb = (size_t)blockIdx.x * 64 * 4096;
  int w = threadIdx.x >> 6;
  int wr = (w >> 1) * 64, wc = (w & 1) * 64;
  stageB_chunk(APh + ab, Ash);
  stageB_chunk(APl + ab, Asl);
  stageB_chunk(BPh + cb, Bsh);
  stageB_chunk(BPl + cb, Bsl);
  WAIT_ALL;
  BAR;
  f32x4 acc[4][4] = {};
  for (int kt = 0; kt < 64; kt++) {
    int cur = (kt & 1) << 12, nxt = 4096 - cur;
    if (kt + 1 < 64) {
      size_t o = (size_t)(kt + 1) * 4096;
      stageB_chunk(APh + ab + o, Ash + nxt);
      stageB_chunk(APl + ab + o, Asl + nxt);
      stageB_chunk(BPh + cb + o, Bsh + nxt);
      stageB_chunk(BPl + cb + o, Bsl + nxt);
    }
    SCHEDBAR;
    mma16_split_reg(Ash + cur, Asl + cur, Bsh + cur, Bsl + cur, wr, wc, acc);
    SCHEDBAR;
    WAIT_ALL;
    BAR;
  }
  int row0 = blockIdx.y * 128, col0 = blockIdx.x * 128;
  int l = threadIdx.x & 63;
  int er = wr + ((l >> 4) << 2), ec = wc + (l & 15);
#pragma unroll
  for (int m = 0; m < 4; m++)
#pragma unroll
    for (int n = 0; n < 4; n++)
#pragma unroll
      for (int r = 0; r < 4; r++) {
        size_t idx = (size_t)(row0 + er + m * 16 + r) * DMODEL + col0 + ec + n * 16;
        x1[idx] = resid[idx] + acc[m][n][r];
      }
}

// ---------------- flash attention (r8-verified core; chunk-layout epilogue) ----------------

__global__ __launch_bounds__(128) void k_flash(const unsigned short* __restrict__ qh,
                                               const unsigned short* __restrict__ ql,
                                               const unsigned short* __restrict__ kPh,
                                               const unsigned short* __restrict__ kPl,
                                               const unsigned short* __restrict__ vPh,
                                               const unsigned short* __restrict__ vPl,
                                               unsigned short* __restrict__ atPh,
                                               unsigned short* __restrict__ atPl) {
  int bid = blockIdx.x;
  int h = (bid & 7) | ((bid >> 8) << 3);
  int rt = (bid >> 3) & 31;
  int kv = h >> 2;
  int ntiles = (rt >> 1) + 1;
  __shared__ float Pds[2][32 * 132];
  int t = threadIdx.x;
  int w = t >> 6, l = t & 63;
  int lr = l & 15, lg = l >> 4;
  int qoff = ((lg ^ ((lr ^ (lr >> 2)) & 3)) << 3);
  int wrow0 = rt * 64 + w * 32;
  const unsigned short* Qbh = qh + (size_t)h * S_LEN * HD;
  const unsigned short* Qbl = ql + (size_t)h * S_LEN * HD;
  const unsigned short* Kch = kPh + (size_t)kv * 64 * 4096;
  const unsigned short* Kcl = kPl + (size_t)kv * 64 * 4096;
  const unsigned short* Vch = vPh + (size_t)kv * 64 * 4096;
  const unsigned short* Vcl = vPl + (size_t)kv * 64 * 4096;
  float* Pw = &Pds[w][0];
  float mrun[2][4], lrun[2][4];
  f32x4 Oc[2][8];
#pragma unroll
  for (int m = 0; m < 2; m++)
#pragma unroll
    for (int r = 0; r < 4; r++) { mrun[m][r] = -3.4e38f; lrun[m][r] = 0.f; }
#pragma unroll
  for (int m = 0; m < 2; m++)
#pragma unroll
    for (int n = 0; n < 8; n++)
#pragma unroll
      for (int r = 0; r < 4; r++) Oc[m][n][r] = 0.f;
  const float scale = 0.08838834764831845f;

  for (int kt = 0; kt < ntiles; kt++) {
    f32x4 Sa[2][8];
#pragma unroll
    for (int m = 0; m < 2; m++)
#pragma unroll
      for (int n = 0; n < 8; n++)
#pragma unroll
        for (int r = 0; r < 4; r++) Sa[m][n][r] = 0.f;
#pragma unroll
    for (int kst = 0; kst < 4; kst++) {
      short8 qfh[2], qfl[2];
#pragma unroll
      for (int m = 0; m < 2; m++) {
        size_t o = (size_t)(wrow0 + m * 16 + lr) * HD + kst * 32 + lg * 8;
        qfh[m] = *(const short8*)(Qbh + o);
        qfl[m] = *(const short8*)(Qbl + o);
      }
      const unsigned short* Kh = Kch + (size_t)(kt * 4 + kst) * 4096;
      const unsigned short* Kl = Kcl + (size_t)(kt * 4 + kst) * 4096;
      short8 bh[8], bl[8];
#pragma unroll
      for (int n = 0; n < 8; n++) {
        bh[n] = *(const short8*)(Kh + (n * 16 + lr) * 32 + qoff);
        bl[n] = *(const short8*)(Kl + (n * 16 + lr) * 32 + qoff);
      }
#pragma unroll
      for (int m = 0; m < 2; m++)
#pragma unroll
        for (int n = 0; n < 8; n++) {
          Sa[m][n] = __builtin_amdgcn_mfma_f32_16x16x32_bf16(qfh[m], bh[n], Sa[m][n], 0, 0, 0);
          Sa[m][n] = __builtin_amdgcn_mfma_f32_16x16x32_bf16(qfh[m], bl[n], Sa[m][n], 0, 0, 0);
          Sa[m][n] = __builtin_amdgcn_mfma_f32_16x16x32_bf16(qfl[m], bh[n], Sa[m][n], 0, 0, 0);
        }
    }
#pragma unroll
    for (int m = 0; m < 2; m++)
#pragma unroll
      for (int r = 0; r < 4; r++) {
        int row = wrow0 + m * 16 + lg * 4 + r;
        float mx = mrun[m][r];
#pragma unroll
        for (int n = 0; n < 8; n++) {
          float v = Sa[m][n][r] * scale;
          int col = kt * 128 + n * 16 + lr;
          v = (col <= row) ? v : -3.4e38f;
          Sa[m][n][r] = v;
          mx = fmaxf(mx, v);
        }
        mx = fmaxf(mx, __shfl_xor(mx, 1));
        mx = fmaxf(mx, __shfl_xor(mx, 2));
        mx = fmaxf(mx, __shfl_xor(mx, 4));
        mx = fmaxf(mx, __shfl_xor(mx, 8));
        float al_ = expf(mrun[m][r] - mx);
        float sum = 0.f;
#pragma unroll
        for (int n = 0; n < 8; n++) {
          float v = Sa[m][n][r];
          float e = (v > -1.0e37f) ? expf(v - mx) : 0.f;
          Sa[m][n][r] = e;
          sum += e;
        }
        sum += __shfl_xor(sum, 1);
        sum += __shfl_xor(sum, 2);
        sum += __shfl_xor(sum, 4);
        sum += __shfl_xor(sum, 8);
        lrun[m][r] = lrun[m][r] * al_ + sum;
        mrun[m][r] = mx;
#pragma unroll
        for (int n = 0; n < 8; n++) Oc[m][n][r] *= al_;
      }
    WAIT_LDS;
    SCHEDBAR;
#pragma unroll
    for (int m = 0; m < 2; m++)
#pragma unroll
      for (int n = 0; n < 8; n++)
#pragma unroll
        for (int r = 0; r < 4; r++)
          Pw[(m * 16 + lg * 4 + r) * 132 + n * 16 + lr] = Sa[m][n][r];
    WAIT_LDS;
    SCHEDBAR;
#pragma unroll
    for (int kst = 0; kst < 4; kst++) {
      const unsigned short* Vh = Vch + (size_t)(kt * 4 + kst) * 4096;
      const unsigned short* Vl = Vcl + (size_t)(kt * 4 + kst) * 4096;
      short8 bh[8], bl[8];
#pragma unroll
      for (int n = 0; n < 8; n++) {
        bh[n] = *(const short8*)(Vh + (n * 16 + lr) * 32 + qoff);
        bl[n] = *(const short8*)(Vl + (n * 16 + lr) * 32 + qoff);
      }
#pragma unroll
      for (int m = 0; m < 2; m++) {
        const float* pp = &Pw[(m * 16 + lr) * 132 + kst * 32 + lg * 8];
        unsigned short ahb[8] __attribute__((aligned(16)));
        unsigned short alb[8] __attribute__((aligned(16)));
#pragma unroll
        for (int j = 0; j < 8; j++) split2(pp[j], ahb[j], alb[j]);
        short8 ah = *(const short8*)ahb;
        short8 al_ = *(const short8*)alb;
#pragma unroll
        for (int n = 0; n < 8; n++) {
          Oc[m][n] = __builtin_amdgcn_mfma_f32_16x16x32_bf16(ah, bh[n], Oc[m][n], 0, 0, 0);
          Oc[m][n] = __builtin_amdgcn_mfma_f32_16x16x32_bf16(ah, bl[n], Oc[m][n], 0, 0, 0);
          Oc[m][n] = __builtin_amdgcn_mfma_f32_16x16x32_bf16(al_, bh[n], Oc[m][n], 0, 0, 0);
        }
      }
    }
  }
#pragma unroll
  for (int m = 0; m < 2; m++)
#pragma unroll
    for (int r = 0; r < 4; r++) {
      int row = wrow0 + m * 16 + lg * 4 + r;
      int rtc = row >> 7, rl = row & 127;
      int sr = (rl ^ (rl >> 2)) & 3;
      float lv = lrun[m][r];
#pragma unroll
      for (int n = 0; n < 8; n++) {
        int col = h * HD + n * 16 + lr;
        size_t off = ((size_t)(rtc * 64 + (col >> 5))) * 4096 + rl * 32 +
                     ((((col & 31) >> 3) ^ sr) << 3) + (col & 7);
        unsigned short hh, ll;
        split2(Oc[m][n][r] / lv, hh, ll);
        atPh[off] = hh;
        atPl[off] = ll;
      }
    }
}

// ---------------- MoE GEMMs: BARRIER-FREE per-wave pipelines ----------------

// g(chunks) = silu(h2 @ w1[e]) * (h2 @ v1[e]); depth-3, no s_barrier in loop
__global__ __launch_bounds__(256) void k_moe1f(const unsigned short* __restrict__ hAP,
                                               const unsigned short* __restrict__ wPa,
                                               const unsigned short* __restrict__ wPb,
                                               const int* __restrict__ meta,
                                               unsigned short* __restrict__ g) {
  int ty = blockIdx.y;
  if (ty >= meta[25]) return;
  int tt = meta[26 + ty];
  int e = tt & 7, m0 = tt >> 3;
  int nvalid = min(128, meta[e] - m0);
  const unsigned short* Ab = hAP + (size_t)ty * 64 * 4096;
  const unsigned short* B1 = wPa + (size_t)(e * 16 + blockIdx.x) * 64 * 4096;
  const unsigned short* B2 = wPb + (size_t)(e * 16 + blockIdx.x) * 64 * 4096;
  __shared__ unsigned short L[4][3][3][2048];  // [wave][stream][buf][4KB] = 144KB
  int w = threadIdx.x >> 6;
  int wr = (w >> 1) * 64, wc = (w & 1) * 64;
  const unsigned short* Ah = Ab + wr * 32;   // this wave's A half (row offset)
  const unsigned short* B1h = B1 + wc * 32;  // this wave's B halves (col offset)
  const unsigned short* B2h = B2 + wc * 32;
  // prologue: steps 0,1,2 -> bufs 0,1,2
#pragma unroll
  for (int p = 0; p < 3; p++) {
    size_t o = (size_t)p * 4096;
    stage_half4(Ah + o, &L[w][0][p][0]);
    stage_half4(B1h + o, &L[w][1][p][0]);
    stage_half4(B2h + o, &L[w][2][p][0]);
  }
  WVM24;  // step 0 complete (steps 1,2 = 24 gloads in flight)
  SCHEDBAR;
  f32x4 acc1[4][4] = {}, acc2[4][4] = {};
  int cur = 0;
  for (int kt = 0; kt < 64; kt++) {
    mma16_dualB_loc(&L[w][0][cur][0], &L[w][1][cur][0], &L[w][2][cur][0], acc1, acc2);
    SCHEDBAR;  // keep gloads below the ds_reads above
    if (kt + 3 < 64) {
      size_t o = (size_t)(kt + 3) * 4096;
      stage_half4(Ah + o, &L[w][0][cur][0]);
      stage_half4(B1h + o, &L[w][1][cur][0]);
      stage_half4(B2h + o, &L[w][2][cur][0]);
      WVM24;  // step kt+1 complete; kt+2, kt+3 in flight
    } else {
      WVM0;
    }
    SCHEDBAR;
    cur = (cur == 2) ? 0 : cur + 1;
  }
  int l = threadIdx.x & 63;
  int er = wr + ((l >> 4) << 2), ec = wc + (l & 15);
  int ktf0 = blockIdx.x * 4;
#pragma unroll
  for (int m = 0; m < 4; m++)
#pragma unroll
    for (int n = 0; n < 4; n++)
#pragma unroll
      for (int r = 0; r < 4; r++) {
        int rl = er + m * 16 + r;
        int cc = ec + n * 16;
        float a = acc1[m][n][r];
        float s = a / (1.f + expf(-a));
        unsigned short val = (rl < nvalid) ? f2bf(s * acc2[m][n][r]) : (unsigned short)0;
        int srl = (rl ^ (rl >> 2)) & 3;
        g[((size_t)(ty * 64 + ktf0 + (cc >> 5))) * 4096 + rl * 32 +
          ((((cc & 31) >> 3) ^ srl) << 3) + (cc & 7)] = val;
      }
}

// out[tok] += gate * (g @ w2[e]); depth-2 per-wave, no s_barrier in loop
__global__ __launch_bounds__(256) void k_moe2(const unsigned short* __restrict__ gP,
                                              const unsigned short* __restrict__ wP,
                                              const int* __restrict__ ptok,
                                              const float* __restrict__ pw,
                                              const int* __restrict__ meta,
                                              float* __restrict__ out) {
  int ty = blockIdx.y;
  if (ty >= meta[25]) return;
  int tt = meta[26 + ty];
  int e = tt & 7, m0 = tt >> 3;
  int nvalid = min(128, meta[e] - m0);
  long pbase = (long)meta[16 + e] + m0;
  const unsigned short* Ab = gP + (size_t)ty * 64 * 4096;
  const unsigned short* Bb = wP + (size_t)(e * 16 + blockIdx.x) * 64 * 4096;
  __shared__ unsigned short L[4][2][2][2048];  // 64KB
  int w = threadIdx.x >> 6;
  int wr = (w >> 1) * 64, wc = (w & 1) * 64;
  const unsigned short* Ah = Ab + wr * 32;
  const unsigned short* Bh = Bb + wc * 32;
#pragma unroll
  for (int p = 0; p < 2; p++) {
    size_t o = (size_t)p * 4096;
    stage_half4(Ah + o, &L[w][0][p][0]);
    stage_half4(Bh + o, &L[w][1][p][0]);
  }
  WVM8;  // step 0 complete (step 1 = 8 gloads in flight)
  SCHEDBAR;
  f32x4 acc[4][4] = {};
  for (int kt = 0; kt < 64; kt++) {
    int cur = kt & 1;
    mma16_loc(&L[w][0][cur][0], &L[w][1][cur][0], acc);
    SCHEDBAR;
    if (kt + 2 < 64) {
      size_t o = (size_t)(kt + 2) * 4096;
      stage_half4(Ah + o, &L[w][0][cur][0]);
      stage_half4(Bh + o, &L[w][1][cur][0]);
      WVM8;  // step kt+1 complete
    } else {
      WVM0;
    }
    SCHEDBAR;
  }
  int col0 = blockIdx.x * 128;
  int l = threadIdx.x & 63;
  int er = wr + ((l >> 4) << 2), ec = wc + (l & 15);
#pragma unroll
  for (int m = 0; m < 4; m++)
#pragma unroll
    for (int n = 0; n < 4; n++)
#pragma unroll
      for (int r = 0; r < 4; r++) {
        int rl = er + m * 16 + r;
        if (rl < nvalid) {
          long p = pbase + rl;
          int tk = ptok[p];
          atomicAdd(&out[(size_t)tk * DMODEL + col0 + ec + n * 16], acc[m][n][r] * pw[p]);
        }
      }
}

// ---------------- small kernels ----------------

__global__ __launch_bounds__(256) void k_ln(const float* __restrict__ x,
                                            const float* __restrict__ w,
                                            unsigned short* __restrict__ obh,
                                            unsigned short* __restrict__ obl,
                                            float* __restrict__ of, int mode) {
  int row = blockIdx.x;
  const float* xr = x + (size_t)row * DMODEL;
  float s = 0.f, ss = 0.f;
  for (int c = threadIdx.x; c < DMODEL; c += 256) {
    float v = xr[c];
    s += v; ss += v * v;
  }
#pragma unroll
  for (int o = 32; o; o >>= 1) { s += __shfl_down(s, o); ss += __shfl_down(ss, o); }
  __shared__ float rs[4], rss[4], mu_s, inv_s;
  int wid = threadIdx.x >> 6;
  if ((threadIdx.x & 63) == 0) { rs[wid] = s; rss[wid] = ss; }
  __syncthreads();
  if (threadIdx.x == 0) {
    float S1 = rs[0] + rs[1] + rs[2] + rs[3];
    float S2 = rss[0] + rss[1] + rss[2] + rss[3];
    float mu = S1 / DMODEL;
    mu_s = mu;
    inv_s = rsqrtf(S2 / DMODEL - mu * mu + 1e-5f);
  }
  __syncthreads();
  float mu = mu_s, inv = inv_s;
  int rt = row >> 7, rl = row & 127;
  int sw = (rl ^ (rl >> 2)) & 3;
  for (int c = threadIdx.x; c < DMODEL; c += 256) {
    float v = (xr[c] - mu) * inv * w[c];
    unsigned short hh, ll;
    split2(v, hh, ll);
    if (mode) {
      size_t off = ((size_t)(rt * 64 + (c >> 5))) * 4096 + rl * 32 +
                   ((((c & 31) >> 3) ^ sw) << 3) + (c & 7);
      obh[off] = hh;
      obl[off] = ll;
    } else {
      obh[(size_t)row * DMODEL + c] = hh;
      obl[(size_t)row * DMODEL + c] = ll;
      of[(size_t)row * DMODEL + c] = v;
    }
  }
}

__global__ void k_rope2(const float* __restrict__ qkv, unsigned short* __restrict__ qh,
                        unsigned short* __restrict__ ql, unsigned short* __restrict__ kh,
                        unsigned short* __restrict__ kl) {
  int t = blockIdx.x;
  int d = threadIdx.x;
  float pf = (float)pow(500000.0, (double)d * (1.0 / 64.0));
  float invf = 1.0f / pf;
  float ang = (float)t * invf;
  float cs = (float)cos((double)ang);
  float sn = (float)sin((double)ang);
  const float* row = qkv + (size_t)t * QKV_N;
  unsigned short hh, ll;
#pragma unroll
  for (int hq = 0; hq < NH; hq++) {
    float a = row[hq * HD + d], b = row[hq * HD + d + 64];
    size_t base = ((size_t)hq * S_LEN + t) * HD;
    split2(a * cs - b * sn, hh, ll); qh[base + d] = hh; ql[base + d] = ll;
    split2(b * cs + a * sn, hh, ll); qh[base + d + 64] = hh; ql[base + d + 64] = ll;
  }
#pragma unroll
  for (int kv = 0; kv < NKV; kv++) {
    float a = row[NH * HD + kv * HD + d], b = row[NH * HD + kv * HD + d + 64];
    size_t base = ((size_t)kv * S_LEN + t) * HD;
    split2(a * cs - b * sn, hh, ll); kh[base + d] = hh; kl[base + d] = ll;
    split2(b * cs + a * sn, hh, ll); kh[base + d + 64] = hh; kl[base + d + 64] = ll;
  }
}

__global__ __launch_bounds__(256) void k_router(const float* __restrict__ h2,
                                                const float* __restrict__ rw,
                                                int* __restrict__ topi,
                                                float* __restrict__ topw,
                                                int* __restrict__ cnt) {
  int t = blockIdx.x;
  __shared__ float hs[DMODEL];
  __shared__ float lg[NE];
  for (int c = threadIdx.x; c < DMODEL; c += 256) hs[c] = h2[(size_t)t * DMODEL + c];
  __syncthreads();
  int grp = threadIdx.x >> 5;
  int ln = threadIdx.x & 31;
  float p = 0.f;
  for (int c = ln; c < DMODEL; c += 32) p += hs[c] * rw[(size_t)grp * DMODEL + c];
#pragma unroll
  for (int o = 16; o; o >>= 1) p += __shfl_down(p, o, 32);
  if (ln == 0) lg[grp] = p;
  __syncthreads();
  if (threadIdx.x == 0) {
    float l0 = -3.4e38f; int i0 = 0;
    for (int e = 0; e < NE; e++)
      if (lg[e] > l0) { l0 = lg[e]; i0 = e; }
    float l1 = -3.4e38f; int i1 = 0;
    for (int e = 0; e < NE; e++)
      if (e != i0 && lg[e] > l1) { l1 = lg[e]; i1 = e; }
    float z = expf(l1 - l0);
    topi[t * 2] = i0; topi[t * 2 + 1] = i1;
    topw[t * 2] = 1.f / (1.f + z); topw[t * 2 + 1] = z / (1.f + z);
    atomicAdd(&cnt[i0], 1);
    atomicAdd(&cnt[i1], 1);
  }
}

__global__ void k_scan(int* __restrict__ meta) {
  if (threadIdx.x == 0 && blockIdx.x == 0) {
    int o = 0, nt = 0;
    for (int e = 0; e < NE; e++) {
      meta[16 + e] = o;
      for (int m0 = 0; m0 < meta[e]; m0 += 128) meta[26 + nt++] = (m0 << 3) | e;
      o += meta[e];
    }
    meta[24] = o;
    meta[25] = nt;
  }
}

__global__ void k_fill(const int* __restrict__ topi, const float* __restrict__ topw,
                       int* __restrict__ meta, int* __restrict__ ptok,
                       float* __restrict__ pw) {
  int t = blockIdx.x * blockDim.x + threadIdx.x;
  if (t >= S_LEN) return;
#pragma unroll
  for (int j = 0; j < 2; j++) {
    int e = topi[t * 2 + j];
    int p = atomicAdd(&meta[8 + e], 1);
    ptok[meta[16 + e] + p] = t;
    pw[meta[16 + e] + p] = topw[t * 2 + j];
  }
}

// ---------------- launch ----------------

extern "C" void kernel_launch(void* const* d_in, const int* in_sizes, int n_in,
                              void* d_out, int out_size, void* d_ws, size_t ws_size,
                              hipStream_t stream) {
  (void)in_sizes; (void)n_in; (void)out_size; (void)ws_size;
  const float* x = (const float*)d_in[0];
  const float* ln1w = (const float*)d_in[2];
  const float* ln2w = (const float*)d_in[3];
  const float* wqkv = (const float*)d_in[4];
  const float* wo = (const float*)d_in[5];
  const float* rw = (const float*)d_in[6];
  const float* w1 = (const float*)d_in[7];
  const float* v1 = (const float*)d_in[8];
  const float* w2 = (const float*)d_in[9];
  float* out = (float*)d_out;  // x1 after k_wo_s; MoE adds in place

  char* wsb = (char*)d_ws;
  const size_t MiB = 1u << 20;
  // ---- attention phase ----
  unsigned short* h1Ph = (unsigned short*)(wsb + 0 * MiB);     // 8 (chunks)
  unsigned short* h1Pl = (unsigned short*)(wsb + 8 * MiB);     // 8
  float* qkvb = (float*)(wsb + 16 * MiB);                      // 24
  unsigned short* qh = (unsigned short*)(wsb + 40 * MiB);      // 8
  unsigned short* ql = (unsigned short*)(wsb + 48 * MiB);      // 8
  unsigned short* kh = (unsigned short*)(wsb + 56 * MiB);      // 2
  unsigned short* kl = (unsigned short*)(wsb + 58 * MiB);      // 2
  unsigned short* vPh = (unsigned short*)(wsb + 60 * MiB);     // 2
  unsigned short* vPl = (unsigned short*)(wsb + 62 * MiB);     // 2
  unsigned short* kPh = (unsigned short*)(wsb + 64 * MiB);     // 2
  unsigned short* kPl = (unsigned short*)(wsb + 66 * MiB);     // 2
  unsigned short* atPh = (unsigned short*)(wsb + 68 * MiB);    // 8 (chunks)
  unsigned short* atPl = (unsigned short*)(wsb + 76 * MiB);    // 8
  unsigned short* wqkvPh = (unsigned short*)(wsb + 84 * MiB);  // 12
  unsigned short* wqkvPl = (unsigned short*)(wsb + 96 * MiB);  // 12
  unsigned short* woPh = (unsigned short*)(wsb + 108 * MiB);   // 8
  unsigned short* woPl = (unsigned short*)(wsb + 116 * MiB);   // 8
  // ---- MoE phase (overlays) ----
  unsigned short* hAP = (unsigned short*)(wsb + 0 * MiB);      // 20 (over h1P)
  unsigned short* g = (unsigned short*)(wsb + 20 * MiB);       // 20 (over qkvb)
  float* h2f = (float*)(wsb + 40 * MiB);                       // 16 (over qh/ql)
  unsigned short* h2b = (unsigned short*)(wsb + 56 * MiB);     // 8 (over kh..vP)
  unsigned short* h2lo = (unsigned short*)(wsb + 20 * MiB);    // scratch (lo never read)
  unsigned short* wPa = (unsigned short*)(wsb + 40 * MiB);     // 64 (after router/gpack)
  unsigned short* wPb = (unsigned short*)(wsb + 104 * MiB);    // 64
  char* small = wsb + 168 * MiB;
  int* topi = (int*)small;
  float* topw = (float*)(small + 16384);
  int* ptok = (int*)(small + 32768);
  float* pw = (float*)(small + 49152);
  int* meta = (int*)(small + 65536);  // 128 ints

  // ---- pack attention weights ----
  k_pack2<<<dim3(QKV_N / 128, 16, 1), 256, 0, stream>>>(wqkv, QKV_N, 0, QKV_N / 128,
                                                        wqkvPh, wqkvPl);
  k_pack2<<<dim3(DMODEL / 128, 16, 1), 256, 0, stream>>>(wo, DMODEL, 0, DMODEL / 128,
                                                         woPh, woPl);

  // ---- attention sublayer (fp32-emulated) ----
  k_ln<<<S_LEN, 256, 0, stream>>>(x, ln1w, h1Ph, h1Pl, (float*)nullptr, 1);
  k_qkv_s<<<dim3(QKV_N / 128, S_LEN / 128), 256, 0, stream>>>(h1Ph, h1Pl, wqkvPh, wqkvPl,
                                                              qkvb);
  k_rope2<<<S_LEN, 64, 0, stream>>>(qkvb, qh, ql, kh, kl);
  k_pack2<<<dim3(1, 16, NKV), 256, 0, stream>>>(qkvb + (NH + NKV) * HD, QKV_N, HD, 1,
                                                vPh, vPl);
  k_packbf<<<dim3(16, NKV), 256, 0, stream>>>(kh, kPh);
  k_packbf<<<dim3(16, NKV), 256, 0, stream>>>(kl, kPl);
  k_flash<<<512, 128, 0, stream>>>(qh, ql, kPh, kPl, vPh, vPl, atPh, atPl);
  k_wo_s<<<dim3(16, 16), 256, 0, stream>>>(atPh, atPl, woPh, woPl, x, out);

  // ---- MoE sublayer ----
  k_ln<<<S_LEN, 256, 0, stream>>>(out, ln2w, h2b, h2lo, h2f, 0);
  hipMemsetAsync(meta, 0, 512, stream);
  k_router<<<S_LEN, 256, 0, stream>>>(h2f, rw, topi, topw, meta);
  k_scan<<<1, 64, 0, stream>>>(meta);
  k_fill<<<8, 256, 0, stream>>>(topi, topw, meta, ptok, pw);
  k_gpack<<<dim3(40, 8), 256, 0, stream>>>(h2b, ptok, meta, hAP);
  k_pack1<<<dim3(16, 16, NE), 256, 0, stream>>>(w1, FF, (long)DMODEL * FF, 16, wPa);
  k_pack1<<<dim3(16, 16, NE), 256, 0, stream>>>(v1, FF, (long)DMODEL * FF, 16, wPb);
  k_moe1f<<<dim3(16, 40), 256, 0, stream>>>(hAP, wPa, wPb, meta, g);
  k_pack1<<<dim3(16, 16, NE), 256, 0, stream>>>(w2, DMODEL, (long)FF * DMODEL, 16, wPa);
  k_moe2<<<dim3(16, 40), 256, 0, stream>>>(g, wPa, ptok, pw, meta, out);
}

// Round 13
// 917.627 us; speedup vs baseline: 1.0912x; 1.0576x over previous
//
#include <hip/hip_runtime.h>

#define S_LEN 2048
#define DMODEL 2048
#define NH 16
#define NKV 4
#define HD 128
#define NE 8
#define FF 2048
#define QKV_N 3072   // (H + 2*KV) * HD

typedef __attribute__((ext_vector_type(8))) short short8;
typedef __attribute__((ext_vector_type(4))) float f32x4;

__device__ inline unsigned short f2bf(float f) {
  unsigned int u = __builtin_bit_cast(unsigned int, f);
  u += 0x7fffu + ((u >> 16) & 1u);
  return (unsigned short)(u >> 16);
}
__device__ inline float bf2f(unsigned short h) {
  unsigned int u = ((unsigned int)h) << 16;
  return __builtin_bit_cast(float, u);
}
__device__ inline void split2(float v, unsigned short& h, unsigned short& l) {
  h = f2bf(v);
  l = f2bf(v - bf2f(h));
}

// ======== chunk format (verified r3-r12): 8KB = 128 rows x 32 k bf16 ========

__device__ inline void gload16(const void* g, void* l) {
  __builtin_amdgcn_global_load_lds((const __attribute__((address_space(1))) unsigned int*)g,
                                   (__attribute__((address_space(3))) unsigned int*)l,
                                   16, 0, 0);
}
__device__ inline void stageB_chunk(const unsigned short* __restrict__ chunk,
                                    unsigned short* __restrict__ lds) {
  int w = threadIdx.x >> 6, l = threadIdx.x & 63;
  const unsigned short* s = chunk + w * 1024 + l * 8;
  unsigned short* d = lds + w * 1024;
  gload16(s, d);
  gload16(s + 512, d + 512);
}

#define WVM0   asm volatile("s_waitcnt vmcnt(0)" ::: "memory")
#define WVM4   asm volatile("s_waitcnt vmcnt(4)" ::: "memory")
#define WVM6   asm volatile("s_waitcnt vmcnt(6)" ::: "memory")
#define WVM8   asm volatile("s_waitcnt vmcnt(8)" ::: "memory")
#define WVM12  asm volatile("s_waitcnt vmcnt(12)" ::: "memory")
#define WAIT_ALL  asm volatile("s_waitcnt vmcnt(0) lgkmcnt(0)" ::: "memory")
#define WAIT_LDS  asm volatile("s_waitcnt lgkmcnt(0)" ::: "memory")
#define SCHEDBAR  __builtin_amdgcn_sched_barrier(0)
#define BAR       __builtin_amdgcn_s_barrier()

// ---------------- MFMA cores ----------------

__device__ inline void mma16(const unsigned short* As, const unsigned short* Bs,
                             int wr, int wc, f32x4 acc[4][4]) {
  int l = threadIdx.x & 63;
  int lr = l & 15, lg = l >> 4;
  int qoff = ((lg ^ ((lr ^ (lr >> 2)) & 3)) << 3);
  short8 a[4], b[4];
#pragma unroll
  for (int m = 0; m < 4; m++)
    a[m] = *(const short8*)(As + (wr + m * 16 + lr) * 32 + qoff);
#pragma unroll
  for (int n = 0; n < 4; n++)
    b[n] = *(const short8*)(Bs + (wc + n * 16 + lr) * 32 + qoff);
#pragma unroll
  for (int m = 0; m < 4; m++)
#pragma unroll
    for (int n = 0; n < 4; n++)
      acc[m][n] = __builtin_amdgcn_mfma_f32_16x16x32_bf16(a[m], b[n], acc[m][n], 0, 0, 0);
}

__device__ inline void mma16_dualB(const unsigned short* As, const unsigned short* Bs1,
                                   const unsigned short* Bs2, int wr, int wc,
                                   f32x4 acc1[4][4], f32x4 acc2[4][4]) {
  int l = threadIdx.x & 63;
  int lr = l & 15, lg = l >> 4;
  int qoff = ((lg ^ ((lr ^ (lr >> 2)) & 3)) << 3);
  short8 a[4], b1[4], b2[4];
#pragma unroll
  for (int m = 0; m < 4; m++)
    a[m] = *(const short8*)(As + (wr + m * 16 + lr) * 32 + qoff);
#pragma unroll
  for (int n = 0; n < 4; n++) {
    b1[n] = *(const short8*)(Bs1 + (wc + n * 16 + lr) * 32 + qoff);
    b2[n] = *(const short8*)(Bs2 + (wc + n * 16 + lr) * 32 + qoff);
  }
#pragma unroll
  for (int m = 0; m < 4; m++)
#pragma unroll
    for (int n = 0; n < 4; n++) {
      acc1[m][n] = __builtin_amdgcn_mfma_f32_16x16x32_bf16(a[m], b1[n], acc1[m][n], 0, 0, 0);
      acc2[m][n] = __builtin_amdgcn_mfma_f32_16x16x32_bf16(a[m], b2[n], acc2[m][n], 0, 0, 0);
    }
}

__device__ inline void mma16_split_reg(const unsigned short* Ash, const unsigned short* Asl,
                                       const unsigned short* Bsh, const unsigned short* Bsl,
                                       int wr, int wc, f32x4 acc[4][4]) {
  int l = threadIdx.x & 63;
  int lr = l & 15, lg = l >> 4;
  int qoff = ((lg ^ ((lr ^ (lr >> 2)) & 3)) << 3);
  short8 ah[4], al[4], bh[4], bl[4];
#pragma unroll
  for (int m = 0; m < 4; m++) {
    ah[m] = *(const short8*)(Ash + (wr + m * 16 + lr) * 32 + qoff);
    al[m] = *(const short8*)(Asl + (wr + m * 16 + lr) * 32 + qoff);
  }
#pragma unroll
  for (int n = 0; n < 4; n++) {
    bh[n] = *(const short8*)(Bsh + (wc + n * 16 + lr) * 32 + qoff);
    bl[n] = *(const short8*)(Bsl + (wc + n * 16 + lr) * 32 + qoff);
  }
#pragma unroll
  for (int m = 0; m < 4; m++)
#pragma unroll
    for (int n = 0; n < 4; n++) {
      acc[m][n] = __builtin_amdgcn_mfma_f32_16x16x32_bf16(ah[m], bh[n], acc[m][n], 0, 0, 0);
      acc[m][n] = __builtin_amdgcn_mfma_f32_16x16x32_bf16(ah[m], bl[n], acc[m][n], 0, 0, 0);
      acc[m][n] = __builtin_amdgcn_mfma_f32_16x16x32_bf16(al[m], bh[n], acc[m][n], 0, 0, 0);
    }
}

// ---------------- pack kernels ----------------

__global__ __launch_bounds__(256) void k_pack1(const float* __restrict__ src, long ld,
                                               long zs, int nc,
                                               unsigned short* __restrict__ dst) {
  __shared__ float tile[32][132];
  const float* Sp = src + (long)blockIdx.z * zs;
  int c = blockIdx.x, t = threadIdx.x;
  for (int i = 0; i < 4; i++) {
    int kt = blockIdx.y * 4 + i;
    long k0 = (long)kt * 32, n0 = (long)c * 128;
    {
      int k = t >> 3, nn = (t & 7) * 16;
      const float4* p = (const float4*)(Sp + (k0 + k) * ld + n0 + nn);
#pragma unroll
      for (int j = 0; j < 4; j++) *(float4*)&tile[k][nn + j * 4] = p[j];
    }
    __syncthreads();
    size_t cbase = ((size_t)(blockIdx.z * nc + c) * 64 + kt) * 4096;
#pragma unroll
    for (int uu = 0; uu < 2; uu++) {
      int u = t * 2 + uu;
      int n = u >> 2, qp = u & 3;
      int q = qp ^ ((n ^ (n >> 2)) & 3);
      unsigned short hb[8] __attribute__((aligned(16)));
#pragma unroll
      for (int j = 0; j < 8; j++) hb[j] = f2bf(tile[8 * q + j][n]);
      *(uint4*)(dst + cbase + u * 8) = *(const uint4*)hb;
    }
    __syncthreads();
  }
}

__global__ __launch_bounds__(256) void k_pack2(const float* __restrict__ src, long ld,
                                               long zs, int nc,
                                               unsigned short* __restrict__ dh,
                                               unsigned short* __restrict__ dl) {
  __shared__ float tile[32][132];
  const float* Sp = src + (long)blockIdx.z * zs;
  int c = blockIdx.x, t = threadIdx.x;
  for (int i = 0; i < 4; i++) {
    int kt = blockIdx.y * 4 + i;
    long k0 = (long)kt * 32, n0 = (long)c * 128;
    {
      int k = t >> 3, nn = (t & 7) * 16;
      const float4* p = (const float4*)(Sp + (k0 + k) * ld + n0 + nn);
#pragma unroll
      for (int j = 0; j < 4; j++) *(float4*)&tile[k][nn + j * 4] = p[j];
    }
    __syncthreads();
    size_t cbase = ((size_t)(blockIdx.z * nc + c) * 64 + kt) * 4096;
#pragma unroll
    for (int uu = 0; uu < 2; uu++) {
      int u = t * 2 + uu;
      int n = u >> 2, qp = u & 3;
      int q = qp ^ ((n ^ (n >> 2)) & 3);
      unsigned short hb[8] __attribute__((aligned(16)));
      unsigned short lb[8] __attribute__((aligned(16)));
#pragma unroll
      for (int j = 0; j < 8; j++) split2(tile[8 * q + j][n], hb[j], lb[j]);
      *(uint4*)(dh + cbase + u * 8) = *(const uint4*)hb;
      *(uint4*)(dl + cbase + u * 8) = *(const uint4*)lb;
    }
    __syncthreads();
  }
}

__global__ __launch_bounds__(256) void k_packbf(const unsigned short* __restrict__ src,
                                                unsigned short* __restrict__ dst) {
  int ttile = blockIdx.x;
  int z = blockIdx.y;
  const unsigned short* Sp = src + ((size_t)z * S_LEN + (size_t)ttile * 128) * HD;
  size_t ob = ((size_t)z * 64 + (size_t)ttile * 4) * 4096;
  int t = threadIdx.x;
#pragma unroll
  for (int kst = 0; kst < 4; kst++) {
#pragma unroll
    for (int uu = 0; uu < 2; uu++) {
      int u = t * 2 + uu;
      int n = u >> 2, qp = u & 3;
      int q = qp ^ ((n ^ (n >> 2)) & 3);
      *(uint4*)(dst + ob + (size_t)kst * 4096 + u * 8) =
          *(const uint4*)(Sp + (size_t)n * HD + kst * 32 + q * 8);
    }
  }
}

__global__ __launch_bounds__(256) void k_gpack(const unsigned short* __restrict__ h2b,
                                               const int* __restrict__ ptok,
                                               const int* __restrict__ meta,
                                               unsigned short* __restrict__ hAP) {
  int ty = blockIdx.x;
  if (ty >= meta[25]) return;
  int tt = meta[26 + ty];
  int e = tt & 7, m0 = tt >> 3;
  int nvalid = min(128, meta[e] - m0);
  const int* toks = ptok + meta[16 + e] + m0;
  int t = threadIdx.x;
  int r = t >> 2, q = t & 3;
  int s = (r ^ (r >> 2)) & 3;
  for (int kt = blockIdx.y * 8; kt < blockIdx.y * 8 + 8; kt++) {
    unsigned short* dst = hAP + ((size_t)ty * 64 + kt) * 4096;
#pragma unroll
    for (int rr = 0; rr < 2; rr++) {
      int row = r + rr * 64;
      uint4 v = make_uint4(0, 0, 0, 0);
      if (row < nvalid)
        v = *(const uint4*)(h2b + (size_t)toks[row] * DMODEL + kt * 32 + q * 8);
      *(uint4*)(dst + row * 32 + ((q ^ s) << 3)) = v;
    }
  }
}

// ---------------- qkv / wo GEMMs (r10-proven 2-phase) ----------------

__global__ __launch_bounds__(256) void k_qkv_s(const unsigned short* __restrict__ APh,
                                               const unsigned short* __restrict__ APl,
                                               const unsigned short* __restrict__ BPh,
                                               const unsigned short* __restrict__ BPl,
                                               float* __restrict__ C) {
  __shared__ unsigned short Ash[2 * 4096], Asl[2 * 4096], Bsh[2 * 4096], Bsl[2 * 4096];
  size_t ab = (size_t)blockIdx.y * 64 * 4096;
  size_t cb = (size_t)blockIdx.x * 64 * 4096;
  int w = threadIdx.x >> 6;
  int wr = (w >> 1) * 64, wc = (w & 1) * 64;
  stageB_chunk(APh + ab, Ash);
  stageB_chunk(APl + ab, Asl);
  stageB_chunk(BPh + cb, Bsh);
  stageB_chunk(BPl + cb, Bsl);
  WAIT_ALL;
  BAR;
  f32x4 acc[4][4] = {};
  for (int kt = 0; kt < 64; kt++) {
    int cur = (kt & 1) << 12, nxt = 4096 - cur;
    if (kt + 1 < 64) {
      size_t o = (size_t)(kt + 1) * 4096;
      stageB_chunk(APh + ab + o, Ash + nxt);
      stageB_chunk(APl + ab + o, Asl + nxt);
      stageB_chunk(BPh + cb + o, Bsh + nxt);
      stageB_chunk(BPl + cb + o, Bsl + nxt);
    }
    SCHEDBAR;
    mma16_split_reg(Ash + cur, Asl + cur, Bsh + cur, Bsl + cur, wr, wc, acc);
    SCHEDBAR;
    WAIT_ALL;
    BAR;
  }
  int row0 = blockIdx.y * 128, col0 = blockIdx.x * 128;
  int l = threadIdx.x & 63;
  int er = wr + ((l >> 4) << 2), ec = wc + (l & 15);
#pragma unroll
  for (int m = 0; m < 4; m++)
#pragma unroll
    for (int n = 0; n < 4; n++)
#pragma unroll
      for (int r = 0; r < 4; r++) {
        float v = acc[m][n][r];
        v = fminf(fmaxf(v, -8.f), 8.f);
        C[(size_t)(row0 + er + m * 16 + r) * QKV_N + col0 + ec + n * 16] = v;
      }
}

__global__ __launch_bounds__(256) void k_wo_s(const unsigned short* __restrict__ APh,
                                              const unsigned short* __restrict__ APl,
                                              const unsigned short* __restrict__ BPh,
                                              const unsigned short* __restrict__ BPl,
                                              const float* __restrict__ resid,
                                              float* __restrict__ x1) {
  __shared__ unsigned short Ash[2 * 4096], Asl[2 * 4096], Bsh[2 * 4096], Bsl[2 * 4096];
  size_t ab = (size_t)blockIdx.y * 64 * 4096;
  size_t cb = (size_t)blockIdx.x * 64 * 4096;
  int w = threadIdx.x >> 6;
  int wr = (w >> 1) * 64, wc = (w & 1) * 64;
  stageB_chunk(APh + ab, Ash);
  stageB_chunk(APl + ab, Asl);
  stageB_chunk(BPh + cb, Bsh);
  stageB_chunk(BPl + cb, Bsl);
  WAIT_ALL;
  BAR;
  f32x4 acc[4][4] = {};
  for (int kt = 0; kt < 64; kt++) {
    int cur = (kt & 1) << 12, nxt = 4096 - cur;
    if (kt + 1 < 64) {
      size_t o = (size_t)(kt + 1) * 4096;
      stageB_chunk(APh + ab + o, Ash + nxt);
      stageB_chunk(APl + ab + o, Asl + nxt);
      stageB_chunk(BPh + cb + o, Bsh + nxt);
      stageB_chunk(BPl + cb + o, Bsl + nxt);
    }
    SCHEDBAR;
    mma16_split_reg(Ash + cur, Asl + cur, Bsh + cur, Bsl + cur, wr, wc, acc);
    SCHEDBAR;
    WAIT_ALL;
    BAR;
  }
  int row0 = blockIdx.y * 128, col0 = blockIdx.x * 128;
  int l = threadIdx.x & 63;
  int er = wr + ((l >> 4) << 2), ec = wc + (l & 15);
#pragma unroll
  for (int m = 0; m < 4; m++)
#pragma unroll
    for (int n = 0; n < 4; n++)
#pragma unroll
      for (int r = 0; r < 4; r++) {
        size_t idx = (size_t)(row0 + er + m * 16 + r) * DMODEL + col0 + ec + n * 16;
        x1[idx] = resid[idx] + acc[m][n][r];
      }
}

// ---------------- flash attention (r8-verified core; chunk-layout epilogue) ----------------

__global__ __launch_bounds__(128) void k_flash(const unsigned short* __restrict__ qh,
                                               const unsigned short* __restrict__ ql,
                                               const unsigned short* __restrict__ kPh,
                                               const unsigned short* __restrict__ kPl,
                                               const unsigned short* __restrict__ vPh,
                                               const unsigned short* __restrict__ vPl,
                                               unsigned short* __restrict__ atPh,
                                               unsigned short* __restrict__ atPl) {
  int bid = blockIdx.x;
  int h = (bid & 7) | ((bid >> 8) << 3);
  int rt = (bid >> 3) & 31;
  int kv = h >> 2;
  int ntiles = (rt >> 1) + 1;
  __shared__ float Pds[2][32 * 132];
  int t = threadIdx.x;
  int w = t >> 6, l = t & 63;
  int lr = l & 15, lg = l >> 4;
  int qoff = ((lg ^ ((lr ^ (lr >> 2)) & 3)) << 3);
  int wrow0 = rt * 64 + w * 32;
  const unsigned short* Qbh = qh + (size_t)h * S_LEN * HD;
  const unsigned short* Qbl = ql + (size_t)h * S_LEN * HD;
  const unsigned short* Kch = kPh + (size_t)kv * 64 * 4096;
  const unsigned short* Kcl = kPl + (size_t)kv * 64 * 4096;
  const unsigned short* Vch = vPh + (size_t)kv * 64 * 4096;
  const unsigned short* Vcl = vPl + (size_t)kv * 64 * 4096;
  float* Pw = &Pds[w][0];
  float mrun[2][4], lrun[2][4];
  f32x4 Oc[2][8];
#pragma unroll
  for (int m = 0; m < 2; m++)
#pragma unroll
    for (int r = 0; r < 4; r++) { mrun[m][r] = -3.4e38f; lrun[m][r] = 0.f; }
#pragma unroll
  for (int m = 0; m < 2; m++)
#pragma unroll
    for (int n = 0; n < 8; n++)
#pragma unroll
      for (int r = 0; r < 4; r++) Oc[m][n][r] = 0.f;
  const float scale = 0.08838834764831845f;

  for (int kt = 0; kt < ntiles; kt++) {
    f32x4 Sa[2][8];
#pragma unroll
    for (int m = 0; m < 2; m++)
#pragma unroll
      for (int n = 0; n < 8; n++)
#pragma unroll
        for (int r = 0; r < 4; r++) Sa[m][n][r] = 0.f;
#pragma unroll
    for (int kst = 0; kst < 4; kst++) {
      short8 qfh[2], qfl[2];
#pragma unroll
      for (int m = 0; m < 2; m++) {
        size_t o = (size_t)(wrow0 + m * 16 + lr) * HD + kst * 32 + lg * 8;
        qfh[m] = *(const short8*)(Qbh + o);
        qfl[m] = *(const short8*)(Qbl + o);
      }
      const unsigned short* Kh = Kch + (size_t)(kt * 4 + kst) * 4096;
      const unsigned short* Kl = Kcl + (size_t)(kt * 4 + kst) * 4096;
      short8 bh[8], bl[8];
#pragma unroll
      for (int n = 0; n < 8; n++) {
        bh[n] = *(const short8*)(Kh + (n * 16 + lr) * 32 + qoff);
        bl[n] = *(const short8*)(Kl + (n * 16 + lr) * 32 + qoff);
      }
#pragma unroll
      for (int m = 0; m < 2; m++)
#pragma unroll
        for (int n = 0; n < 8; n++) {
          Sa[m][n] = __builtin_amdgcn_mfma_f32_16x16x32_bf16(qfh[m], bh[n], Sa[m][n], 0, 0, 0);
          Sa[m][n] = __builtin_amdgcn_mfma_f32_16x16x32_bf16(qfh[m], bl[n], Sa[m][n], 0, 0, 0);
          Sa[m][n] = __builtin_amdgcn_mfma_f32_16x16x32_bf16(qfl[m], bh[n], Sa[m][n], 0, 0, 0);
        }
    }
#pragma unroll
    for (int m = 0; m < 2; m++)
#pragma unroll
      for (int r = 0; r < 4; r++) {
        int row = wrow0 + m * 16 + lg * 4 + r;
        float mx = mrun[m][r];
#pragma unroll
        for (int n = 0; n < 8; n++) {
          float v = Sa[m][n][r] * scale;
          int col = kt * 128 + n * 16 + lr;
          v = (col <= row) ? v : -3.4e38f;
          Sa[m][n][r] = v;
          mx = fmaxf(mx, v);
        }
        mx = fmaxf(mx, __shfl_xor(mx, 1));
        mx = fmaxf(mx, __shfl_xor(mx, 2));
        mx = fmaxf(mx, __shfl_xor(mx, 4));
        mx = fmaxf(mx, __shfl_xor(mx, 8));
        float al_ = expf(mrun[m][r] - mx);
        float sum = 0.f;
#pragma unroll
        for (int n = 0; n < 8; n++) {
          float v = Sa[m][n][r];
          float e = (v > -1.0e37f) ? expf(v - mx) : 0.f;
          Sa[m][n][r] = e;
          sum += e;
        }
        sum += __shfl_xor(sum, 1);
        sum += __shfl_xor(sum, 2);
        sum += __shfl_xor(sum, 4);
        sum += __shfl_xor(sum, 8);
        lrun[m][r] = lrun[m][r] * al_ + sum;
        mrun[m][r] = mx;
#pragma unroll
        for (int n = 0; n < 8; n++) Oc[m][n][r] *= al_;
      }
    WAIT_LDS;
    SCHEDBAR;
#pragma unroll
    for (int m = 0; m < 2; m++)
#pragma unroll
      for (int n = 0; n < 8; n++)
#pragma unroll
        for (int r = 0; r < 4; r++)
          Pw[(m * 16 + lg * 4 + r) * 132 + n * 16 + lr] = Sa[m][n][r];
    WAIT_LDS;
    SCHEDBAR;
#pragma unroll
    for (int kst = 0; kst < 4; kst++) {
      const unsigned short* Vh = Vch + (size_t)(kt * 4 + kst) * 4096;
      const unsigned short* Vl = Vcl + (size_t)(kt * 4 + kst) * 4096;
      short8 bh[8], bl[8];
#pragma unroll
      for (int n = 0; n < 8; n++) {
        bh[n] = *(const short8*)(Vh + (n * 16 + lr) * 32 + qoff);
        bl[n] = *(const short8*)(Vl + (n * 16 + lr) * 32 + qoff);
      }
#pragma unroll
      for (int m = 0; m < 2; m++) {
        const float* pp = &Pw[(m * 16 + lr) * 132 + kst * 32 + lg * 8];
        unsigned short ahb[8] __attribute__((aligned(16)));
        unsigned short alb[8] __attribute__((aligned(16)));
#pragma unroll
        for (int j = 0; j < 8; j++) split2(pp[j], ahb[j], alb[j]);
        short8 ah = *(const short8*)ahb;
        short8 al_ = *(const short8*)alb;
#pragma unroll
        for (int n = 0; n < 8; n++) {
          Oc[m][n] = __builtin_amdgcn_mfma_f32_16x16x32_bf16(ah, bh[n], Oc[m][n], 0, 0, 0);
          Oc[m][n] = __builtin_amdgcn_mfma_f32_16x16x32_bf16(ah, bl[n], Oc[m][n], 0, 0, 0);
          Oc[m][n] = __builtin_amdgcn_mfma_f32_16x16x32_bf16(al_, bh[n], Oc[m][n], 0, 0, 0);
        }
      }
    }
  }
#pragma unroll
  for (int m = 0; m < 2; m++)
#pragma unroll
    for (int r = 0; r < 4; r++) {
      int row = wrow0 + m * 16 + lg * 4 + r;
      int rtc = row >> 7, rl = row & 127;
      int sr = (rl ^ (rl >> 2)) & 3;
      float lv = lrun[m][r];
#pragma unroll
      for (int n = 0; n < 8; n++) {
        int col = h * HD + n * 16 + lr;
        size_t off = ((size_t)(rtc * 64 + (col >> 5))) * 4096 + rl * 32 +
                     ((((col & 31) >> 3) ^ sr) << 3) + (col & 7);
        unsigned short hh, ll;
        split2(Oc[m][n][r] / lv, hh, ll);
        atPh[off] = hh;
        atPl[off] = ll;
      }
    }
}

// ---------------- MoE GEMMs: depth-3 block-cooperative counted-vmcnt ----------------

__global__ __launch_bounds__(256) void k_moe1f(const unsigned short* __restrict__ hAP,
                                               const unsigned short* __restrict__ wPa,
                                               const unsigned short* __restrict__ wPb,
                                               const int* __restrict__ meta,
                                               unsigned short* __restrict__ g) {
  int ty = blockIdx.y;
  if (ty >= meta[25]) return;
  int tt = meta[26 + ty];
  int e = tt & 7, m0 = tt >> 3;
  int nvalid = min(128, meta[e] - m0);
  const unsigned short* Ab = hAP + (size_t)ty * 64 * 4096;
  const unsigned short* B1 = wPa + (size_t)(e * 16 + blockIdx.x) * 64 * 4096;
  const unsigned short* B2 = wPb + (size_t)(e * 16 + blockIdx.x) * 64 * 4096;
  __shared__ unsigned short L[3][3][4096];  // 72KB
  int w = threadIdx.x >> 6;
  int wr = (w >> 1) * 64, wc = (w & 1) * 64;
#pragma unroll
  for (int p = 0; p < 3; p++) {
    size_t o = (size_t)p * 4096;
    stageB_chunk(Ab + o, &L[p][0][0]);
    stageB_chunk(B1 + o, &L[p][1][0]);
    stageB_chunk(B2 + o, &L[p][2][0]);
  }
  WVM12;
  BAR;
  f32x4 acc1[4][4] = {}, acc2[4][4] = {};
  int cur = 0;
  for (int kt = 0; kt < 64; kt++) {
    SCHEDBAR;
    mma16_dualB(&L[cur][0][0], &L[cur][1][0], &L[cur][2][0], wr, wc, acc1, acc2);
    SCHEDBAR;
    BAR;
    if (kt + 3 < 64) {
      size_t o = (size_t)(kt + 3) * 4096;
      stageB_chunk(Ab + o, &L[cur][0][0]);
      stageB_chunk(B1 + o, &L[cur][1][0]);
      stageB_chunk(B2 + o, &L[cur][2][0]);
      WVM12;
    } else if (kt + 3 == 64) {
      WVM6;
    } else {
      WVM0;
    }
    BAR;
    cur = (cur == 2) ? 0 : cur + 1;
  }
  int l = threadIdx.x & 63;
  int er = wr + ((l >> 4) << 2), ec = wc + (l & 15);
  int ktf0 = blockIdx.x * 4;
#pragma unroll
  for (int m = 0; m < 4; m++)
#pragma unroll
    for (int n = 0; n < 4; n++)
#pragma unroll
      for (int r = 0; r < 4; r++) {
        int rl = er + m * 16 + r;
        int cc = ec + n * 16;
        float a = acc1[m][n][r];
        float s = a / (1.f + expf(-a));
        unsigned short val = (rl < nvalid) ? f2bf(s * acc2[m][n][r]) : (unsigned short)0;
        int srl = (rl ^ (rl >> 2)) & 3;
        g[((size_t)(ty * 64 + ktf0 + (cc >> 5))) * 4096 + rl * 32 +
          ((((cc & 31) >> 3) ^ srl) << 3) + (cc & 7)] = val;
      }
}

__global__ __launch_bounds__(256) void k_moe2(const unsigned short* __restrict__ gP,
                                              const unsigned short* __restrict__ wP,
                                              const int* __restrict__ ptok,
                                              const float* __restrict__ pw,
                                              const int* __restrict__ meta,
                                              float* __restrict__ out) {
  int ty = blockIdx.y;
  if (ty >= meta[25]) return;
  int tt = meta[26 + ty];
  int e = tt & 7, m0 = tt >> 3;
  int nvalid = min(128, meta[e] - m0);
  long pbase = (long)meta[16 + e] + m0;
  int kc = blockIdx.z;
  const unsigned short* Ab = gP + ((size_t)ty * 64 + kc * 32) * 4096;
  const unsigned short* Bb = wP + ((size_t)(e * 16 + blockIdx.x) * 64 + kc * 32) * 4096;
  __shared__ unsigned short L[3][2][4096];  // 48KB
  int w = threadIdx.x >> 6;
  int wr = (w >> 1) * 64, wc = (w & 1) * 64;
#pragma unroll
  for (int p = 0; p < 3; p++) {
    size_t o = (size_t)p * 4096;
    stageB_chunk(Ab + o, &L[p][0][0]);
    stageB_chunk(Bb + o, &L[p][1][0]);
  }
  WVM8;
  BAR;
  f32x4 acc[4][4] = {};
  int cur = 0;
  for (int kt = 0; kt < 32; kt++) {
    SCHEDBAR;
    mma16(&L[cur][0][0], &L[cur][1][0], wr, wc, acc);
    SCHEDBAR;
    BAR;
    if (kt + 3 < 32) {
      size_t o = (size_t)(kt + 3) * 4096;
      stageB_chunk(Ab + o, &L[cur][0][0]);
      stageB_chunk(Bb + o, &L[cur][1][0]);
      WVM8;
    } else if (kt + 3 == 32) {
      WVM4;
    } else {
      WVM0;
    }
    BAR;
    cur = (cur == 2) ? 0 : cur + 1;
  }
  int col0 = blockIdx.x * 128;
  int l = threadIdx.x & 63;
  int er = wr + ((l >> 4) << 2), ec = wc + (l & 15);
#pragma unroll
  for (int m = 0; m < 4; m++)
#pragma unroll
    for (int n = 0; n < 4; n++)
#pragma unroll
      for (int r = 0; r < 4; r++) {
        int rl = er + m * 16 + r;
        if (rl < nvalid) {
          long p = pbase + rl;
          int tk = ptok[p];
          atomicAdd(&out[(size_t)tk * DMODEL + col0 + ec + n * 16], acc[m][n][r] * pw[p]);
        }
      }
}

// ---------------- small kernels ----------------

__global__ __launch_bounds__(256) void k_ln(const float* __restrict__ x,
                                            const float* __restrict__ w,
                                            unsigned short* __restrict__ obh,
                                            unsigned short* __restrict__ obl,
                                            float* __restrict__ of, int mode) {
  int row = blockIdx.x;
  const float* xr = x + (size_t)row * DMODEL;
  float s = 0.f, ss = 0.f;
  for (int c = threadIdx.x; c < DMODEL; c += 256) {
    float v = xr[c];
    s += v; ss += v * v;
  }
#pragma unroll
  for (int o = 32; o; o >>= 1) { s += __shfl_down(s, o); ss += __shfl_down(ss, o); }
  __shared__ float rs[4], rss[4], mu_s, inv_s;
  int wid = threadIdx.x >> 6;
  if ((threadIdx.x & 63) == 0) { rs[wid] = s; rss[wid] = ss; }
  __syncthreads();
  if (threadIdx.x == 0) {
    float S1 = rs[0] + rs[1] + rs[2] + rs[3];
    float S2 = rss[0] + rss[1] + rss[2] + rss[3];
    float mu = S1 / DMODEL;
    mu_s = mu;
    inv_s = rsqrtf(S2 / DMODEL - mu * mu + 1e-5f);
  }
  __syncthreads();
  float mu = mu_s, inv = inv_s;
  int rt = row >> 7, rl = row & 127;
  int sw = (rl ^ (rl >> 2)) & 3;
  for (int c = threadIdx.x; c < DMODEL; c += 256) {
    float v = (xr[c] - mu) * inv * w[c];
    unsigned short hh, ll;
    split2(v, hh, ll);
    if (mode) {
      size_t off = ((size_t)(rt * 64 + (c >> 5))) * 4096 + rl * 32 +
                   ((((c & 31) >> 3) ^ sw) << 3) + (c & 7);
      obh[off] = hh;
      obl[off] = ll;
    } else {
      obh[(size_t)row * DMODEL + c] = hh;
      obl[(size_t)row * DMODEL + c] = ll;
      of[(size_t)row * DMODEL + c] = v;
    }
  }
}

__global__ void k_rope2(const float* __restrict__ qkv, unsigned short* __restrict__ qh,
                        unsigned short* __restrict__ ql, unsigned short* __restrict__ kh,
                        unsigned short* __restrict__ kl) {
  int t = blockIdx.x;
  int d = threadIdx.x;
  float pf = (float)pow(500000.0, (double)d * (1.0 / 64.0));
  float invf = 1.0f / pf;
  float ang = (float)t * invf;
  float cs = (float)cos((double)ang);
  float sn = (float)sin((double)ang);
  const float* row = qkv + (size_t)t * QKV_N;
  unsigned short hh, ll;
#pragma unroll
  for (int hq = 0; hq < NH; hq++) {
    float a = row[hq * HD + d], b = row[hq * HD + d + 64];
    size_t base = ((size_t)hq * S_LEN + t) * HD;
    split2(a * cs - b * sn, hh, ll); qh[base + d] = hh; ql[base + d] = ll;
    split2(b * cs + a * sn, hh, ll); qh[base + d + 64] = hh; ql[base + d + 64] = ll;
  }
#pragma unroll
  for (int kv = 0; kv < NKV; kv++) {
    float a = row[NH * HD + kv * HD + d], b = row[NH * HD + kv * HD + d + 64];
    size_t base = ((size_t)kv * S_LEN + t) * HD;
    split2(a * cs - b * sn, hh, ll); kh[base + d] = hh; kl[base + d] = ll;
    split2(b * cs + a * sn, hh, ll); kh[base + d + 64] = hh; kl[base + d + 64] = ll;
  }
}

__global__ __launch_bounds__(256) void k_router(const float* __restrict__ h2,
                                                const float* __restrict__ rw,
                                                int* __restrict__ topi,
                                                float* __restrict__ topw,
                                                int* __restrict__ cnt) {
  int t = blockIdx.x;
  __shared__ float hs[DMODEL];
  __shared__ float lg[NE];
  for (int c = threadIdx.x; c < DMODEL; c += 256) hs[c] = h2[(size_t)t * DMODEL + c];
  __syncthreads();
  int grp = threadIdx.x >> 5;
  int ln = threadIdx.x & 31;
  float p = 0.f;
  for (int c = ln; c < DMODEL; c += 32) p += hs[c] * rw[(size_t)grp * DMODEL + c];
#pragma unroll
  for (int o = 16; o; o >>= 1) p += __shfl_down(p, o, 32);
  if (ln == 0) lg[grp] = p;
  __syncthreads();
  if (threadIdx.x == 0) {
    float l0 = -3.4e38f; int i0 = 0;
    for (int e = 0; e < NE; e++)
      if (lg[e] > l0) { l0 = lg[e]; i0 = e; }
    float l1 = -3.4e38f; int i1 = 0;
    for (int e = 0; e < NE; e++)
      if (e != i0 && lg[e] > l1) { l1 = lg[e]; i1 = e; }
    float z = expf(l1 - l0);
    topi[t * 2] = i0; topi[t * 2 + 1] = i1;
    topw[t * 2] = 1.f / (1.f + z); topw[t * 2 + 1] = z / (1.f + z);
    atomicAdd(&cnt[i0], 1);
    atomicAdd(&cnt[i1], 1);
  }
}

__global__ void k_scan(int* __restrict__ meta) {
  if (threadIdx.x == 0 && blockIdx.x == 0) {
    int o = 0, nt = 0;
    for (int e = 0; e < NE; e++) {
      meta[16 + e] = o;
      for (int m0 = 0; m0 < meta[e]; m0 += 128) meta[26 + nt++] = (m0 << 3) | e;
      o += meta[e];
    }
    meta[24] = o;
    meta[25] = nt;
  }
}

__global__ void k_fill(const int* __restrict__ topi, const float* __restrict__ topw,
                       int* __restrict__ meta, int* __restrict__ ptok,
                       float* __restrict__ pw) {
  int t = blockIdx.x * blockDim.x + threadIdx.x;
  if (t >= S_LEN) return;
#pragma unroll
  for (int j = 0; j < 2; j++) {
    int e = topi[t * 2 + j];
    int p = atomicAdd(&meta[8 + e], 1);
    ptok[meta[16 + e] + p] = t;
    pw[meta[16 + e] + p] = topw[t * 2 + j];
  }
}

// ---------------- launch ----------------

extern "C" void kernel_launch(void* const* d_in, const int* in_sizes, int n_in,
                              void* d_out, int out_size, void* d_ws, size_t ws_size,
                              hipStream_t stream) {
  (void)in_sizes; (void)n_in; (void)out_size; (void)ws_size;
  const float* x = (const float*)d_in[0];
  const float* ln1w = (const float*)d_in[2];
  const float* ln2w = (const float*)d_in[3];
  const float* wqkv = (const float*)d_in[4];
  const float* wo = (const float*)d_in[5];
  const float* rw = (const float*)d_in[6];
  const float* w1 = (const float*)d_in[7];
  const float* v1 = (const float*)d_in[8];
  const float* w2 = (const float*)d_in[9];
  float* out = (float*)d_out;

  char* wsb = (char*)d_ws;
  const size_t MiB = 1u << 20;
  unsigned short* h1Ph = (unsigned short*)(wsb + 0 * MiB);
  unsigned short* h1Pl = (unsigned short*)(wsb + 8 * MiB);
  float* qkvb = (float*)(wsb + 16 * MiB);
  unsigned short* qh = (unsigned short*)(wsb + 40 * MiB);
  unsigned short* ql = (unsigned short*)(wsb + 48 * MiB);
  unsigned short* kh = (unsigned short*)(wsb + 56 * MiB);
  unsigned short* kl = (unsigned short*)(wsb + 58 * MiB);
  unsigned short* vPh = (unsigned short*)(wsb + 60 * MiB);
  unsigned short* vPl = (unsigned short*)(wsb + 62 * MiB);
  unsigned short* kPh = (unsigned short*)(wsb + 64 * MiB);
  unsigned short* kPl = (unsigned short*)(wsb + 66 * MiB);
  unsigned short* atPh = (unsigned short*)(wsb + 68 * MiB);
  unsigned short* atPl = (unsigned short*)(wsb + 76 * MiB);
  unsigned short* wqkvPh = (unsigned short*)(wsb + 84 * MiB);
  unsigned short* wqkvPl = (unsigned short*)(wsb + 96 * MiB);
  unsigned short* woPh = (unsigned short*)(wsb + 108 * MiB);
  unsigned short* woPl = (unsigned short*)(wsb + 116 * MiB);
  unsigned short* hAP = (unsigned short*)(wsb + 0 * MiB);
  unsigned short* g = (unsigned short*)(wsb + 20 * MiB);
  float* h2f = (float*)(wsb + 40 * MiB);
  unsigned short* h2b = (unsigned short*)(wsb + 56 * MiB);
  unsigned short* h2lo = (unsigned short*)(wsb + 20 * MiB);
  unsigned short* wPa = (unsigned short*)(wsb + 40 * MiB);
  unsigned short* wPb = (unsigned short*)(wsb + 104 * MiB);
  char* small = wsb + 168 * MiB;
  int* topi = (int*)small;
  float* topw = (float*)(small + 16384);
  int* ptok = (int*)(small + 32768);
  float* pw = (float*)(small + 49152);
  int* meta = (int*)(small + 65536);

  k_pack2<<<dim3(QKV_N / 128, 16, 1), 256, 0, stream>>>(wqkv, QKV_N, 0, QKV_N / 128,
                                                        wqkvPh, wqkvPl);
  k_pack2<<<dim3(DMODEL / 128, 16, 1), 256, 0, stream>>>(wo, DMODEL, 0, DMODEL / 128,
                                                         woPh, woPl);

  k_ln<<<S_LEN, 256, 0, stream>>>(x, ln1w, h1Ph, h1Pl, (float*)nullptr, 1);
  k_qkv_s<<<dim3(QKV_N / 128, S_LEN / 128), 256, 0, stream>>>(h1Ph, h1Pl, wqkvPh, wqkvPl,
                                                              qkvb);
  k_rope2<<<S_LEN, 64, 0, stream>>>(qkvb, qh, ql, kh, kl);
  k_pack2<<<dim3(1, 16, NKV), 256, 0, stream>>>(qkvb + (NH + NKV) * HD, QKV_N, HD, 1,
                                                vPh, vPl);
  k_packbf<<<dim3(16, NKV), 256, 0, stream>>>(kh, kPh);
  k_packbf<<<dim3(16, NKV), 256, 0, stream>>>(kl, kPl);
  k_flash<<<512, 128, 0, stream>>>(qh, ql, kPh, kPl, vPh, vPl, atPh, atPl);
  k_wo_s<<<dim3(16, 16), 256, 0, stream>>>(atPh, atPl, woPh, woPl, x, out);

  k_ln<<<S_LEN, 256, 0, stream>>>(out, ln2w, h2b, h2lo, h2f, 0);
  hipMemsetAsync(meta, 0, 512, stream);
  k_router<<<S_LEN, 256, 0, stream>>>(h2f, rw, topi, topw, meta);
  k_scan<<<1, 64, 0, stream>>>(meta);
  k_fill<<<8, 256, 0, stream>>>(topi, topw, meta, ptok, pw);
  k_gpack<<<dim3(40, 8), 256, 0, stream>>>(h2b, ptok, meta, hAP);
  k_pack1<<<dim3(16, 16, NE), 256, 0, stream>>>(w1, FF, (long)DMODEL * FF, 16, wPa);
  k_pack1<<<dim3(16, 16, NE), 256, 0, stream>>>(v1, FF, (long)DMODEL * FF, 16, wPb);
  k_moe1f<<<dim3(16, 40), 256, 0, stream>>>(hAP, wPa, wPb, meta, g);
  k_pack1<<<dim3(16, 16, NE), 256, 0, stream>>>(w2, DMODEL, (long)FF * DMODEL, 16, wPa);
  k_moe2<<<dim3(16, 40, 2), 256, 0, stream>>>(g, wPa, ptok, pw, meta, out);
}

// Round 14
// 912.147 us; speedup vs baseline: 1.0977x; 1.0060x over previous
//
#include <hip/hip_runtime.h>

#define S_LEN 2048
#define DMODEL 2048
#define NH 16
#define NKV 4
#define HD 128
#define NE 8
#define FF 2048
#define QKV_N 3072   // (H + 2*KV) * HD

typedef __attribute__((ext_vector_type(8))) short short8;
typedef __attribute__((ext_vector_type(4))) float f32x4;

__device__ inline unsigned short f2bf(float f) {
  unsigned int u = __builtin_bit_cast(unsigned int, f);
  u += 0x7fffu + ((u >> 16) & 1u);
  return (unsigned short)(u >> 16);
}
__device__ inline float bf2f(unsigned short h) {
  unsigned int u = ((unsigned int)h) << 16;
  return __builtin_bit_cast(float, u);
}
__device__ inline void split2(float v, unsigned short& h, unsigned short& l) {
  h = f2bf(v);
  l = f2bf(v - bf2f(h));
}

// ======== chunk format (verified r3-r13): 8KB = 128 rows x 32 k bf16 ========
// element (row, k=8q+j) at ushort off row*32 + ((q ^ s(row))<<3) + j, s=(row^(row>>2))&3
// s(row) == s(row+16).  LDS pos (w*1024 + l*8) <-> row = w*32+(l>>2), phys slot qp = l&3.

__device__ inline void gload16(const void* g, void* l) {
  __builtin_amdgcn_global_load_lds((const __attribute__((address_space(1))) unsigned int*)g,
                                   (__attribute__((address_space(3))) unsigned int*)l,
                                   16, 0, 0);
}
__device__ inline void stageB_chunk(const unsigned short* __restrict__ chunk,
                                    unsigned short* __restrict__ lds) {
  int w = threadIdx.x >> 6, l = threadIdx.x & 63;
  const unsigned short* s = chunk + w * 1024 + l * 8;
  unsigned short* d = lds + w * 1024;
  gload16(s, d);
  gload16(s + 512, d + 512);
}

#define WVM0   asm volatile("s_waitcnt vmcnt(0)" ::: "memory")
#define WVM4   asm volatile("s_waitcnt vmcnt(4)" ::: "memory")
#define WVM6   asm volatile("s_waitcnt vmcnt(6)" ::: "memory")
#define WVM8   asm volatile("s_waitcnt vmcnt(8)" ::: "memory")
#define WVM12  asm volatile("s_waitcnt vmcnt(12)" ::: "memory")
#define WAIT_ALL  asm volatile("s_waitcnt vmcnt(0) lgkmcnt(0)" ::: "memory")
#define WAIT_LDS  asm volatile("s_waitcnt lgkmcnt(0)" ::: "memory")
#define SCHEDBAR  __builtin_amdgcn_sched_barrier(0)
#define BAR       __builtin_amdgcn_s_barrier()

// ---------------- MFMA cores ----------------

__device__ inline void mma16(const unsigned short* As, const unsigned short* Bs,
                             int wr, int wc, f32x4 acc[4][4]) {
  int l = threadIdx.x & 63;
  int lr = l & 15, lg = l >> 4;
  int qoff = ((lg ^ ((lr ^ (lr >> 2)) & 3)) << 3);
  short8 a[4], b[4];
#pragma unroll
  for (int m = 0; m < 4; m++)
    a[m] = *(const short8*)(As + (wr + m * 16 + lr) * 32 + qoff);
#pragma unroll
  for (int n = 0; n < 4; n++)
    b[n] = *(const short8*)(Bs + (wc + n * 16 + lr) * 32 + qoff);
#pragma unroll
  for (int m = 0; m < 4; m++)
#pragma unroll
    for (int n = 0; n < 4; n++)
      acc[m][n] = __builtin_amdgcn_mfma_f32_16x16x32_bf16(a[m], b[n], acc[m][n], 0, 0, 0);
}

__device__ inline void mma16_dualB(const unsigned short* As, const unsigned short* Bs1,
                                   const unsigned short* Bs2, int wr, int wc,
                                   f32x4 acc1[4][4], f32x4 acc2[4][4]) {
  int l = threadIdx.x & 63;
  int lr = l & 15, lg = l >> 4;
  int qoff = ((lg ^ ((lr ^ (lr >> 2)) & 3)) << 3);
  short8 a[4], b1[4], b2[4];
#pragma unroll
  for (int m = 0; m < 4; m++)
    a[m] = *(const short8*)(As + (wr + m * 16 + lr) * 32 + qoff);
#pragma unroll
  for (int n = 0; n < 4; n++) {
    b1[n] = *(const short8*)(Bs1 + (wc + n * 16 + lr) * 32 + qoff);
    b2[n] = *(const short8*)(Bs2 + (wc + n * 16 + lr) * 32 + qoff);
  }
#pragma unroll
  for (int m = 0; m < 4; m++)
#pragma unroll
    for (int n = 0; n < 4; n++) {
      acc1[m][n] = __builtin_amdgcn_mfma_f32_16x16x32_bf16(a[m], b1[n], acc1[m][n], 0, 0, 0);
      acc2[m][n] = __builtin_amdgcn_mfma_f32_16x16x32_bf16(a[m], b2[n], acc2[m][n], 0, 0, 0);
    }
}

__device__ inline void mma16_split_reg(const unsigned short* Ash, const unsigned short* Asl,
                                       const unsigned short* Bsh, const unsigned short* Bsl,
                                       int wr, int wc, f32x4 acc[4][4]) {
  int l = threadIdx.x & 63;
  int lr = l & 15, lg = l >> 4;
  int qoff = ((lg ^ ((lr ^ (lr >> 2)) & 3)) << 3);
  short8 ah[4], al[4], bh[4], bl[4];
#pragma unroll
  for (int m = 0; m < 4; m++) {
    ah[m] = *(const short8*)(Ash + (wr + m * 16 + lr) * 32 + qoff);
    al[m] = *(const short8*)(Asl + (wr + m * 16 + lr) * 32 + qoff);
  }
#pragma unroll
  for (int n = 0; n < 4; n++) {
    bh[n] = *(const short8*)(Bsh + (wc + n * 16 + lr) * 32 + qoff);
    bl[n] = *(const short8*)(Bsl + (wc + n * 16 + lr) * 32 + qoff);
  }
#pragma unroll
  for (int m = 0; m < 4; m++)
#pragma unroll
    for (int n = 0; n < 4; n++) {
      acc[m][n] = __builtin_amdgcn_mfma_f32_16x16x32_bf16(ah[m], bh[n], acc[m][n], 0, 0, 0);
      acc[m][n] = __builtin_amdgcn_mfma_f32_16x16x32_bf16(ah[m], bl[n], acc[m][n], 0, 0, 0);
      acc[m][n] = __builtin_amdgcn_mfma_f32_16x16x32_bf16(al[m], bh[n], acc[m][n], 0, 0, 0);
    }
}

// ---------------- pack kernels ----------------

__global__ __launch_bounds__(256) void k_pack1(const float* __restrict__ src, long ld,
                                               long zs, int nc,
                                               unsigned short* __restrict__ dst) {
  __shared__ float tile[32][132];
  const float* Sp = src + (long)blockIdx.z * zs;
  int c = blockIdx.x, t = threadIdx.x;
  for (int i = 0; i < 4; i++) {
    int kt = blockIdx.y * 4 + i;
    long k0 = (long)kt * 32, n0 = (long)c * 128;
    {
      int k = t >> 3, nn = (t & 7) * 16;
      const float4* p = (const float4*)(Sp + (k0 + k) * ld + n0 + nn);
#pragma unroll
      for (int j = 0; j < 4; j++) *(float4*)&tile[k][nn + j * 4] = p[j];
    }
    __syncthreads();
    size_t cbase = ((size_t)(blockIdx.z * nc + c) * 64 + kt) * 4096;
#pragma unroll
    for (int uu = 0; uu < 2; uu++) {
      int u = t * 2 + uu;
      int n = u >> 2, qp = u & 3;
      int q = qp ^ ((n ^ (n >> 2)) & 3);
      unsigned short hb[8] __attribute__((aligned(16)));
#pragma unroll
      for (int j = 0; j < 8; j++) hb[j] = f2bf(tile[8 * q + j][n]);
      *(uint4*)(dst + cbase + u * 8) = *(const uint4*)hb;
    }
    __syncthreads();
  }
}

__global__ __launch_bounds__(256) void k_pack2(const float* __restrict__ src, long ld,
                                               long zs, int nc,
                                               unsigned short* __restrict__ dh,
                                               unsigned short* __restrict__ dl) {
  __shared__ float tile[32][132];
  const float* Sp = src + (long)blockIdx.z * zs;
  int c = blockIdx.x, t = threadIdx.x;
  for (int i = 0; i < 4; i++) {
    int kt = blockIdx.y * 4 + i;
    long k0 = (long)kt * 32, n0 = (long)c * 128;
    {
      int k = t >> 3, nn = (t & 7) * 16;
      const float4* p = (const float4*)(Sp + (k0 + k) * ld + n0 + nn);
#pragma unroll
      for (int j = 0; j < 4; j++) *(float4*)&tile[k][nn + j * 4] = p[j];
    }
    __syncthreads();
    size_t cbase = ((size_t)(blockIdx.z * nc + c) * 64 + kt) * 4096;
#pragma unroll
    for (int uu = 0; uu < 2; uu++) {
      int u = t * 2 + uu;
      int n = u >> 2, qp = u & 3;
      int q = qp ^ ((n ^ (n >> 2)) & 3);
      unsigned short hb[8] __attribute__((aligned(16)));
      unsigned short lb[8] __attribute__((aligned(16)));
#pragma unroll
      for (int j = 0; j < 8; j++) split2(tile[8 * q + j][n], hb[j], lb[j]);
      *(uint4*)(dh + cbase + u * 8) = *(const uint4*)hb;
      *(uint4*)(dl + cbase + u * 8) = *(const uint4*)lb;
    }
    __syncthreads();
  }
}

// ---------------- qkv / wo GEMMs (r10/r13-proven 2-phase) ----------------

__global__ __launch_bounds__(256) void k_qkv_s(const unsigned short* __restrict__ APh,
                                               const unsigned short* __restrict__ APl,
                                               const unsigned short* __restrict__ BPh,
                                               const unsigned short* __restrict__ BPl,
                                               float* __restrict__ C) {
  __shared__ unsigned short Ash[2 * 4096], Asl[2 * 4096], Bsh[2 * 4096], Bsl[2 * 4096];
  size_t ab = (size_t)blockIdx.y * 64 * 4096;
  size_t cb = (size_t)blockIdx.x * 64 * 4096;
  int w = threadIdx.x >> 6;
  int wr = (w >> 1) * 64, wc = (w & 1) * 64;
  stageB_chunk(APh + ab, Ash);
  stageB_chunk(APl + ab, Asl);
  stageB_chunk(BPh + cb, Bsh);
  stageB_chunk(BPl + cb, Bsl);
  WAIT_ALL;
  BAR;
  f32x4 acc[4][4] = {};
  for (int kt = 0; kt < 64; kt++) {
    int cur = (kt & 1) << 12, nxt = 4096 - cur;
    if (kt + 1 < 64) {
      size_t o = (size_t)(kt + 1) * 4096;
      stageB_chunk(APh + ab + o, Ash + nxt);
      stageB_chunk(APl + ab + o, Asl + nxt);
      stageB_chunk(BPh + cb + o, Bsh + nxt);
      stageB_chunk(BPl + cb + o, Bsl + nxt);
    }
    SCHEDBAR;
    mma16_split_reg(Ash + cur, Asl + cur, Bsh + cur, Bsl + cur, wr, wc, acc);
    SCHEDBAR;
    WAIT_ALL;
    BAR;
  }
  int row0 = blockIdx.y * 128, col0 = blockIdx.x * 128;
  int l = threadIdx.x & 63;
  int er = wr + ((l >> 4) << 2), ec = wc + (l & 15);
#pragma unroll
  for (int m = 0; m < 4; m++)
#pragma unroll
    for (int n = 0; n < 4; n++)
#pragma unroll
      for (int r = 0; r < 4; r++) {
        float v = acc[m][n][r];
        v = fminf(fmaxf(v, -8.f), 8.f);
        C[(size_t)(row0 + er + m * 16 + r) * QKV_N + col0 + ec + n * 16] = v;
      }
}

__global__ __launch_bounds__(256) void k_wo_s(const unsigned short* __restrict__ APh,
                                              const unsigned short* __restrict__ APl,
                                              const unsigned short* __restrict__ BPh,
                                              const unsigned short* __restrict__ BPl,
                                              const float* __restrict__ resid,
                                              float* __restrict__ x1) {
  __shared__ unsigned short Ash[2 * 4096], Asl[2 * 4096], Bsh[2 * 4096], Bsl[2 * 4096];
  size_t ab = (size_t)blockIdx.y * 64 * 4096;
  size_t cb = (size_t)blockIdx.x * 64 * 4096;
  int w = threadIdx.x >> 6;
  int wr = (w >> 1) * 64, wc = (w & 1) * 64;
  stageB_chunk(APh + ab, Ash);
  stageB_chunk(APl + ab, Asl);
  stageB_chunk(BPh + cb, Bsh);
  stageB_chunk(BPl + cb, Bsl);
  WAIT_ALL;
  BAR;
  f32x4 acc[4][4] = {};
  for (int kt = 0; kt < 64; kt++) {
    int cur = (kt & 1) << 12, nxt = 4096 - cur;
    if (kt + 1 < 64) {
      size_t o = (size_t)(kt + 1) * 4096;
      stageB_chunk(APh + ab + o, Ash + nxt);
      stageB_chunk(APl + ab + o, Asl + nxt);
      stageB_chunk(BPh + cb + o, Bsh + nxt);
      stageB_chunk(BPl + cb + o, Bsl + nxt);
    }
    SCHEDBAR;
    mma16_split_reg(Ash + cur, Asl + cur, Bsh + cur, Bsl + cur, wr, wc, acc);
    SCHEDBAR;
    WAIT_ALL;
    BAR;
  }
  int row0 = blockIdx.y * 128, col0 = blockIdx.x * 128;
  int l = threadIdx.x & 63;
  int er = wr + ((l >> 4) << 2), ec = wc + (l & 15);
#pragma unroll
  for (int m = 0; m < 4; m++)
#pragma unroll
    for (int n = 0; n < 4; n++)
#pragma unroll
      for (int r = 0; r < 4; r++) {
        size_t idx = (size_t)(row0 + er + m * 16 + r) * DMODEL + col0 + ec + n * 16;
        x1[idx] = resid[idx] + acc[m][n][r];
      }
}

// ---------------- flash attention (r8-verified core; chunk-layout epilogue) ----------------

__global__ __launch_bounds__(128) void k_flash(const unsigned short* __restrict__ qh,
                                               const unsigned short* __restrict__ ql,
                                               const unsigned short* __restrict__ kPh,
                                               const unsigned short* __restrict__ kPl,
                                               const unsigned short* __restrict__ vPh,
                                               const unsigned short* __restrict__ vPl,
                                               unsigned short* __restrict__ atPh,
                                               unsigned short* __restrict__ atPl) {
  int bid = blockIdx.x;
  int h = (bid & 7) | ((bid >> 8) << 3);
  int rt = (bid >> 3) & 31;
  int kv = h >> 2;
  int ntiles = (rt >> 1) + 1;
  __shared__ float Pds[2][32 * 132];
  int t = threadIdx.x;
  int w = t >> 6, l = t & 63;
  int lr = l & 15, lg = l >> 4;
  int qoff = ((lg ^ ((lr ^ (lr >> 2)) & 3)) << 3);
  int wrow0 = rt * 64 + w * 32;
  const unsigned short* Qbh = qh + (size_t)h * S_LEN * HD;
  const unsigned short* Qbl = ql + (size_t)h * S_LEN * HD;
  const unsigned short* Kch = kPh + (size_t)kv * 64 * 4096;
  const unsigned short* Kcl = kPl + (size_t)kv * 64 * 4096;
  const unsigned short* Vch = vPh + (size_t)kv * 64 * 4096;
  const unsigned short* Vcl = vPl + (size_t)kv * 64 * 4096;
  float* Pw = &Pds[w][0];
  float mrun[2][4], lrun[2][4];
  f32x4 Oc[2][8];
#pragma unroll
  for (int m = 0; m < 2; m++)
#pragma unroll
    for (int r = 0; r < 4; r++) { mrun[m][r] = -3.4e38f; lrun[m][r] = 0.f; }
#pragma unroll
  for (int m = 0; m < 2; m++)
#pragma unroll
    for (int n = 0; n < 8; n++)
#pragma unroll
      for (int r = 0; r < 4; r++) Oc[m][n][r] = 0.f;
  const float scale = 0.08838834764831845f;

  for (int kt = 0; kt < ntiles; kt++) {
    f32x4 Sa[2][8];
#pragma unroll
    for (int m = 0; m < 2; m++)
#pragma unroll
      for (int n = 0; n < 8; n++)
#pragma unroll
        for (int r = 0; r < 4; r++) Sa[m][n][r] = 0.f;
#pragma unroll
    for (int kst = 0; kst < 4; kst++) {
      short8 qfh[2], qfl[2];
#pragma unroll
      for (int m = 0; m < 2; m++) {
        size_t o = (size_t)(wrow0 + m * 16 + lr) * HD + kst * 32 + lg * 8;
        qfh[m] = *(const short8*)(Qbh + o);
        qfl[m] = *(const short8*)(Qbl + o);
      }
      const unsigned short* Kh = Kch + (size_t)(kt * 4 + kst) * 4096;
      const unsigned short* Kl = Kcl + (size_t)(kt * 4 + kst) * 4096;
      short8 bh[8], bl[8];
#pragma unroll
      for (int n = 0; n < 8; n++) {
        bh[n] = *(const short8*)(Kh + (n * 16 + lr) * 32 + qoff);
        bl[n] = *(const short8*)(Kl + (n * 16 + lr) * 32 + qoff);
      }
#pragma unroll
      for (int m = 0; m < 2; m++)
#pragma unroll
        for (int n = 0; n < 8; n++) {
          Sa[m][n] = __builtin_amdgcn_mfma_f32_16x16x32_bf16(qfh[m], bh[n], Sa[m][n], 0, 0, 0);
          Sa[m][n] = __builtin_amdgcn_mfma_f32_16x16x32_bf16(qfh[m], bl[n], Sa[m][n], 0, 0, 0);
          Sa[m][n] = __builtin_amdgcn_mfma_f32_16x16x32_bf16(qfl[m], bh[n], Sa[m][n], 0, 0, 0);
        }
    }
#pragma unroll
    for (int m = 0; m < 2; m++)
#pragma unroll
      for (int r = 0; r < 4; r++) {
        int row = wrow0 + m * 16 + lg * 4 + r;
        float mx = mrun[m][r];
#pragma unroll
        for (int n = 0; n < 8; n++) {
          float v = Sa[m][n][r] * scale;
          int col = kt * 128 + n * 16 + lr;
          v = (col <= row) ? v : -3.4e38f;
          Sa[m][n][r] = v;
          mx = fmaxf(mx, v);
        }
        mx = fmaxf(mx, __shfl_xor(mx, 1));
        mx = fmaxf(mx, __shfl_xor(mx, 2));
        mx = fmaxf(mx, __shfl_xor(mx, 4));
        mx = fmaxf(mx, __shfl_xor(mx, 8));
        float al_ = expf(mrun[m][r] - mx);
        float sum = 0.f;
#pragma unroll
        for (int n = 0; n < 8; n++) {
          float v = Sa[m][n][r];
          float e = (v > -1.0e37f) ? expf(v - mx) : 0.f;
          Sa[m][n][r] = e;
          sum += e;
        }
        sum += __shfl_xor(sum, 1);
        sum += __shfl_xor(sum, 2);
        sum += __shfl_xor(sum, 4);
        sum += __shfl_xor(sum, 8);
        lrun[m][r] = lrun[m][r] * al_ + sum;
        mrun[m][r] = mx;
#pragma unroll
        for (int n = 0; n < 8; n++) Oc[m][n][r] *= al_;
      }
    WAIT_LDS;
    SCHEDBAR;
#pragma unroll
    for (int m = 0; m < 2; m++)
#pragma unroll
      for (int n = 0; n < 8; n++)
#pragma unroll
        for (int r = 0; r < 4; r++)
          Pw[(m * 16 + lg * 4 + r) * 132 + n * 16 + lr] = Sa[m][n][r];
    WAIT_LDS;
    SCHEDBAR;
#pragma unroll
    for (int kst = 0; kst < 4; kst++) {
      const unsigned short* Vh = Vch + (size_t)(kt * 4 + kst) * 4096;
      const unsigned short* Vl = Vcl + (size_t)(kt * 4 + kst) * 4096;
      short8 bh[8], bl[8];
#pragma unroll
      for (int n = 0; n < 8; n++) {
        bh[n] = *(const short8*)(Vh + (n * 16 + lr) * 32 + qoff);
        bl[n] = *(const short8*)(Vl + (n * 16 + lr) * 32 + qoff);
      }
#pragma unroll
      for (int m = 0; m < 2; m++) {
        const float* pp = &Pw[(m * 16 + lr) * 132 + kst * 32 + lg * 8];
        unsigned short ahb[8] __attribute__((aligned(16)));
        unsigned short alb[8] __attribute__((aligned(16)));
#pragma unroll
        for (int j = 0; j < 8; j++) split2(pp[j], ahb[j], alb[j]);
        short8 ah = *(const short8*)ahb;
        short8 al_ = *(const short8*)alb;
#pragma unroll
        for (int n = 0; n < 8; n++) {
          Oc[m][n] = __builtin_amdgcn_mfma_f32_16x16x32_bf16(ah, bh[n], Oc[m][n], 0, 0, 0);
          Oc[m][n] = __builtin_amdgcn_mfma_f32_16x16x32_bf16(ah, bl[n], Oc[m][n], 0, 0, 0);
          Oc[m][n] = __builtin_amdgcn_mfma_f32_16x16x32_bf16(al_, bh[n], Oc[m][n], 0, 0, 0);
        }
      }
    }
  }
#pragma unroll
  for (int m = 0; m < 2; m++)
#pragma unroll
    for (int r = 0; r < 4; r++) {
      int row = wrow0 + m * 16 + lg * 4 + r;
      int rtc = row >> 7, rl = row & 127;
      int sr = (rl ^ (rl >> 2)) & 3;
      float lv = lrun[m][r];
#pragma unroll
      for (int n = 0; n < 8; n++) {
        int col = h * HD + n * 16 + lr;
        size_t off = ((size_t)(rtc * 64 + (col >> 5))) * 4096 + rl * 32 +
                     ((((col & 31) >> 3) ^ sr) << 3) + (col & 7);
        unsigned short hh, ll;
        split2(Oc[m][n][r] / lv, hh, ll);
        atPh[off] = hh;
        atPl[off] = ll;
      }
    }
}

// ---------------- MoE GEMMs: depth-3 block-cooperative counted-vmcnt (r13) ----------------

// g(chunks) = silu(h2 @ w1[e]) * (h2 @ v1[e]); A staged DIRECTLY from h2b (gathered)
__global__ __launch_bounds__(256) void k_moe1f(const unsigned short* __restrict__ h2b,
                                               const int* __restrict__ ptok,
                                               const unsigned short* __restrict__ wPa,
                                               const unsigned short* __restrict__ wPb,
                                               const int* __restrict__ meta,
                                               unsigned short* __restrict__ g) {
  int ty = blockIdx.y;
  if (ty >= meta[25]) return;
  int tt = meta[26 + ty];
  int e = tt & 7, m0 = tt >> 3;
  int nvalid = min(128, meta[e] - m0);
  const unsigned short* B1 = wPa + (size_t)(e * 16 + blockIdx.x) * 64 * 4096;
  const unsigned short* B2 = wPb + (size_t)(e * 16 + blockIdx.x) * 64 * 4096;
  __shared__ unsigned short L[3][3][4096];  // 72KB
  int w = threadIdx.x >> 6;
  int lid = threadIdx.x & 63;
  int wr = (w >> 1) * 64, wc = (w & 1) * 64;
  // per-lane gathered A sources (loop-invariant bases; s(row)==s(row+16))
  int r0 = w * 32 + (lid >> 2);
  int qx = lid & 3;
  int s0 = (r0 ^ (r0 >> 2)) & 3;
  long pb = (long)meta[16 + e] + m0;
  int tk0 = ptok[pb + min(r0, nvalid - 1)];
  int tk1 = ptok[pb + min(r0 + 16, nvalid - 1)];
  const unsigned short* a0 = h2b + (size_t)tk0 * DMODEL + ((qx ^ s0) << 3);
  const unsigned short* a1 = h2b + (size_t)tk1 * DMODEL + ((qx ^ s0) << 3);
#pragma unroll
  for (int p = 0; p < 3; p++) {
    size_t o = (size_t)p * 4096;
    unsigned short* dA = &L[p][0][0] + w * 1024;
    gload16(a0 + p * 32, dA);
    gload16(a1 + p * 32, dA + 512);
    stageB_chunk(B1 + o, &L[p][1][0]);
    stageB_chunk(B2 + o, &L[p][2][0]);
  }
  WVM12;
  BAR;
  f32x4 acc1[4][4] = {}, acc2[4][4] = {};
  int cur = 0;
  for (int kt = 0; kt < 64; kt++) {
    SCHEDBAR;
    mma16_dualB(&L[cur][0][0], &L[cur][1][0], &L[cur][2][0], wr, wc, acc1, acc2);
    SCHEDBAR;
    BAR;
    if (kt + 3 < 64) {
      size_t o = (size_t)(kt + 3) * 4096;
      unsigned short* dA = &L[cur][0][0] + w * 1024;
      gload16(a0 + (kt + 3) * 32, dA);
      gload16(a1 + (kt + 3) * 32, dA + 512);
      stageB_chunk(B1 + o, &L[cur][1][0]);
      stageB_chunk(B2 + o, &L[cur][2][0]);
      WVM12;
    } else if (kt + 3 == 64) {
      WVM6;
    } else {
      WVM0;
    }
    BAR;
    cur = (cur == 2) ? 0 : cur + 1;
  }
  int l = threadIdx.x & 63;
  int er = wr + ((l >> 4) << 2), ec = wc + (l & 15);
  int ktf0 = blockIdx.x * 4;
#pragma unroll
  for (int m = 0; m < 4; m++)
#pragma unroll
    for (int n = 0; n < 4; n++)
#pragma unroll
      for (int r = 0; r < 4; r++) {
        int rl = er + m * 16 + r;
        int cc = ec + n * 16;
        float a = acc1[m][n][r];
        float s = a / (1.f + expf(-a));
        unsigned short val = (rl < nvalid) ? f2bf(s * acc2[m][n][r]) : (unsigned short)0;
        int srl = (rl ^ (rl >> 2)) & 3;
        g[((size_t)(ty * 64 + ktf0 + (cc >> 5))) * 4096 + rl * 32 +
          ((((cc & 31) >> 3) ^ srl) << 3) + (cc & 7)] = val;
      }
}

__global__ __launch_bounds__(256) void k_moe2(const unsigned short* __restrict__ gP,
                                              const unsigned short* __restrict__ wP,
                                              const int* __restrict__ ptok,
                                              const float* __restrict__ pw,
                                              const int* __restrict__ meta,
                                              float* __restrict__ out) {
  int ty = blockIdx.y;
  if (ty >= meta[25]) return;
  int tt = meta[26 + ty];
  int e = tt & 7, m0 = tt >> 3;
  int nvalid = min(128, meta[e] - m0);
  long pbase = (long)meta[16 + e] + m0;
  int kc = blockIdx.z;
  const unsigned short* Ab = gP + ((size_t)ty * 64 + kc * 32) * 4096;
  const unsigned short* Bb = wP + ((size_t)(e * 16 + blockIdx.x) * 64 + kc * 32) * 4096;
  __shared__ unsigned short L[3][2][4096];  // 48KB
  int w = threadIdx.x >> 6;
  int wr = (w >> 1) * 64, wc = (w & 1) * 64;
#pragma unroll
  for (int p = 0; p < 3; p++) {
    size_t o = (size_t)p * 4096;
    stageB_chunk(Ab + o, &L[p][0][0]);
    stageB_chunk(Bb + o, &L[p][1][0]);
  }
  WVM8;
  BAR;
  f32x4 acc[4][4] = {};
  int cur = 0;
  for (int kt = 0; kt < 32; kt++) {
    SCHEDBAR;
    mma16(&L[cur][0][0], &L[cur][1][0], wr, wc, acc);
    SCHEDBAR;
    BAR;
    if (kt + 3 < 32) {
      size_t o = (size_t)(kt + 3) * 4096;
      stageB_chunk(Ab + o, &L[cur][0][0]);
      stageB_chunk(Bb + o, &L[cur][1][0]);
      WVM8;
    } else if (kt + 3 == 32) {
      WVM4;
    } else {
      WVM0;
    }
    BAR;
    cur = (cur == 2) ? 0 : cur + 1;
  }
  int col0 = blockIdx.x * 128;
  int l = threadIdx.x & 63;
  int er = wr + ((l >> 4) << 2), ec = wc + (l & 15);
#pragma unroll
  for (int m = 0; m < 4; m++)
#pragma unroll
    for (int n = 0; n < 4; n++)
#pragma unroll
      for (int r = 0; r < 4; r++) {
        int rl = er + m * 16 + r;
        if (rl < nvalid) {
          long p = pbase + rl;
          int tk = ptok[p];
          atomicAdd(&out[(size_t)tk * DMODEL + col0 + ec + n * 16], acc[m][n][r] * pw[p]);
        }
      }
}

// ---------------- small kernels ----------------

__global__ __launch_bounds__(256) void k_ln(const float* __restrict__ x,
                                            const float* __restrict__ w,
                                            unsigned short* __restrict__ obh,
                                            unsigned short* __restrict__ obl,
                                            float* __restrict__ of, int mode) {
  int row = blockIdx.x;
  const float* xr = x + (size_t)row * DMODEL;
  float s = 0.f, ss = 0.f;
  for (int c = threadIdx.x; c < DMODEL; c += 256) {
    float v = xr[c];
    s += v; ss += v * v;
  }
#pragma unroll
  for (int o = 32; o; o >>= 1) { s += __shfl_down(s, o); ss += __shfl_down(ss, o); }
  __shared__ float rs[4], rss[4], mu_s, inv_s;
  int wid = threadIdx.x >> 6;
  if ((threadIdx.x & 63) == 0) { rs[wid] = s; rss[wid] = ss; }
  __syncthreads();
  if (threadIdx.x == 0) {
    float S1 = rs[0] + rs[1] + rs[2] + rs[3];
    float S2 = rss[0] + rss[1] + rss[2] + rss[3];
    float mu = S1 / DMODEL;
    mu_s = mu;
    inv_s = rsqrtf(S2 / DMODEL - mu * mu + 1e-5f);
  }
  __syncthreads();
  float mu = mu_s, inv = inv_s;
  int rt = row >> 7, rl = row & 127;
  int sw = (rl ^ (rl >> 2)) & 3;
  for (int c = threadIdx.x; c < DMODEL; c += 256) {
    float v = (xr[c] - mu) * inv * w[c];
    unsigned short hh, ll;
    split2(v, hh, ll);
    if (mode) {
      size_t off = ((size_t)(rt * 64 + (c >> 5))) * 4096 + rl * 32 +
                   ((((c & 31) >> 3) ^ sw) << 3) + (c & 7);
      obh[off] = hh;
      obl[off] = ll;
    } else {
      obh[(size_t)row * DMODEL + c] = hh;
      obl[(size_t)row * DMODEL + c] = ll;
      of[(size_t)row * DMODEL + c] = v;
    }
  }
}

// RoPE: Q written row-major (split), K written directly in chunk layout (split)
__global__ void k_rope2(const float* __restrict__ qkv, unsigned short* __restrict__ qh,
                        unsigned short* __restrict__ ql, unsigned short* __restrict__ kPh,
                        unsigned short* __restrict__ kPl) {
  int t = blockIdx.x;
  int d = threadIdx.x;  // 0..63
  float pf = (float)pow(500000.0, (double)d * (1.0 / 64.0));
  float invf = 1.0f / pf;
  float ang = (float)t * invf;
  float cs = (float)cos((double)ang);
  float sn = (float)sin((double)ang);
  const float* row = qkv + (size_t)t * QKV_N;
  unsigned short hh, ll;
#pragma unroll
  for (int hq = 0; hq < NH; hq++) {
    float a = row[hq * HD + d], b = row[hq * HD + d + 64];
    size_t base = ((size_t)hq * S_LEN + t) * HD;
    split2(a * cs - b * sn, hh, ll); qh[base + d] = hh; ql[base + d] = ll;
    split2(b * cs + a * sn, hh, ll); qh[base + d + 64] = hh; ql[base + d + 64] = ll;
  }
  int tt2 = t >> 7, rl2 = t & 127;
  int s2 = (rl2 ^ (rl2 >> 2)) & 3;
#pragma unroll
  for (int kv = 0; kv < NKV; kv++) {
    float a = row[NH * HD + kv * HD + d], b = row[NH * HD + kv * HD + d + 64];
    float o0 = a * cs - b * sn;   // col d
    float o1 = b * cs + a * sn;   // col d+64
#pragma unroll
    for (int half = 0; half < 2; half++) {
      int col = d + half * 64;
      float v = half ? o1 : o0;
      size_t off = ((size_t)(kv * 64 + tt2 * 4 + (col >> 5))) * 4096 + rl2 * 32 +
                   ((((col & 31) >> 3) ^ s2) << 3) + (col & 7);
      split2(v, hh, ll);
      kPh[off] = hh;
      kPl[off] = ll;
    }
  }
}

__global__ __launch_bounds__(256) void k_router(const float* __restrict__ h2,
                                                const float* __restrict__ rw,
                                                int* __restrict__ topi,
                                                float* __restrict__ topw,
                                                int* __restrict__ cnt) {
  int t = blockIdx.x;
  __shared__ float hs[DMODEL];
  __shared__ float lg[NE];
  for (int c = threadIdx.x; c < DMODEL; c += 256) hs[c] = h2[(size_t)t * DMODEL + c];
  __syncthreads();
  int grp = threadIdx.x >> 5;
  int ln = threadIdx.x & 31;
  float p = 0.f;
  for (int c = ln; c < DMODEL; c += 32) p += hs[c] * rw[(size_t)grp * DMODEL + c];
#pragma unroll
  for (int o = 16; o; o >>= 1) p += __shfl_down(p, o, 32);
  if (ln == 0) lg[grp] = p;
  __syncthreads();
  if (threadIdx.x == 0) {
    float l0 = -3.4e38f; int i0 = 0;
    for (int e = 0; e < NE; e++)
      if (lg[e] > l0) { l0 = lg[e]; i0 = e; }
    float l1 = -3.4e38f; int i1 = 0;
    for (int e = 0; e < NE; e++)
      if (e != i0 && lg[e] > l1) { l1 = lg[e]; i1 = e; }
    float z = expf(l1 - l0);
    topi[t * 2] = i0; topi[t * 2 + 1] = i1;
    topw[t * 2] = 1.f / (1.f + z); topw[t * 2 + 1] = z / (1.f + z);
    atomicAdd(&cnt[i0], 1);
    atomicAdd(&cnt[i1], 1);
  }
}

__global__ void k_scan(int* __restrict__ meta) {
  if (threadIdx.x == 0 && blockIdx.x == 0) {
    int o = 0, nt = 0;
    for (int e = 0; e < NE; e++) {
      meta[16 + e] = o;
      for (int m0 = 0; m0 < meta[e]; m0 += 128) meta[26 + nt++] = (m0 << 3) | e;
      o += meta[e];
    }
    meta[24] = o;
    meta[25] = nt;
  }
}

__global__ void k_fill(const int* __restrict__ topi, const float* __restrict__ topw,
                       int* __restrict__ meta, int* __restrict__ ptok,
                       float* __restrict__ pw) {
  int t = blockIdx.x * blockDim.x + threadIdx.x;
  if (t >= S_LEN) return;
#pragma unroll
  for (int j = 0; j < 2; j++) {
    int e = topi[t * 2 + j];
    int p = atomicAdd(&meta[8 + e], 1);
    ptok[meta[16 + e] + p] = t;
    pw[meta[16 + e] + p] = topw[t * 2 + j];
  }
}

// ---------------- launch ----------------

extern "C" void kernel_launch(void* const* d_in, const int* in_sizes, int n_in,
                              void* d_out, int out_size, void* d_ws, size_t ws_size,
                              hipStream_t stream) {
  (void)in_sizes; (void)n_in; (void)out_size; (void)ws_size;
  const float* x = (const float*)d_in[0];
  const float* ln1w = (const float*)d_in[2];
  const float* ln2w = (const float*)d_in[3];
  const float* wqkv = (const float*)d_in[4];
  const float* wo = (const float*)d_in[5];
  const float* rw = (const float*)d_in[6];
  const float* w1 = (const float*)d_in[7];
  const float* v1 = (const float*)d_in[8];
  const float* w2 = (const float*)d_in[9];
  float* out = (float*)d_out;  // x1 after k_wo_s; MoE adds in place

  char* wsb = (char*)d_ws;
  const size_t MiB = 1u << 20;
  // ---- attention phase ----
  unsigned short* h1Ph = (unsigned short*)(wsb + 0 * MiB);     // 8 (chunks)
  unsigned short* h1Pl = (unsigned short*)(wsb + 8 * MiB);     // 8
  float* qkvb = (float*)(wsb + 16 * MiB);                      // 24
  unsigned short* qh = (unsigned short*)(wsb + 40 * MiB);      // 8
  unsigned short* ql = (unsigned short*)(wsb + 48 * MiB);      // 8
  unsigned short* vPh = (unsigned short*)(wsb + 60 * MiB);     // 2
  unsigned short* vPl = (unsigned short*)(wsb + 62 * MiB);     // 2
  unsigned short* kPh = (unsigned short*)(wsb + 64 * MiB);     // 2
  unsigned short* kPl = (unsigned short*)(wsb + 66 * MiB);     // 2
  unsigned short* atPh = (unsigned short*)(wsb + 68 * MiB);    // 8 (chunks)
  unsigned short* atPl = (unsigned short*)(wsb + 76 * MiB);    // 8
  unsigned short* wqkvPh = (unsigned short*)(wsb + 84 * MiB);  // 12
  unsigned short* wqkvPl = (unsigned short*)(wsb + 96 * MiB);  // 12
  unsigned short* woPh = (unsigned short*)(wsb + 108 * MiB);   // 8
  unsigned short* woPl = (unsigned short*)(wsb + 116 * MiB);   // 8
  // ---- MoE phase (overlays; attention buffers dead) ----
  unsigned short* h2b = (unsigned short*)(wsb + 0 * MiB);      // 8 (over h1Ph; survives moe1f)
  unsigned short* h2lo = (unsigned short*)(wsb + 8 * MiB);     // 8 scratch (lo never read)
  unsigned short* g = (unsigned short*)(wsb + 16 * MiB);       // 20 (over qkvb)
  float* h2f = (float*)(wsb + 40 * MiB);                       // 16 (over qh/ql; dead after router)
  unsigned short* wPa = (unsigned short*)(wsb + 40 * MiB);     // 64 (after router)
  unsigned short* wPb = (unsigned short*)(wsb + 104 * MiB);    // 64
  char* small = wsb + 168 * MiB;
  int* topi = (int*)small;
  float* topw = (float*)(small + 16384);
  int* ptok = (int*)(small + 32768);
  float* pw = (float*)(small + 49152);
  int* meta = (int*)(small + 65536);  // 128 ints

  // ---- pack attention weights ----
  k_pack2<<<dim3(QKV_N / 128, 16, 1), 256, 0, stream>>>(wqkv, QKV_N, 0, QKV_N / 128,
                                                        wqkvPh, wqkvPl);
  k_pack2<<<dim3(DMODEL / 128, 16, 1), 256, 0, stream>>>(wo, DMODEL, 0, DMODEL / 128,
                                                         woPh, woPl);

  // ---- attention sublayer (fp32-emulated) ----
  k_ln<<<S_LEN, 256, 0, stream>>>(x, ln1w, h1Ph, h1Pl, (float*)nullptr, 1);
  k_qkv_s<<<dim3(QKV_N / 128, S_LEN / 128), 256, 0, stream>>>(h1Ph, h1Pl, wqkvPh, wqkvPl,
                                                              qkvb);
  k_rope2<<<S_LEN, 64, 0, stream>>>(qkvb, qh, ql, kPh, kPl);
  k_pack2<<<dim3(1, 16, NKV), 256, 0, stream>>>(qkvb + (NH + NKV) * HD, QKV_N, HD, 1,
                                                vPh, vPl);
  k_flash<<<512, 128, 0, stream>>>(qh, ql, kPh, kPl, vPh, vPl, atPh, atPl);
  k_wo_s<<<dim3(16, 16), 256, 0, stream>>>(atPh, atPl, woPh, woPl, x, out);

  // ---- MoE sublayer ----
  k_ln<<<S_LEN, 256, 0, stream>>>(out, ln2w, h2b, h2lo, h2f, 0);
  hipMemsetAsync(meta, 0, 512, stream);
  k_router<<<S_LEN, 256, 0, stream>>>(h2f, rw, topi, topw, meta);
  k_scan<<<1, 64, 0, stream>>>(meta);
  k_fill<<<8, 256, 0, stream>>>(topi, topw, meta, ptok, pw);
  k_pack1<<<dim3(16, 16, NE), 256, 0, stream>>>(w1, FF, (long)DMODEL * FF, 16, wPa);
  k_pack1<<<dim3(16, 16, NE), 256, 0, stream>>>(v1, FF, (long)DMODEL * FF, 16, wPb);
  k_moe1f<<<dim3(16, 40), 256, 0, stream>>>(h2b, ptok, wPa, wPb, meta, g);
  k_pack1<<<dim3(16, 16, NE), 256, 0, stream>>>(w2, DMODEL, (long)FF * DMODEL, 16, wPa);
  k_moe2<<<dim3(16, 40, 2), 256, 0, stream>>>(g, wPa, ptok, pw, meta, out);
}

// Round 15
// 909.682 us; speedup vs baseline: 1.1007x; 1.0027x over previous
//
#include <hip/hip_runtime.h>

#define S_LEN 2048
#define DMODEL 2048
#define NH 16
#define NKV 4
#define HD 128
#define NE 8
#define FF 2048
#define QKV_N 3072   // (H + 2*KV) * HD

typedef __attribute__((ext_vector_type(8))) short short8;
typedef __attribute__((ext_vector_type(4))) float f32x4;

__device__ inline unsigned short f2bf(float f) {
  unsigned int u = __builtin_bit_cast(unsigned int, f);
  u += 0x7fffu + ((u >> 16) & 1u);
  return (unsigned short)(u >> 16);
}
__device__ inline float bf2f(unsigned short h) {
  unsigned int u = ((unsigned int)h) << 16;
  return __builtin_bit_cast(float, u);
}
__device__ inline void split2(float v, unsigned short& h, unsigned short& l) {
  h = f2bf(v);
  l = f2bf(v - bf2f(h));
}

// ======== chunk format (verified r3-r14): 8KB = 128 rows x 32 k bf16 ========
// element (row, k=8q+j) at ushort off row*32 + ((q ^ s(row))<<3) + j, s=(row^(row>>2))&3
// s(row) == s(row+16).  LDS pos (w*1024 + l*8) <-> row = w*32+(l>>2), phys slot qp = l&3.

__device__ inline void gload16(const void* g, void* l) {
  __builtin_amdgcn_global_load_lds((const __attribute__((address_space(1))) unsigned int*)g,
                                   (__attribute__((address_space(3))) unsigned int*)l,
                                   16, 0, 0);
}
__device__ inline void stageB_chunk(const unsigned short* __restrict__ chunk,
                                    unsigned short* __restrict__ lds) {
  int w = threadIdx.x >> 6, l = threadIdx.x & 63;
  const unsigned short* s = chunk + w * 1024 + l * 8;
  unsigned short* d = lds + w * 1024;
  gload16(s, d);
  gload16(s + 512, d + 512);
}

#define WVM0   asm volatile("s_waitcnt vmcnt(0)" ::: "memory")
#define WVM4   asm volatile("s_waitcnt vmcnt(4)" ::: "memory")
#define WVM6   asm volatile("s_waitcnt vmcnt(6)" ::: "memory")
#define WVM8   asm volatile("s_waitcnt vmcnt(8)" ::: "memory")
#define WVM12  asm volatile("s_waitcnt vmcnt(12)" ::: "memory")
#define WAIT_ALL  asm volatile("s_waitcnt vmcnt(0) lgkmcnt(0)" ::: "memory")
#define WAIT_LDS  asm volatile("s_waitcnt lgkmcnt(0)" ::: "memory")
#define SCHEDBAR  __builtin_amdgcn_sched_barrier(0)
#define BAR       __builtin_amdgcn_s_barrier()

// ---------------- MFMA cores ----------------

__device__ inline void mma16(const unsigned short* As, const unsigned short* Bs,
                             int wr, int wc, f32x4 acc[4][4]) {
  int l = threadIdx.x & 63;
  int lr = l & 15, lg = l >> 4;
  int qoff = ((lg ^ ((lr ^ (lr >> 2)) & 3)) << 3);
  short8 a[4], b[4];
#pragma unroll
  for (int m = 0; m < 4; m++)
    a[m] = *(const short8*)(As + (wr + m * 16 + lr) * 32 + qoff);
#pragma unroll
  for (int n = 0; n < 4; n++)
    b[n] = *(const short8*)(Bs + (wc + n * 16 + lr) * 32 + qoff);
#pragma unroll
  for (int m = 0; m < 4; m++)
#pragma unroll
    for (int n = 0; n < 4; n++)
      acc[m][n] = __builtin_amdgcn_mfma_f32_16x16x32_bf16(a[m], b[n], acc[m][n], 0, 0, 0);
}

__device__ inline void mma16_dualB(const unsigned short* As, const unsigned short* Bs1,
                                   const unsigned short* Bs2, int wr, int wc,
                                   f32x4 acc1[4][4], f32x4 acc2[4][4]) {
  int l = threadIdx.x & 63;
  int lr = l & 15, lg = l >> 4;
  int qoff = ((lg ^ ((lr ^ (lr >> 2)) & 3)) << 3);
  short8 a[4], b1[4], b2[4];
#pragma unroll
  for (int m = 0; m < 4; m++)
    a[m] = *(const short8*)(As + (wr + m * 16 + lr) * 32 + qoff);
#pragma unroll
  for (int n = 0; n < 4; n++) {
    b1[n] = *(const short8*)(Bs1 + (wc + n * 16 + lr) * 32 + qoff);
    b2[n] = *(const short8*)(Bs2 + (wc + n * 16 + lr) * 32 + qoff);
  }
#pragma unroll
  for (int m = 0; m < 4; m++)
#pragma unroll
    for (int n = 0; n < 4; n++) {
      acc1[m][n] = __builtin_amdgcn_mfma_f32_16x16x32_bf16(a[m], b1[n], acc1[m][n], 0, 0, 0);
      acc2[m][n] = __builtin_amdgcn_mfma_f32_16x16x32_bf16(a[m], b2[n], acc2[m][n], 0, 0, 0);
    }
}

__device__ inline void mma16_split_reg(const unsigned short* Ash, const unsigned short* Asl,
                                       const unsigned short* Bsh, const unsigned short* Bsl,
                                       int wr, int wc, f32x4 acc[4][4]) {
  int l = threadIdx.x & 63;
  int lr = l & 15, lg = l >> 4;
  int qoff = ((lg ^ ((lr ^ (lr >> 2)) & 3)) << 3);
  short8 ah[4], al[4], bh[4], bl[4];
#pragma unroll
  for (int m = 0; m < 4; m++) {
    ah[m] = *(const short8*)(Ash + (wr + m * 16 + lr) * 32 + qoff);
    al[m] = *(const short8*)(Asl + (wr + m * 16 + lr) * 32 + qoff);
  }
#pragma unroll
  for (int n = 0; n < 4; n++) {
    bh[n] = *(const short8*)(Bsh + (wc + n * 16 + lr) * 32 + qoff);
    bl[n] = *(const short8*)(Bsl + (wc + n * 16 + lr) * 32 + qoff);
  }
#pragma unroll
  for (int m = 0; m < 4; m++)
#pragma unroll
    for (int n = 0; n < 4; n++) {
      acc[m][n] = __builtin_amdgcn_mfma_f32_16x16x32_bf16(ah[m], bh[n], acc[m][n], 0, 0, 0);
      acc[m][n] = __builtin_amdgcn_mfma_f32_16x16x32_bf16(ah[m], bl[n], acc[m][n], 0, 0, 0);
      acc[m][n] = __builtin_amdgcn_mfma_f32_16x16x32_bf16(al[m], bh[n], acc[m][n], 0, 0, 0);
    }
}

// ---------------- pack kernels ----------------

__global__ __launch_bounds__(256) void k_pack1(const float* __restrict__ src, long ld,
                                               long zs, int nc,
                                               unsigned short* __restrict__ dst) {
  __shared__ float tile[32][132];
  const float* Sp = src + (long)blockIdx.z * zs;
  int c = blockIdx.x, t = threadIdx.x;
  for (int i = 0; i < 4; i++) {
    int kt = blockIdx.y * 4 + i;
    long k0 = (long)kt * 32, n0 = (long)c * 128;
    {
      int k = t >> 3, nn = (t & 7) * 16;
      const float4* p = (const float4*)(Sp + (k0 + k) * ld + n0 + nn);
#pragma unroll
      for (int j = 0; j < 4; j++) *(float4*)&tile[k][nn + j * 4] = p[j];
    }
    __syncthreads();
    size_t cbase = ((size_t)(blockIdx.z * nc + c) * 64 + kt) * 4096;
#pragma unroll
    for (int uu = 0; uu < 2; uu++) {
      int u = t * 2 + uu;
      int n = u >> 2, qp = u & 3;
      int q = qp ^ ((n ^ (n >> 2)) & 3);
      unsigned short hb[8] __attribute__((aligned(16)));
#pragma unroll
      for (int j = 0; j < 8; j++) hb[j] = f2bf(tile[8 * q + j][n]);
      *(uint4*)(dst + cbase + u * 8) = *(const uint4*)hb;
    }
    __syncthreads();
  }
}

__global__ __launch_bounds__(256) void k_pack2(const float* __restrict__ src, long ld,
                                               long zs, int nc,
                                               unsigned short* __restrict__ dh,
                                               unsigned short* __restrict__ dl) {
  __shared__ float tile[32][132];
  const float* Sp = src + (long)blockIdx.z * zs;
  int c = blockIdx.x, t = threadIdx.x;
  for (int i = 0; i < 4; i++) {
    int kt = blockIdx.y * 4 + i;
    long k0 = (long)kt * 32, n0 = (long)c * 128;
    {
      int k = t >> 3, nn = (t & 7) * 16;
      const float4* p = (const float4*)(Sp + (k0 + k) * ld + n0 + nn);
#pragma unroll
      for (int j = 0; j < 4; j++) *(float4*)&tile[k][nn + j * 4] = p[j];
    }
    __syncthreads();
    size_t cbase = ((size_t)(blockIdx.z * nc + c) * 64 + kt) * 4096;
#pragma unroll
    for (int uu = 0; uu < 2; uu++) {
      int u = t * 2 + uu;
      int n = u >> 2, qp = u & 3;
      int q = qp ^ ((n ^ (n >> 2)) & 3);
      unsigned short hb[8] __attribute__((aligned(16)));
      unsigned short lb[8] __attribute__((aligned(16)));
#pragma unroll
      for (int j = 0; j < 8; j++) split2(tile[8 * q + j][n], hb[j], lb[j]);
      *(uint4*)(dh + cbase + u * 8) = *(const uint4*)hb;
      *(uint4*)(dl + cbase + u * 8) = *(const uint4*)lb;
    }
    __syncthreads();
  }
}

// ---------------- qkv / wo GEMMs: counted-vmcnt depth-2 (distance-2 cover) ----------------

__global__ __launch_bounds__(256) void k_qkv_s(const unsigned short* __restrict__ APh,
                                               const unsigned short* __restrict__ APl,
                                               const unsigned short* __restrict__ BPh,
                                               const unsigned short* __restrict__ BPl,
                                               float* __restrict__ C) {
  __shared__ unsigned short Ash[2 * 4096], Asl[2 * 4096], Bsh[2 * 4096], Bsl[2 * 4096];
  size_t ab = (size_t)blockIdx.y * 64 * 4096;
  size_t cb = (size_t)blockIdx.x * 64 * 4096;
  int w = threadIdx.x >> 6;
  int wr = (w >> 1) * 64, wc = (w & 1) * 64;
  // prologue: set0 -> buf0, set1 -> buf1
#pragma unroll
  for (int p = 0; p < 2; p++) {
    size_t o = (size_t)p * 4096;
    int b = p << 12;
    stageB_chunk(APh + ab + o, Ash + b);
    stageB_chunk(APl + ab + o, Asl + b);
    stageB_chunk(BPh + cb + o, Bsh + b);
    stageB_chunk(BPl + cb + o, Bsl + b);
  }
  WVM8;  // set0 done; set1 (8 ops) in flight
  BAR;
  f32x4 acc[4][4] = {};
  for (int kt = 0; kt < 64; kt++) {
    int cur = (kt & 1) << 12;
    SCHEDBAR;
    mma16_split_reg(Ash + cur, Asl + cur, Bsh + cur, Bsl + cur, wr, wc, acc);
    SCHEDBAR;
    BAR;  // all waves done reading buf cur
    if (kt + 2 < 64) {
      size_t o = (size_t)(kt + 2) * 4096;
      stageB_chunk(APh + ab + o, Ash + cur);
      stageB_chunk(APl + ab + o, Asl + cur);
      stageB_chunk(BPh + cb + o, Bsh + cur);
      stageB_chunk(BPl + cb + o, Bsl + cur);
      WVM8;  // set kt+1 done; set kt+2 in flight
    } else {
      WVM0;
    }
    BAR;
  }
  int row0 = blockIdx.y * 128, col0 = blockIdx.x * 128;
  int l = threadIdx.x & 63;
  int er = wr + ((l >> 4) << 2), ec = wc + (l & 15);
#pragma unroll
  for (int m = 0; m < 4; m++)
#pragma unroll
    for (int n = 0; n < 4; n++)
#pragma unroll
      for (int r = 0; r < 4; r++) {
        float v = acc[m][n][r];
        v = fminf(fmaxf(v, -8.f), 8.f);
        C[(size_t)(row0 + er + m * 16 + r) * QKV_N + col0 + ec + n * 16] = v;
      }
}

__global__ __launch_bounds__(256) void k_wo_s(const unsigned short* __restrict__ APh,
                                              const unsigned short* __restrict__ APl,
                                              const unsigned short* __restrict__ BPh,
                                              const unsigned short* __restrict__ BPl,
                                              const float* __restrict__ resid,
                                              float* __restrict__ x1) {
  __shared__ unsigned short Ash[2 * 4096], Asl[2 * 4096], Bsh[2 * 4096], Bsl[2 * 4096];
  size_t ab = (size_t)blockIdx.y * 64 * 4096;
  size_t cb = (size_t)blockIdx.x * 64 * 4096;
  int w = threadIdx.x >> 6;
  int wr = (w >> 1) * 64, wc = (w & 1) * 64;
#pragma unroll
  for (int p = 0; p < 2; p++) {
    size_t o = (size_t)p * 4096;
    int b = p << 12;
    stageB_chunk(APh + ab + o, Ash + b);
    stageB_chunk(APl + ab + o, Asl + b);
    stageB_chunk(BPh + cb + o, Bsh + b);
    stageB_chunk(BPl + cb + o, Bsl + b);
  }
  WVM8;
  BAR;
  f32x4 acc[4][4] = {};
  for (int kt = 0; kt < 64; kt++) {
    int cur = (kt & 1) << 12;
    SCHEDBAR;
    mma16_split_reg(Ash + cur, Asl + cur, Bsh + cur, Bsl + cur, wr, wc, acc);
    SCHEDBAR;
    BAR;
    if (kt + 2 < 64) {
      size_t o = (size_t)(kt + 2) * 4096;
      stageB_chunk(APh + ab + o, Ash + cur);
      stageB_chunk(APl + ab + o, Asl + cur);
      stageB_chunk(BPh + cb + o, Bsh + cur);
      stageB_chunk(BPl + cb + o, Bsl + cur);
      WVM8;
    } else {
      WVM0;
    }
    BAR;
  }
  int row0 = blockIdx.y * 128, col0 = blockIdx.x * 128;
  int l = threadIdx.x & 63;
  int er = wr + ((l >> 4) << 2), ec = wc + (l & 15);
#pragma unroll
  for (int m = 0; m < 4; m++)
#pragma unroll
    for (int n = 0; n < 4; n++)
#pragma unroll
      for (int r = 0; r < 4; r++) {
        size_t idx = (size_t)(row0 + er + m * 16 + r) * DMODEL + col0 + ec + n * 16;
        x1[idx] = resid[idx] + acc[m][n][r];
      }
}

// ---------------- flash attention (r8-verified core; chunk-layout epilogue) ----------------

__global__ __launch_bounds__(128) void k_flash(const unsigned short* __restrict__ qh,
                                               const unsigned short* __restrict__ ql,
                                               const unsigned short* __restrict__ kPh,
                                               const unsigned short* __restrict__ kPl,
                                               const unsigned short* __restrict__ vPh,
                                               const unsigned short* __restrict__ vPl,
                                               unsigned short* __restrict__ atPh,
                                               unsigned short* __restrict__ atPl) {
  int bid = blockIdx.x;
  int h = (bid & 7) | ((bid >> 8) << 3);
  int rt = (bid >> 3) & 31;
  int kv = h >> 2;
  int ntiles = (rt >> 1) + 1;
  __shared__ float Pds[2][32 * 132];
  int t = threadIdx.x;
  int w = t >> 6, l = t & 63;
  int lr = l & 15, lg = l >> 4;
  int qoff = ((lg ^ ((lr ^ (lr >> 2)) & 3)) << 3);
  int wrow0 = rt * 64 + w * 32;
  const unsigned short* Qbh = qh + (size_t)h * S_LEN * HD;
  const unsigned short* Qbl = ql + (size_t)h * S_LEN * HD;
  const unsigned short* Kch = kPh + (size_t)kv * 64 * 4096;
  const unsigned short* Kcl = kPl + (size_t)kv * 64 * 4096;
  const unsigned short* Vch = vPh + (size_t)kv * 64 * 4096;
  const unsigned short* Vcl = vPl + (size_t)kv * 64 * 4096;
  float* Pw = &Pds[w][0];
  float mrun[2][4], lrun[2][4];
  f32x4 Oc[2][8];
#pragma unroll
  for (int m = 0; m < 2; m++)
#pragma unroll
    for (int r = 0; r < 4; r++) { mrun[m][r] = -3.4e38f; lrun[m][r] = 0.f; }
#pragma unroll
  for (int m = 0; m < 2; m++)
#pragma unroll
    for (int n = 0; n < 8; n++)
#pragma unroll
      for (int r = 0; r < 4; r++) Oc[m][n][r] = 0.f;
  const float scale = 0.08838834764831845f;

  for (int kt = 0; kt < ntiles; kt++) {
    f32x4 Sa[2][8];
#pragma unroll
    for (int m = 0; m < 2; m++)
#pragma unroll
      for (int n = 0; n < 8; n++)
#pragma unroll
        for (int r = 0; r < 4; r++) Sa[m][n][r] = 0.f;
#pragma unroll
    for (int kst = 0; kst < 4; kst++) {
      short8 qfh[2], qfl[2];
#pragma unroll
      for (int m = 0; m < 2; m++) {
        size_t o = (size_t)(wrow0 + m * 16 + lr) * HD + kst * 32 + lg * 8;
        qfh[m] = *(const short8*)(Qbh + o);
        qfl[m] = *(const short8*)(Qbl + o);
      }
      const unsigned short* Kh = Kch + (size_t)(kt * 4 + kst) * 4096;
      const unsigned short* Kl = Kcl + (size_t)(kt * 4 + kst) * 4096;
      short8 bh[8], bl[8];
#pragma unroll
      for (int n = 0; n < 8; n++) {
        bh[n] = *(const short8*)(Kh + (n * 16 + lr) * 32 + qoff);
        bl[n] = *(const short8*)(Kl + (n * 16 + lr) * 32 + qoff);
      }
#pragma unroll
      for (int m = 0; m < 2; m++)
#pragma unroll
        for (int n = 0; n < 8; n++) {
          Sa[m][n] = __builtin_amdgcn_mfma_f32_16x16x32_bf16(qfh[m], bh[n], Sa[m][n], 0, 0, 0);
          Sa[m][n] = __builtin_amdgcn_mfma_f32_16x16x32_bf16(qfh[m], bl[n], Sa[m][n], 0, 0, 0);
          Sa[m][n] = __builtin_amdgcn_mfma_f32_16x16x32_bf16(qfl[m], bh[n], Sa[m][n], 0, 0, 0);
        }
    }
#pragma unroll
    for (int m = 0; m < 2; m++)
#pragma unroll
      for (int r = 0; r < 4; r++) {
        int row = wrow0 + m * 16 + lg * 4 + r;
        float mx = mrun[m][r];
#pragma unroll
        for (int n = 0; n < 8; n++) {
          float v = Sa[m][n][r] * scale;
          int col = kt * 128 + n * 16 + lr;
          v = (col <= row) ? v : -3.4e38f;
          Sa[m][n][r] = v;
          mx = fmaxf(mx, v);
        }
        mx = fmaxf(mx, __shfl_xor(mx, 1));
        mx = fmaxf(mx, __shfl_xor(mx, 2));
        mx = fmaxf(mx, __shfl_xor(mx, 4));
        mx = fmaxf(mx, __shfl_xor(mx, 8));
        float al_ = expf(mrun[m][r] - mx);
        float sum = 0.f;
#pragma unroll
        for (int n = 0; n < 8; n++) {
          float v = Sa[m][n][r];
          float e = (v > -1.0e37f) ? expf(v - mx) : 0.f;
          Sa[m][n][r] = e;
          sum += e;
        }
        sum += __shfl_xor(sum, 1);
        sum += __shfl_xor(sum, 2);
        sum += __shfl_xor(sum, 4);
        sum += __shfl_xor(sum, 8);
        lrun[m][r] = lrun[m][r] * al_ + sum;
        mrun[m][r] = mx;
#pragma unroll
        for (int n = 0; n < 8; n++) Oc[m][n][r] *= al_;
      }
    WAIT_LDS;
    SCHEDBAR;
#pragma unroll
    for (int m = 0; m < 2; m++)
#pragma unroll
      for (int n = 0; n < 8; n++)
#pragma unroll
        for (int r = 0; r < 4; r++)
          Pw[(m * 16 + lg * 4 + r) * 132 + n * 16 + lr] = Sa[m][n][r];
    WAIT_LDS;
    SCHEDBAR;
#pragma unroll
    for (int kst = 0; kst < 4; kst++) {
      const unsigned short* Vh = Vch + (size_t)(kt * 4 + kst) * 4096;
      const unsigned short* Vl = Vcl + (size_t)(kt * 4 + kst) * 4096;
      short8 bh[8], bl[8];
#pragma unroll
      for (int n = 0; n < 8; n++) {
        bh[n] = *(const short8*)(Vh + (n * 16 + lr) * 32 + qoff);
        bl[n] = *(const short8*)(Vl + (n * 16 + lr) * 32 + qoff);
      }
#pragma unroll
      for (int m = 0; m < 2; m++) {
        const float* pp = &Pw[(m * 16 + lr) * 132 + kst * 32 + lg * 8];
        unsigned short ahb[8] __attribute__((aligned(16)));
        unsigned short alb[8] __attribute__((aligned(16)));
#pragma unroll
        for (int j = 0; j < 8; j++) split2(pp[j], ahb[j], alb[j]);
        short8 ah = *(const short8*)ahb;
        short8 al_ = *(const short8*)alb;
#pragma unroll
        for (int n = 0; n < 8; n++) {
          Oc[m][n] = __builtin_amdgcn_mfma_f32_16x16x32_bf16(ah, bh[n], Oc[m][n], 0, 0, 0);
          Oc[m][n] = __builtin_amdgcn_mfma_f32_16x16x32_bf16(ah, bl[n], Oc[m][n], 0, 0, 0);
          Oc[m][n] = __builtin_amdgcn_mfma_f32_16x16x32_bf16(al_, bh[n], Oc[m][n], 0, 0, 0);
        }
      }
    }
  }
#pragma unroll
  for (int m = 0; m < 2; m++)
#pragma unroll
    for (int r = 0; r < 4; r++) {
      int row = wrow0 + m * 16 + lg * 4 + r;
      int rtc = row >> 7, rl = row & 127;
      int sr = (rl ^ (rl >> 2)) & 3;
      float lv = lrun[m][r];
#pragma unroll
      for (int n = 0; n < 8; n++) {
        int col = h * HD + n * 16 + lr;
        size_t off = ((size_t)(rtc * 64 + (col >> 5))) * 4096 + rl * 32 +
                     ((((col & 31) >> 3) ^ sr) << 3) + (col & 7);
        unsigned short hh, ll;
        split2(Oc[m][n][r] / lv, hh, ll);
        atPh[off] = hh;
        atPl[off] = ll;
      }
    }
}

// ---------------- MoE GEMMs: depth-3 block-cooperative counted-vmcnt (r13/r14) ----------------

__global__ __launch_bounds__(256) void k_moe1f(const unsigned short* __restrict__ h2b,
                                               const int* __restrict__ ptok,
                                               const unsigned short* __restrict__ wPa,
                                               const unsigned short* __restrict__ wPb,
                                               const int* __restrict__ meta,
                                               unsigned short* __restrict__ g) {
  int ty = blockIdx.y;
  if (ty >= meta[25]) return;
  int tt = meta[26 + ty];
  int e = tt & 7, m0 = tt >> 3;
  int nvalid = min(128, meta[e] - m0);
  const unsigned short* B1 = wPa + (size_t)(e * 16 + blockIdx.x) * 64 * 4096;
  const unsigned short* B2 = wPb + (size_t)(e * 16 + blockIdx.x) * 64 * 4096;
  __shared__ unsigned short L[3][3][4096];  // 72KB
  int w = threadIdx.x >> 6;
  int lid = threadIdx.x & 63;
  int wr = (w >> 1) * 64, wc = (w & 1) * 64;
  int r0 = w * 32 + (lid >> 2);
  int qx = lid & 3;
  int s0 = (r0 ^ (r0 >> 2)) & 3;
  long pb = (long)meta[16 + e] + m0;
  int tk0 = ptok[pb + min(r0, nvalid - 1)];
  int tk1 = ptok[pb + min(r0 + 16, nvalid - 1)];
  const unsigned short* a0 = h2b + (size_t)tk0 * DMODEL + ((qx ^ s0) << 3);
  const unsigned short* a1 = h2b + (size_t)tk1 * DMODEL + ((qx ^ s0) << 3);
#pragma unroll
  for (int p = 0; p < 3; p++) {
    size_t o = (size_t)p * 4096;
    unsigned short* dA = &L[p][0][0] + w * 1024;
    gload16(a0 + p * 32, dA);
    gload16(a1 + p * 32, dA + 512);
    stageB_chunk(B1 + o, &L[p][1][0]);
    stageB_chunk(B2 + o, &L[p][2][0]);
  }
  WVM12;
  BAR;
  f32x4 acc1[4][4] = {}, acc2[4][4] = {};
  int cur = 0;
  for (int kt = 0; kt < 64; kt++) {
    SCHEDBAR;
    mma16_dualB(&L[cur][0][0], &L[cur][1][0], &L[cur][2][0], wr, wc, acc1, acc2);
    SCHEDBAR;
    BAR;
    if (kt + 3 < 64) {
      size_t o = (size_t)(kt + 3) * 4096;
      unsigned short* dA = &L[cur][0][0] + w * 1024;
      gload16(a0 + (kt + 3) * 32, dA);
      gload16(a1 + (kt + 3) * 32, dA + 512);
      stageB_chunk(B1 + o, &L[cur][1][0]);
      stageB_chunk(B2 + o, &L[cur][2][0]);
      WVM12;
    } else if (kt + 3 == 64) {
      WVM6;
    } else {
      WVM0;
    }
    BAR;
    cur = (cur == 2) ? 0 : cur + 1;
  }
  int l = threadIdx.x & 63;
  int er = wr + ((l >> 4) << 2), ec = wc + (l & 15);
  int ktf0 = blockIdx.x * 4;
#pragma unroll
  for (int m = 0; m < 4; m++)
#pragma unroll
    for (int n = 0; n < 4; n++)
#pragma unroll
      for (int r = 0; r < 4; r++) {
        int rl = er + m * 16 + r;
        int cc = ec + n * 16;
        float a = acc1[m][n][r];
        float s = a / (1.f + expf(-a));
        unsigned short val = (rl < nvalid) ? f2bf(s * acc2[m][n][r]) : (unsigned short)0;
        int srl = (rl ^ (rl >> 2)) & 3;
        g[((size_t)(ty * 64 + ktf0 + (cc >> 5))) * 4096 + rl * 32 +
          ((((cc & 31) >> 3) ^ srl) << 3) + (cc & 7)] = val;
      }
}

__global__ __launch_bounds__(256) void k_moe2(const unsigned short* __restrict__ gP,
                                              const unsigned short* __restrict__ wP,
                                              const int* __restrict__ ptok,
                                              const float* __restrict__ pw,
                                              const int* __restrict__ meta,
                                              float* __restrict__ out) {
  int ty = blockIdx.y;
  if (ty >= meta[25]) return;
  int tt = meta[26 + ty];
  int e = tt & 7, m0 = tt >> 3;
  int nvalid = min(128, meta[e] - m0);
  long pbase = (long)meta[16 + e] + m0;
  int kc = blockIdx.z;
  const unsigned short* Ab = gP + ((size_t)ty * 64 + kc * 32) * 4096;
  const unsigned short* Bb = wP + ((size_t)(e * 16 + blockIdx.x) * 64 + kc * 32) * 4096;
  __shared__ unsigned short L[3][2][4096];  // 48KB
  int w = threadIdx.x >> 6;
  int wr = (w >> 1) * 64, wc = (w & 1) * 64;
#pragma unroll
  for (int p = 0; p < 3; p++) {
    size_t o = (size_t)p * 4096;
    stageB_chunk(Ab + o, &L[p][0][0]);
    stageB_chunk(Bb + o, &L[p][1][0]);
  }
  WVM8;
  BAR;
  f32x4 acc[4][4] = {};
  int cur = 0;
  for (int kt = 0; kt < 32; kt++) {
    SCHEDBAR;
    mma16(&L[cur][0][0], &L[cur][1][0], wr, wc, acc);
    SCHEDBAR;
    BAR;
    if (kt + 3 < 32) {
      size_t o = (size_t)(kt + 3) * 4096;
      stageB_chunk(Ab + o, &L[cur][0][0]);
      stageB_chunk(Bb + o, &L[cur][1][0]);
      WVM8;
    } else if (kt + 3 == 32) {
      WVM4;
    } else {
      WVM0;
    }
    BAR;
    cur = (cur == 2) ? 0 : cur + 1;
  }
  int col0 = blockIdx.x * 128;
  int l = threadIdx.x & 63;
  int er = wr + ((l >> 4) << 2), ec = wc + (l & 15);
#pragma unroll
  for (int m = 0; m < 4; m++)
#pragma unroll
    for (int n = 0; n < 4; n++)
#pragma unroll
      for (int r = 0; r < 4; r++) {
        int rl = er + m * 16 + r;
        if (rl < nvalid) {
          long p = pbase + rl;
          int tk = ptok[p];
          atomicAdd(&out[(size_t)tk * DMODEL + col0 + ec + n * 16], acc[m][n][r] * pw[p]);
        }
      }
}

// ---------------- small kernels ----------------

// mode 1: chunk-layout hi/lo. mode 0: row-major hi (+lo if obl) (+f32 if of).
__global__ __launch_bounds__(256) void k_ln(const float* __restrict__ x,
                                            const float* __restrict__ w,
                                            unsigned short* __restrict__ obh,
                                            unsigned short* __restrict__ obl,
                                            float* __restrict__ of, int mode) {
  int row = blockIdx.x;
  const float* xr = x + (size_t)row * DMODEL;
  float s = 0.f, ss = 0.f;
  for (int c = threadIdx.x; c < DMODEL; c += 256) {
    float v = xr[c];
    s += v; ss += v * v;
  }
#pragma unroll
  for (int o = 32; o; o >>= 1) { s += __shfl_down(s, o); ss += __shfl_down(ss, o); }
  __shared__ float rs[4], rss[4], mu_s, inv_s;
  int wid = threadIdx.x >> 6;
  if ((threadIdx.x & 63) == 0) { rs[wid] = s; rss[wid] = ss; }
  __syncthreads();
  if (threadIdx.x == 0) {
    float S1 = rs[0] + rs[1] + rs[2] + rs[3];
    float S2 = rss[0] + rss[1] + rss[2] + rss[3];
    float mu = S1 / DMODEL;
    mu_s = mu;
    inv_s = rsqrtf(S2 / DMODEL - mu * mu + 1e-5f);
  }
  __syncthreads();
  float mu = mu_s, inv = inv_s;
  int rt = row >> 7, rl = row & 127;
  int sw = (rl ^ (rl >> 2)) & 3;
  for (int c = threadIdx.x; c < DMODEL; c += 256) {
    float v = (xr[c] - mu) * inv * w[c];
    unsigned short hh, ll;
    split2(v, hh, ll);
    if (mode) {
      size_t off = ((size_t)(rt * 64 + (c >> 5))) * 4096 + rl * 32 +
                   ((((c & 31) >> 3) ^ sw) << 3) + (c & 7);
      obh[off] = hh;
      obl[off] = ll;
    } else {
      obh[(size_t)row * DMODEL + c] = hh;
      if (obl) obl[(size_t)row * DMODEL + c] = ll;
      if (of) of[(size_t)row * DMODEL + c] = v;
    }
  }
}

// RoPE: Q written row-major (split), K written directly in chunk layout (split)
__global__ void k_rope2(const float* __restrict__ qkv, unsigned short* __restrict__ qh,
                        unsigned short* __restrict__ ql, unsigned short* __restrict__ kPh,
                        unsigned short* __restrict__ kPl) {
  int t = blockIdx.x;
  int d = threadIdx.x;  // 0..63
  float pf = (float)pow(500000.0, (double)d * (1.0 / 64.0));
  float invf = 1.0f / pf;
  float ang = (float)t * invf;
  float cs = (float)cos((double)ang);
  float sn = (float)sin((double)ang);
  const float* row = qkv + (size_t)t * QKV_N;
  unsigned short hh, ll;
#pragma unroll
  for (int hq = 0; hq < NH; hq++) {
    float a = row[hq * HD + d], b = row[hq * HD + d + 64];
    size_t base = ((size_t)hq * S_LEN + t) * HD;
    split2(a * cs - b * sn, hh, ll); qh[base + d] = hh; ql[base + d] = ll;
    split2(b * cs + a * sn, hh, ll); qh[base + d + 64] = hh; ql[base + d + 64] = ll;
  }
  int tt2 = t >> 7, rl2 = t & 127;
  int s2 = (rl2 ^ (rl2 >> 2)) & 3;
#pragma unroll
  for (int kv = 0; kv < NKV; kv++) {
    float a = row[NH * HD + kv * HD + d], b = row[NH * HD + kv * HD + d + 64];
    float o0 = a * cs - b * sn;
    float o1 = b * cs + a * sn;
#pragma unroll
    for (int half = 0; half < 2; half++) {
      int col = d + half * 64;
      float v = half ? o1 : o0;
      size_t off = ((size_t)(kv * 64 + tt2 * 4 + (col >> 5))) * 4096 + rl2 * 32 +
                   ((((col & 31) >> 3) ^ s2) << 3) + (col & 7);
      split2(v, hh, ll);
      kPh[off] = hh;
      kPl[off] = ll;
    }
  }
}

__global__ __launch_bounds__(256) void k_router(const float* __restrict__ h2,
                                                const float* __restrict__ rw,
                                                int* __restrict__ topi,
                                                float* __restrict__ topw,
                                                int* __restrict__ cnt) {
  int t = blockIdx.x;
  __shared__ float hs[DMODEL];
  __shared__ float lg[NE];
  for (int c = threadIdx.x; c < DMODEL; c += 256) hs[c] = h2[(size_t)t * DMODEL + c];
  __syncthreads();
  int grp = threadIdx.x >> 5;
  int ln = threadIdx.x & 31;
  float p = 0.f;
  for (int c = ln; c < DMODEL; c += 32) p += hs[c] * rw[(size_t)grp * DMODEL + c];
#pragma unroll
  for (int o = 16; o; o >>= 1) p += __shfl_down(p, o, 32);
  if (ln == 0) lg[grp] = p;
  __syncthreads();
  if (threadIdx.x == 0) {
    float l0 = -3.4e38f; int i0 = 0;
    for (int e = 0; e < NE; e++)
      if (lg[e] > l0) { l0 = lg[e]; i0 = e; }
    float l1 = -3.4e38f; int i1 = 0;
    for (int e = 0; e < NE; e++)
      if (e != i0 && lg[e] > l1) { l1 = lg[e]; i1 = e; }
    float z = expf(l1 - l0);
    topi[t * 2] = i0; topi[t * 2 + 1] = i1;
    topw[t * 2] = 1.f / (1.f + z); topw[t * 2 + 1] = z / (1.f + z);
    atomicAdd(&cnt[i0], 1);
    atomicAdd(&cnt[i1], 1);
  }
}

__global__ void k_scan(int* __restrict__ meta) {
  if (threadIdx.x == 0 && blockIdx.x == 0) {
    int o = 0, nt = 0;
    for (int e = 0; e < NE; e++) {
      meta[16 + e] = o;
      for (int m0 = 0; m0 < meta[e]; m0 += 128) meta[26 + nt++] = (m0 << 3) | e;
      o += meta[e];
    }
    meta[24] = o;
    meta[25] = nt;
  }
}

__global__ void k_fill(const int* __restrict__ topi, const float* __restrict__ topw,
                       int* __restrict__ meta, int* __restrict__ ptok,
                       float* __restrict__ pw) {
  int t = blockIdx.x * blockDim.x + threadIdx.x;
  if (t >= S_LEN) return;
#pragma unroll
  for (int j = 0; j < 2; j++) {
    int e = topi[t * 2 + j];
    int p = atomicAdd(&meta[8 + e], 1);
    ptok[meta[16 + e] + p] = t;
    pw[meta[16 + e] + p] = topw[t * 2 + j];
  }
}

// ---------------- launch ----------------

extern "C" void kernel_launch(void* const* d_in, const int* in_sizes, int n_in,
                              void* d_out, int out_size, void* d_ws, size_t ws_size,
                              hipStream_t stream) {
  (void)in_sizes; (void)n_in; (void)out_size; (void)ws_size;
  const float* x = (const float*)d_in[0];
  const float* ln1w = (const float*)d_in[2];
  const float* ln2w = (const float*)d_in[3];
  const float* wqkv = (const float*)d_in[4];
  const float* wo = (const float*)d_in[5];
  const float* rw = (const float*)d_in[6];
  const float* w1 = (const float*)d_in[7];
  const float* v1 = (const float*)d_in[8];
  const float* w2 = (const float*)d_in[9];
  float* out = (float*)d_out;  // x1 after k_wo_s; MoE adds in place

  char* wsb = (char*)d_ws;
  const size_t MiB = 1u << 20;
  // ---- attention phase ----
  unsigned short* h1Ph = (unsigned short*)(wsb + 0 * MiB);     // 8 (chunks)
  unsigned short* h1Pl = (unsigned short*)(wsb + 8 * MiB);     // 8
  float* qkvb = (float*)(wsb + 16 * MiB);                      // 24
  unsigned short* qh = (unsigned short*)(wsb + 40 * MiB);      // 8
  unsigned short* ql = (unsigned short*)(wsb + 48 * MiB);      // 8
  unsigned short* vPh = (unsigned short*)(wsb + 60 * MiB);     // 2
  unsigned short* vPl = (unsigned short*)(wsb + 62 * MiB);     // 2
  unsigned short* kPh = (unsigned short*)(wsb + 64 * MiB);     // 2
  unsigned short* kPl = (unsigned short*)(wsb + 66 * MiB);     // 2
  unsigned short* atPh = (unsigned short*)(wsb + 68 * MiB);    // 8 (chunks)
  unsigned short* atPl = (unsigned short*)(wsb + 76 * MiB);    // 8
  unsigned short* wqkvPh = (unsigned short*)(wsb + 84 * MiB);  // 12
  unsigned short* wqkvPl = (unsigned short*)(wsb + 96 * MiB);  // 12
  unsigned short* woPh = (unsigned short*)(wsb + 108 * MiB);   // 8
  unsigned short* woPl = (unsigned short*)(wsb + 116 * MiB);   // 8
  // ---- MoE phase (overlays; attention buffers dead) ----
  unsigned short* h2b = (unsigned short*)(wsb + 0 * MiB);      // 8 (over h1Ph)
  unsigned short* g = (unsigned short*)(wsb + 16 * MiB);       // 20 (over qkvb)
  float* h2f = (float*)(wsb + 40 * MiB);                       // 16 (over qh/ql)
  unsigned short* wPa = (unsigned short*)(wsb + 40 * MiB);     // 64 (after router)
  unsigned short* wPb = (unsigned short*)(wsb + 104 * MiB);    // 64
  char* small = wsb + 168 * MiB;
  int* topi = (int*)small;
  float* topw = (float*)(small + 16384);
  int* ptok = (int*)(small + 32768);
  float* pw = (float*)(small + 49152);
  int* meta = (int*)(small + 65536);  // 128 ints

  // ---- pack attention weights ----
  k_pack2<<<dim3(QKV_N / 128, 16, 1), 256, 0, stream>>>(wqkv, QKV_N, 0, QKV_N / 128,
                                                        wqkvPh, wqkvPl);
  k_pack2<<<dim3(DMODEL / 128, 16, 1), 256, 0, stream>>>(wo, DMODEL, 0, DMODEL / 128,
                                                         woPh, woPl);

  // ---- attention sublayer (fp32-emulated) ----
  k_ln<<<S_LEN, 256, 0, stream>>>(x, ln1w, h1Ph, h1Pl, (float*)nullptr, 1);
  k_qkv_s<<<dim3(QKV_N / 128, S_LEN / 128), 256, 0, stream>>>(h1Ph, h1Pl, wqkvPh, wqkvPl,
                                                              qkvb);
  k_rope2<<<S_LEN, 64, 0, stream>>>(qkvb, qh, ql, kPh, kPl);
  k_pack2<<<dim3(1, 16, NKV), 256, 0, stream>>>(qkvb + (NH + NKV) * HD, QKV_N, HD, 1,
                                                vPh, vPl);
  k_flash<<<512, 128, 0, stream>>>(qh, ql, kPh, kPl, vPh, vPl, atPh, atPl);
  k_wo_s<<<dim3(16, 16), 256, 0, stream>>>(atPh, atPl, woPh, woPl, x, out);

  // ---- MoE sublayer ----
  k_ln<<<S_LEN, 256, 0, stream>>>(out, ln2w, h2b, (unsigned short*)nullptr, h2f, 0);
  hipMemsetAsync(meta, 0, 512, stream);
  k_router<<<S_LEN, 256, 0, stream>>>(h2f, rw, topi, topw, meta);
  k_scan<<<1, 64, 0, stream>>>(meta);
  k_fill<<<8, 256, 0, stream>>>(topi, topw, meta, ptok, pw);
  k_pack1<<<dim3(16, 16, NE), 256, 0, stream>>>(w1, FF, (long)DMODEL * FF, 16, wPa);
  k_pack1<<<dim3(16, 16, NE), 256, 0, stream>>>(v1, FF, (long)DMODEL * FF, 16, wPb);
  k_moe1f<<<dim3(16, 40), 256, 0, stream>>>(h2b, ptok, wPa, wPb, meta, g);
  k_pack1<<<dim3(16, 16, NE), 256, 0, stream>>>(w2, DMODEL, (long)FF * DMODEL, 16, wPa);
  k_moe2<<<dim3(16, 40, 2), 256, 0, stream>>>(g, wPa, ptok, pw, meta, out);
}

// Round 16
// 835.264 us; speedup vs baseline: 1.1988x; 1.0891x over previous
//
#include <hip/hip_runtime.h>

#define S_LEN 2048
#define DMODEL 2048
#define NH 16
#define NKV 4
#define HD 128
#define NE 8
#define FF 2048
#define QKV_N 3072   // (H + 2*KV) * HD

typedef __attribute__((ext_vector_type(8))) short short8;
typedef __attribute__((ext_vector_type(4))) float f32x4;

__device__ inline unsigned short f2bf(float f) {
  unsigned int u = __builtin_bit_cast(unsigned int, f);
  u += 0x7fffu + ((u >> 16) & 1u);
  return (unsigned short)(u >> 16);
}
__device__ inline float bf2f(unsigned short h) {
  unsigned int u = ((unsigned int)h) << 16;
  return __builtin_bit_cast(float, u);
}
__device__ inline void split2(float v, unsigned short& h, unsigned short& l) {
  h = f2bf(v);
  l = f2bf(v - bf2f(h));
}

// ======== chunk format (verified r3-r15): 8KB = 128 rows x 32 k bf16 ========
// element (row, k=8q+j) at ushort off row*32 + ((q ^ s(row))<<3) + j, s=(row^(row>>2))&3

__device__ inline void gload16(const void* g, void* l) {
  __builtin_amdgcn_global_load_lds((const __attribute__((address_space(1))) unsigned int*)g,
                                   (__attribute__((address_space(3))) unsigned int*)l,
                                   16, 0, 0);
}
// 256-thread cooperative full-chunk stage (2 gloads/lane)
__device__ inline void stageB_chunk(const unsigned short* __restrict__ chunk,
                                    unsigned short* __restrict__ lds) {
  int w = threadIdx.x >> 6, l = threadIdx.x & 63;
  const unsigned short* s = chunk + w * 1024 + l * 8;
  unsigned short* d = lds + w * 1024;
  gload16(s, d);
  gload16(s + 512, d + 512);
}
// 512-thread cooperative full-chunk stage (1 gload/lane)
__device__ inline void stageB_chunk8(const unsigned short* __restrict__ chunk,
                                     unsigned short* __restrict__ lds) {
  int w = threadIdx.x >> 6, l = threadIdx.x & 63;
  gload16(chunk + w * 512 + l * 8, lds + w * 512);
}

#define WVM0   asm volatile("s_waitcnt vmcnt(0)" ::: "memory")
#define WVM3   asm volatile("s_waitcnt vmcnt(3)" ::: "memory")
#define WVM4   asm volatile("s_waitcnt vmcnt(4)" ::: "memory")
#define WVM6   asm volatile("s_waitcnt vmcnt(6)" ::: "memory")
#define WVM8   asm volatile("s_waitcnt vmcnt(8)" ::: "memory")
#define WVM12  asm volatile("s_waitcnt vmcnt(12)" ::: "memory")
#define WAIT_ALL  asm volatile("s_waitcnt vmcnt(0) lgkmcnt(0)" ::: "memory")
#define WAIT_LDS  asm volatile("s_waitcnt lgkmcnt(0)" ::: "memory")
#define SCHEDBAR  __builtin_amdgcn_sched_barrier(0)
#define BAR       __builtin_amdgcn_s_barrier()

// ---------------- MFMA cores ----------------

__device__ inline void mma16(const unsigned short* As, const unsigned short* Bs,
                             int wr, int wc, f32x4 acc[4][4]) {
  int l = threadIdx.x & 63;
  int lr = l & 15, lg = l >> 4;
  int qoff = ((lg ^ ((lr ^ (lr >> 2)) & 3)) << 3);
  short8 a[4], b[4];
#pragma unroll
  for (int m = 0; m < 4; m++)
    a[m] = *(const short8*)(As + (wr + m * 16 + lr) * 32 + qoff);
#pragma unroll
  for (int n = 0; n < 4; n++)
    b[n] = *(const short8*)(Bs + (wc + n * 16 + lr) * 32 + qoff);
#pragma unroll
  for (int m = 0; m < 4; m++)
#pragma unroll
    for (int n = 0; n < 4; n++)
      acc[m][n] = __builtin_amdgcn_mfma_f32_16x16x32_bf16(a[m], b[n], acc[m][n], 0, 0, 0);
}

// 8-wave variant: wave computes 32x64 (2 m-frags x 4 n-frags), dual B
__device__ inline void mma16_dualB24(const unsigned short* As, const unsigned short* Bs1,
                                     const unsigned short* Bs2, int wr, int wc,
                                     f32x4 acc1[2][4], f32x4 acc2[2][4]) {
  int l = threadIdx.x & 63;
  int lr = l & 15, lg = l >> 4;
  int qoff = ((lg ^ ((lr ^ (lr >> 2)) & 3)) << 3);
  short8 a[2], b1[4], b2[4];
#pragma unroll
  for (int m = 0; m < 2; m++)
    a[m] = *(const short8*)(As + (wr + m * 16 + lr) * 32 + qoff);
#pragma unroll
  for (int n = 0; n < 4; n++) {
    b1[n] = *(const short8*)(Bs1 + (wc + n * 16 + lr) * 32 + qoff);
    b2[n] = *(const short8*)(Bs2 + (wc + n * 16 + lr) * 32 + qoff);
  }
#pragma unroll
  for (int m = 0; m < 2; m++)
#pragma unroll
    for (int n = 0; n < 4; n++) {
      acc1[m][n] = __builtin_amdgcn_mfma_f32_16x16x32_bf16(a[m], b1[n], acc1[m][n], 0, 0, 0);
      acc2[m][n] = __builtin_amdgcn_mfma_f32_16x16x32_bf16(a[m], b2[n], acc2[m][n], 0, 0, 0);
    }
}

__device__ inline void mma16_split_reg(const unsigned short* Ash, const unsigned short* Asl,
                                       const unsigned short* Bsh, const unsigned short* Bsl,
                                       int wr, int wc, f32x4 acc[4][4]) {
  int l = threadIdx.x & 63;
  int lr = l & 15, lg = l >> 4;
  int qoff = ((lg ^ ((lr ^ (lr >> 2)) & 3)) << 3);
  short8 ah[4], al[4], bh[4], bl[4];
#pragma unroll
  for (int m = 0; m < 4; m++) {
    ah[m] = *(const short8*)(Ash + (wr + m * 16 + lr) * 32 + qoff);
    al[m] = *(const short8*)(Asl + (wr + m * 16 + lr) * 32 + qoff);
  }
#pragma unroll
  for (int n = 0; n < 4; n++) {
    bh[n] = *(const short8*)(Bsh + (wc + n * 16 + lr) * 32 + qoff);
    bl[n] = *(const short8*)(Bsl + (wc + n * 16 + lr) * 32 + qoff);
  }
#pragma unroll
  for (int m = 0; m < 4; m++)
#pragma unroll
    for (int n = 0; n < 4; n++) {
      acc[m][n] = __builtin_amdgcn_mfma_f32_16x16x32_bf16(ah[m], bh[n], acc[m][n], 0, 0, 0);
      acc[m][n] = __builtin_amdgcn_mfma_f32_16x16x32_bf16(ah[m], bl[n], acc[m][n], 0, 0, 0);
      acc[m][n] = __builtin_amdgcn_mfma_f32_16x16x32_bf16(al[m], bh[n], acc[m][n], 0, 0, 0);
    }
}

// ---------------- pack kernels ----------------

__global__ __launch_bounds__(256) void k_pack1(const float* __restrict__ src, long ld,
                                               long zs, int nc,
                                               unsigned short* __restrict__ dst) {
  __shared__ float tile[32][132];
  const float* Sp = src + (long)blockIdx.z * zs;
  int c = blockIdx.x, t = threadIdx.x;
  for (int i = 0; i < 4; i++) {
    int kt = blockIdx.y * 4 + i;
    long k0 = (long)kt * 32, n0 = (long)c * 128;
    {
      int k = t >> 3, nn = (t & 7) * 16;
      const float4* p = (const float4*)(Sp + (k0 + k) * ld + n0 + nn);
#pragma unroll
      for (int j = 0; j < 4; j++) *(float4*)&tile[k][nn + j * 4] = p[j];
    }
    __syncthreads();
    size_t cbase = ((size_t)(blockIdx.z * nc + c) * 64 + kt) * 4096;
#pragma unroll
    for (int uu = 0; uu < 2; uu++) {
      int u = t * 2 + uu;
      int n = u >> 2, qp = u & 3;
      int q = qp ^ ((n ^ (n >> 2)) & 3);
      unsigned short hb[8] __attribute__((aligned(16)));
#pragma unroll
      for (int j = 0; j < 8; j++) hb[j] = f2bf(tile[8 * q + j][n]);
      *(uint4*)(dst + cbase + u * 8) = *(const uint4*)hb;
    }
    __syncthreads();
  }
}

__global__ __launch_bounds__(256) void k_pack2(const float* __restrict__ src, long ld,
                                               long zs, int nc,
                                               unsigned short* __restrict__ dh,
                                               unsigned short* __restrict__ dl) {
  __shared__ float tile[32][132];
  const float* Sp = src + (long)blockIdx.z * zs;
  int c = blockIdx.x, t = threadIdx.x;
  for (int i = 0; i < 4; i++) {
    int kt = blockIdx.y * 4 + i;
    long k0 = (long)kt * 32, n0 = (long)c * 128;
    {
      int k = t >> 3, nn = (t & 7) * 16;
      const float4* p = (const float4*)(Sp + (k0 + k) * ld + n0 + nn);
#pragma unroll
      for (int j = 0; j < 4; j++) *(float4*)&tile[k][nn + j * 4] = p[j];
    }
    __syncthreads();
    size_t cbase = ((size_t)(blockIdx.z * nc + c) * 64 + kt) * 4096;
#pragma unroll
    for (int uu = 0; uu < 2; uu++) {
      int u = t * 2 + uu;
      int n = u >> 2, qp = u & 3;
      int q = qp ^ ((n ^ (n >> 2)) & 3);
      unsigned short hb[8] __attribute__((aligned(16)));
      unsigned short lb[8] __attribute__((aligned(16)));
#pragma unroll
      for (int j = 0; j < 8; j++) split2(tile[8 * q + j][n], hb[j], lb[j]);
      *(uint4*)(dh + cbase + u * 8) = *(const uint4*)hb;
      *(uint4*)(dl + cbase + u * 8) = *(const uint4*)lb;
    }
    __syncthreads();
  }
}

// ---------------- qkv / wo GEMMs (r15 form) ----------------

__global__ __launch_bounds__(256) void k_qkv_s(const unsigned short* __restrict__ APh,
                                               const unsigned short* __restrict__ APl,
                                               const unsigned short* __restrict__ BPh,
                                               const unsigned short* __restrict__ BPl,
                                               float* __restrict__ C) {
  __shared__ unsigned short Ash[2 * 4096], Asl[2 * 4096], Bsh[2 * 4096], Bsl[2 * 4096];
  size_t ab = (size_t)blockIdx.y * 64 * 4096;
  size_t cb = (size_t)blockIdx.x * 64 * 4096;
  int w = threadIdx.x >> 6;
  int wr = (w >> 1) * 64, wc = (w & 1) * 64;
#pragma unroll
  for (int p = 0; p < 2; p++) {
    size_t o = (size_t)p * 4096;
    int b = p << 12;
    stageB_chunk(APh + ab + o, Ash + b);
    stageB_chunk(APl + ab + o, Asl + b);
    stageB_chunk(BPh + cb + o, Bsh + b);
    stageB_chunk(BPl + cb + o, Bsl + b);
  }
  WVM8;
  BAR;
  f32x4 acc[4][4] = {};
  for (int kt = 0; kt < 64; kt++) {
    int cur = (kt & 1) << 12;
    SCHEDBAR;
    mma16_split_reg(Ash + cur, Asl + cur, Bsh + cur, Bsl + cur, wr, wc, acc);
    SCHEDBAR;
    BAR;
    if (kt + 2 < 64) {
      size_t o = (size_t)(kt + 2) * 4096;
      stageB_chunk(APh + ab + o, Ash + cur);
      stageB_chunk(APl + ab + o, Asl + cur);
      stageB_chunk(BPh + cb + o, Bsh + cur);
      stageB_chunk(BPl + cb + o, Bsl + cur);
      WVM8;
    } else {
      WVM0;
    }
    BAR;
  }
  int row0 = blockIdx.y * 128, col0 = blockIdx.x * 128;
  int l = threadIdx.x & 63;
  int er = wr + ((l >> 4) << 2), ec = wc + (l & 15);
#pragma unroll
  for (int m = 0; m < 4; m++)
#pragma unroll
    for (int n = 0; n < 4; n++)
#pragma unroll
      for (int r = 0; r < 4; r++) {
        float v = acc[m][n][r];
        v = fminf(fmaxf(v, -8.f), 8.f);
        C[(size_t)(row0 + er + m * 16 + r) * QKV_N + col0 + ec + n * 16] = v;
      }
}

__global__ __launch_bounds__(256) void k_wo_s(const unsigned short* __restrict__ APh,
                                              const unsigned short* __restrict__ APl,
                                              const unsigned short* __restrict__ BPh,
                                              const unsigned short* __restrict__ BPl,
                                              const float* __restrict__ resid,
                                              float* __restrict__ x1) {
  __shared__ unsigned short Ash[2 * 4096], Asl[2 * 4096], Bsh[2 * 4096], Bsl[2 * 4096];
  size_t ab = (size_t)blockIdx.y * 64 * 4096;
  size_t cb = (size_t)blockIdx.x * 64 * 4096;
  int w = threadIdx.x >> 6;
  int wr = (w >> 1) * 64, wc = (w & 1) * 64;
#pragma unroll
  for (int p = 0; p < 2; p++) {
    size_t o = (size_t)p * 4096;
    int b = p << 12;
    stageB_chunk(APh + ab + o, Ash + b);
    stageB_chunk(APl + ab + o, Asl + b);
    stageB_chunk(BPh + cb + o, Bsh + b);
    stageB_chunk(BPl + cb + o, Bsl + b);
  }
  WVM8;
  BAR;
  f32x4 acc[4][4] = {};
  for (int kt = 0; kt < 64; kt++) {
    int cur = (kt & 1) << 12;
    SCHEDBAR;
    mma16_split_reg(Ash + cur, Asl + cur, Bsh + cur, Bsl + cur, wr, wc, acc);
    SCHEDBAR;
    BAR;
    if (kt + 2 < 64) {
      size_t o = (size_t)(kt + 2) * 4096;
      stageB_chunk(APh + ab + o, Ash + cur);
      stageB_chunk(APl + ab + o, Asl + cur);
      stageB_chunk(BPh + cb + o, Bsh + cur);
      stageB_chunk(BPl + cb + o, Bsl + cur);
      WVM8;
    } else {
      WVM0;
    }
    BAR;
  }
  int row0 = blockIdx.y * 128, col0 = blockIdx.x * 128;
  int l = threadIdx.x & 63;
  int er = wr + ((l >> 4) << 2), ec = wc + (l & 15);
#pragma unroll
  for (int m = 0; m < 4; m++)
#pragma unroll
    for (int n = 0; n < 4; n++)
#pragma unroll
      for (int r = 0; r < 4; r++) {
        size_t idx = (size_t)(row0 + er + m * 16 + r) * DMODEL + col0 + ec + n * 16;
        x1[idx] = resid[idx] + acc[m][n][r];
      }
}

// ---------------- flash attention (r8-verified core; chunk-layout epilogue) ----------------

__global__ __launch_bounds__(128) void k_flash(const unsigned short* __restrict__ qh,
                                               const unsigned short* __restrict__ ql,
                                               const unsigned short* __restrict__ kPh,
                                               const unsigned short* __restrict__ kPl,
                                               const unsigned short* __restrict__ vPh,
                                               const unsigned short* __restrict__ vPl,
                                               unsigned short* __restrict__ atPh,
                                               unsigned short* __restrict__ atPl) {
  int bid = blockIdx.x;
  int h = (bid & 7) | ((bid >> 8) << 3);
  int rt = (bid >> 3) & 31;
  int kv = h >> 2;
  int ntiles = (rt >> 1) + 1;
  __shared__ float Pds[2][32 * 132];
  int t = threadIdx.x;
  int w = t >> 6, l = t & 63;
  int lr = l & 15, lg = l >> 4;
  int qoff = ((lg ^ ((lr ^ (lr >> 2)) & 3)) << 3);
  int wrow0 = rt * 64 + w * 32;
  const unsigned short* Qbh = qh + (size_t)h * S_LEN * HD;
  const unsigned short* Qbl = ql + (size_t)h * S_LEN * HD;
  const unsigned short* Kch = kPh + (size_t)kv * 64 * 4096;
  const unsigned short* Kcl = kPl + (size_t)kv * 64 * 4096;
  const unsigned short* Vch = vPh + (size_t)kv * 64 * 4096;
  const unsigned short* Vcl = vPl + (size_t)kv * 64 * 4096;
  float* Pw = &Pds[w][0];
  float mrun[2][4], lrun[2][4];
  f32x4 Oc[2][8];
#pragma unroll
  for (int m = 0; m < 2; m++)
#pragma unroll
    for (int r = 0; r < 4; r++) { mrun[m][r] = -3.4e38f; lrun[m][r] = 0.f; }
#pragma unroll
  for (int m = 0; m < 2; m++)
#pragma unroll
    for (int n = 0; n < 8; n++)
#pragma unroll
      for (int r = 0; r < 4; r++) Oc[m][n][r] = 0.f;
  const float scale = 0.08838834764831845f;

  for (int kt = 0; kt < ntiles; kt++) {
    f32x4 Sa[2][8];
#pragma unroll
    for (int m = 0; m < 2; m++)
#pragma unroll
      for (int n = 0; n < 8; n++)
#pragma unroll
        for (int r = 0; r < 4; r++) Sa[m][n][r] = 0.f;
#pragma unroll
    for (int kst = 0; kst < 4; kst++) {
      short8 qfh[2], qfl[2];
#pragma unroll
      for (int m = 0; m < 2; m++) {
        size_t o = (size_t)(wrow0 + m * 16 + lr) * HD + kst * 32 + lg * 8;
        qfh[m] = *(const short8*)(Qbh + o);
        qfl[m] = *(const short8*)(Qbl + o);
      }
      const unsigned short* Kh = Kch + (size_t)(kt * 4 + kst) * 4096;
      const unsigned short* Kl = Kcl + (size_t)(kt * 4 + kst) * 4096;
      short8 bh[8], bl[8];
#pragma unroll
      for (int n = 0; n < 8; n++) {
        bh[n] = *(const short8*)(Kh + (n * 16 + lr) * 32 + qoff);
        bl[n] = *(const short8*)(Kl + (n * 16 + lr) * 32 + qoff);
      }
#pragma unroll
      for (int m = 0; m < 2; m++)
#pragma unroll
        for (int n = 0; n < 8; n++) {
          Sa[m][n] = __builtin_amdgcn_mfma_f32_16x16x32_bf16(qfh[m], bh[n], Sa[m][n], 0, 0, 0);
          Sa[m][n] = __builtin_amdgcn_mfma_f32_16x16x32_bf16(qfh[m], bl[n], Sa[m][n], 0, 0, 0);
          Sa[m][n] = __builtin_amdgcn_mfma_f32_16x16x32_bf16(qfl[m], bh[n], Sa[m][n], 0, 0, 0);
        }
    }
#pragma unroll
    for (int m = 0; m < 2; m++)
#pragma unroll
      for (int r = 0; r < 4; r++) {
        int row = wrow0 + m * 16 + lg * 4 + r;
        float mx = mrun[m][r];
#pragma unroll
        for (int n = 0; n < 8; n++) {
          float v = Sa[m][n][r] * scale;
          int col = kt * 128 + n * 16 + lr;
          v = (col <= row) ? v : -3.4e38f;
          Sa[m][n][r] = v;
          mx = fmaxf(mx, v);
        }
        mx = fmaxf(mx, __shfl_xor(mx, 1));
        mx = fmaxf(mx, __shfl_xor(mx, 2));
        mx = fmaxf(mx, __shfl_xor(mx, 4));
        mx = fmaxf(mx, __shfl_xor(mx, 8));
        float al_ = expf(mrun[m][r] - mx);
        float sum = 0.f;
#pragma unroll
        for (int n = 0; n < 8; n++) {
          float v = Sa[m][n][r];
          float e = (v > -1.0e37f) ? expf(v - mx) : 0.f;
          Sa[m][n][r] = e;
          sum += e;
        }
        sum += __shfl_xor(sum, 1);
        sum += __shfl_xor(sum, 2);
        sum += __shfl_xor(sum, 4);
        sum += __shfl_xor(sum, 8);
        lrun[m][r] = lrun[m][r] * al_ + sum;
        mrun[m][r] = mx;
#pragma unroll
        for (int n = 0; n < 8; n++) Oc[m][n][r] *= al_;
      }
    WAIT_LDS;
    SCHEDBAR;
#pragma unroll
    for (int m = 0; m < 2; m++)
#pragma unroll
      for (int n = 0; n < 8; n++)
#pragma unroll
        for (int r = 0; r < 4; r++)
          Pw[(m * 16 + lg * 4 + r) * 132 + n * 16 + lr] = Sa[m][n][r];
    WAIT_LDS;
    SCHEDBAR;
#pragma unroll
    for (int kst = 0; kst < 4; kst++) {
      const unsigned short* Vh = Vch + (size_t)(kt * 4 + kst) * 4096;
      const unsigned short* Vl = Vcl + (size_t)(kt * 4 + kst) * 4096;
      short8 bh[8], bl[8];
#pragma unroll
      for (int n = 0; n < 8; n++) {
        bh[n] = *(const short8*)(Vh + (n * 16 + lr) * 32 + qoff);
        bl[n] = *(const short8*)(Vl + (n * 16 + lr) * 32 + qoff);
      }
#pragma unroll
      for (int m = 0; m < 2; m++) {
        const float* pp = &Pw[(m * 16 + lr) * 132 + kst * 32 + lg * 8];
        unsigned short ahb[8] __attribute__((aligned(16)));
        unsigned short alb[8] __attribute__((aligned(16)));
#pragma unroll
        for (int j = 0; j < 8; j++) split2(pp[j], ahb[j], alb[j]);
        short8 ah = *(const short8*)ahb;
        short8 al_ = *(const short8*)alb;
#pragma unroll
        for (int n = 0; n < 8; n++) {
          Oc[m][n] = __builtin_amdgcn_mfma_f32_16x16x32_bf16(ah, bh[n], Oc[m][n], 0, 0, 0);
          Oc[m][n] = __builtin_amdgcn_mfma_f32_16x16x32_bf16(ah, bl[n], Oc[m][n], 0, 0, 0);
          Oc[m][n] = __builtin_amdgcn_mfma_f32_16x16x32_bf16(al_, bh[n], Oc[m][n], 0, 0, 0);
        }
      }
    }
  }
#pragma unroll
  for (int m = 0; m < 2; m++)
#pragma unroll
    for (int r = 0; r < 4; r++) {
      int row = wrow0 + m * 16 + lg * 4 + r;
      int rtc = row >> 7, rl = row & 127;
      int sr = (rl ^ (rl >> 2)) & 3;
      float lv = lrun[m][r];
#pragma unroll
      for (int n = 0; n < 8; n++) {
        int col = h * HD + n * 16 + lr;
        size_t off = ((size_t)(rtc * 64 + (col >> 5))) * 4096 + rl * 32 +
                     ((((col & 31) >> 3) ^ sr) << 3) + (col & 7);
        unsigned short hh, ll;
        split2(Oc[m][n][r] / lv, hh, ll);
        atPh[off] = hh;
        atPl[off] = ll;
      }
    }
}

// ---------------- MoE GEMMs ----------------

// moe1f: 8-wave (512 thr), wave = 32x64 quadrant; depth-3 counted vmcnt
__global__ __launch_bounds__(512, 4) void k_moe1f(const unsigned short* __restrict__ h2b,
                                                  const int* __restrict__ ptok,
                                                  const unsigned short* __restrict__ wPa,
                                                  const unsigned short* __restrict__ wPb,
                                                  const int* __restrict__ meta,
                                                  unsigned short* __restrict__ g) {
  int ty = blockIdx.y;
  if (ty >= meta[25]) return;
  int tt = meta[26 + ty];
  int e = tt & 7, m0 = tt >> 3;
  int nvalid = min(128, meta[e] - m0);
  const unsigned short* B1 = wPa + (size_t)(e * 16 + blockIdx.x) * 64 * 4096;
  const unsigned short* B2 = wPb + (size_t)(e * 16 + blockIdx.x) * 64 * 4096;
  __shared__ unsigned short L[3][3][4096];  // 72KB
  int tid = threadIdx.x;
  int w = tid >> 6;
  int lid = tid & 63;
  int wr = (w & 3) * 32, wc = (w >> 2) * 64;  // 4 row-quadrants x 2 col-quadrants
  // per-lane gathered A source: 512 lanes cover 128 rows x 4 q-slots
  int r0 = w * 16 + (lid >> 2);  // 0..127
  int qx = lid & 3;
  int s0 = (r0 ^ (r0 >> 2)) & 3;
  long pb = (long)meta[16 + e] + m0;
  int tk0 = ptok[pb + min(r0, nvalid - 1)];
  const unsigned short* a0 = h2b + (size_t)tk0 * DMODEL + ((qx ^ s0) << 3);
#pragma unroll
  for (int p = 0; p < 3; p++) {
    size_t o = (size_t)p * 4096;
    gload16(a0 + p * 32, &L[p][0][0] + w * 512);
    stageB_chunk8(B1 + o, &L[p][1][0]);
    stageB_chunk8(B2 + o, &L[p][2][0]);
  }
  WVM6;  // set0 (3 ops/wave) done; sets 1,2 in flight
  BAR;
  f32x4 acc1[2][4] = {}, acc2[2][4] = {};
  int cur = 0;
  for (int kt = 0; kt < 64; kt++) {
    SCHEDBAR;
    mma16_dualB24(&L[cur][0][0], &L[cur][1][0], &L[cur][2][0], wr, wc, acc1, acc2);
    SCHEDBAR;
    BAR;
    if (kt + 3 < 64) {
      size_t o = (size_t)(kt + 3) * 4096;
      gload16(a0 + (kt + 3) * 32, &L[cur][0][0] + w * 512);
      stageB_chunk8(B1 + o, &L[cur][1][0]);
      stageB_chunk8(B2 + o, &L[cur][2][0]);
      WVM6;  // set kt+1 done; kt+2, kt+3 in flight
    } else if (kt + 3 == 64) {
      WVM3;
    } else {
      WVM0;
    }
    BAR;
    cur = (cur == 2) ? 0 : cur + 1;
  }
  int lr = lid & 15;
  int er = wr + ((lid >> 4) << 2), ec = wc + lr;
  int ktf0 = blockIdx.x * 4;
#pragma unroll
  for (int m = 0; m < 2; m++)
#pragma unroll
    for (int n = 0; n < 4; n++)
#pragma unroll
      for (int r = 0; r < 4; r++) {
        int rl = er + m * 16 + r;
        int cc = ec + n * 16;
        float a = acc1[m][n][r];
        float s = a / (1.f + expf(-a));
        unsigned short val = (rl < nvalid) ? f2bf(s * acc2[m][n][r]) : (unsigned short)0;
        int srl = (rl ^ (rl >> 2)) & 3;
        g[((size_t)(ty * 64 + ktf0 + (cc >> 5))) * 4096 + rl * 32 +
          ((((cc & 31) >> 3) ^ srl) << 3) + (cc & 7)] = val;
      }
}

__global__ __launch_bounds__(256) void k_moe2(const unsigned short* __restrict__ gP,
                                              const unsigned short* __restrict__ wP,
                                              const int* __restrict__ ptok,
                                              const float* __restrict__ pw,
                                              const int* __restrict__ meta,
                                              float* __restrict__ out) {
  int ty = blockIdx.y;
  if (ty >= meta[25]) return;
  int tt = meta[26 + ty];
  int e = tt & 7, m0 = tt >> 3;
  int nvalid = min(128, meta[e] - m0);
  long pbase = (long)meta[16 + e] + m0;
  int kc = blockIdx.z;
  const unsigned short* Ab = gP + ((size_t)ty * 64 + kc * 32) * 4096;
  const unsigned short* Bb = wP + ((size_t)(e * 16 + blockIdx.x) * 64 + kc * 32) * 4096;
  __shared__ unsigned short L[3][2][4096];  // 48KB
  int w = threadIdx.x >> 6;
  int wr = (w >> 1) * 64, wc = (w & 1) * 64;
#pragma unroll
  for (int p = 0; p < 3; p++) {
    size_t o = (size_t)p * 4096;
    stageB_chunk(Ab + o, &L[p][0][0]);
    stageB_chunk(Bb + o, &L[p][1][0]);
  }
  WVM8;
  BAR;
  f32x4 acc[4][4] = {};
  int cur = 0;
  for (int kt = 0; kt < 32; kt++) {
    SCHEDBAR;
    mma16(&L[cur][0][0], &L[cur][1][0], wr, wc, acc);
    SCHEDBAR;
    BAR;
    if (kt + 3 < 32) {
      size_t o = (size_t)(kt + 3) * 4096;
      stageB_chunk(Ab + o, &L[cur][0][0]);
      stageB_chunk(Bb + o, &L[cur][1][0]);
      WVM8;
    } else if (kt + 3 == 32) {
      WVM4;
    } else {
      WVM0;
    }
    BAR;
    cur = (cur == 2) ? 0 : cur + 1;
  }
  int col0 = blockIdx.x * 128;
  int l = threadIdx.x & 63;
  int er = wr + ((l >> 4) << 2), ec = wc + (l & 15);
#pragma unroll
  for (int m = 0; m < 4; m++)
#pragma unroll
    for (int n = 0; n < 4; n++)
#pragma unroll
      for (int r = 0; r < 4; r++) {
        int rl = er + m * 16 + r;
        if (rl < nvalid) {
          long p = pbase + rl;
          int tk = ptok[p];
          atomicAdd(&out[(size_t)tk * DMODEL + col0 + ec + n * 16], acc[m][n][r] * pw[p]);
        }
      }
}

// ---------------- small kernels ----------------

__global__ __launch_bounds__(256) void k_ln(const float* __restrict__ x,
                                            const float* __restrict__ w,
                                            unsigned short* __restrict__ obh,
                                            unsigned short* __restrict__ obl,
                                            float* __restrict__ of, int mode) {
  int row = blockIdx.x;
  const float* xr = x + (size_t)row * DMODEL;
  float s = 0.f, ss = 0.f;
  for (int c = threadIdx.x; c < DMODEL; c += 256) {
    float v = xr[c];
    s += v; ss += v * v;
  }
#pragma unroll
  for (int o = 32; o; o >>= 1) { s += __shfl_down(s, o); ss += __shfl_down(ss, o); }
  __shared__ float rs[4], rss[4], mu_s, inv_s;
  int wid = threadIdx.x >> 6;
  if ((threadIdx.x & 63) == 0) { rs[wid] = s; rss[wid] = ss; }
  __syncthreads();
  if (threadIdx.x == 0) {
    float S1 = rs[0] + rs[1] + rs[2] + rs[3];
    float S2 = rss[0] + rss[1] + rss[2] + rss[3];
    float mu = S1 / DMODEL;
    mu_s = mu;
    inv_s = rsqrtf(S2 / DMODEL - mu * mu + 1e-5f);
  }
  __syncthreads();
  float mu = mu_s, inv = inv_s;
  int rt = row >> 7, rl = row & 127;
  int sw = (rl ^ (rl >> 2)) & 3;
  for (int c = threadIdx.x; c < DMODEL; c += 256) {
    float v = (xr[c] - mu) * inv * w[c];
    unsigned short hh, ll;
    split2(v, hh, ll);
    if (mode) {
      size_t off = ((size_t)(rt * 64 + (c >> 5))) * 4096 + rl * 32 +
                   ((((c & 31) >> 3) ^ sw) << 3) + (c & 7);
      obh[off] = hh;
      obl[off] = ll;
    } else {
      obh[(size_t)row * DMODEL + c] = hh;
      if (obl) obl[(size_t)row * DMODEL + c] = ll;
      if (of) of[(size_t)row * DMODEL + c] = v;
    }
  }
}

// RoPE: Q row-major (split), K directly in chunk layout (split)
__global__ void k_rope2(const float* __restrict__ qkv, unsigned short* __restrict__ qh,
                        unsigned short* __restrict__ ql, unsigned short* __restrict__ kPh,
                        unsigned short* __restrict__ kPl) {
  int t = blockIdx.x;
  int d = threadIdx.x;  // 0..63
  float pf = (float)pow(500000.0, (double)d * (1.0 / 64.0));
  float invf = 1.0f / pf;
  float ang = (float)t * invf;
  float cs = (float)cos((double)ang);
  float sn = (float)sin((double)ang);
  const float* row = qkv + (size_t)t * QKV_N;
  unsigned short hh, ll;
#pragma unroll
  for (int hq = 0; hq < NH; hq++) {
    float a = row[hq * HD + d], b = row[hq * HD + d + 64];
    size_t base = ((size_t)hq * S_LEN + t) * HD;
    split2(a * cs - b * sn, hh, ll); qh[base + d] = hh; ql[base + d] = ll;
    split2(b * cs + a * sn, hh, ll); qh[base + d + 64] = hh; ql[base + d + 64] = ll;
  }
  int tt2 = t >> 7, rl2 = t & 127;
  int s2 = (rl2 ^ (rl2 >> 2)) & 3;
#pragma unroll
  for (int kv = 0; kv < NKV; kv++) {
    float a = row[NH * HD + kv * HD + d], b = row[NH * HD + kv * HD + d + 64];
    float o0 = a * cs - b * sn;
    float o1 = b * cs + a * sn;
#pragma unroll
    for (int half = 0; half < 2; half++) {
      int col = d + half * 64;
      float v = half ? o1 : o0;
      size_t off = ((size_t)(kv * 64 + tt2 * 4 + (col >> 5))) * 4096 + rl2 * 32 +
                   ((((col & 31) >> 3) ^ s2) << 3) + (col & 7);
      split2(v, hh, ll);
      kPh[off] = hh;
      kPl[off] = ll;
    }
  }
}

__global__ __launch_bounds__(256) void k_router(const float* __restrict__ h2,
                                                const float* __restrict__ rw,
                                                int* __restrict__ topi,
                                                float* __restrict__ topw,
                                                int* __restrict__ cnt) {
  int t = blockIdx.x;
  __shared__ float hs[DMODEL];
  __shared__ float lg[NE];
  for (int c = threadIdx.x; c < DMODEL; c += 256) hs[c] = h2[(size_t)t * DMODEL + c];
  __syncthreads();
  int grp = threadIdx.x >> 5;
  int ln = threadIdx.x & 31;
  float p = 0.f;
  for (int c = ln; c < DMODEL; c += 32) p += hs[c] * rw[(size_t)grp * DMODEL + c];
#pragma unroll
  for (int o = 16; o; o >>= 1) p += __shfl_down(p, o, 32);
  if (ln == 0) lg[grp] = p;
  __syncthreads();
  if (threadIdx.x == 0) {
    float l0 = -3.4e38f; int i0 = 0;
    for (int e = 0; e < NE; e++)
      if (lg[e] > l0) { l0 = lg[e]; i0 = e; }
    float l1 = -3.4e38f; int i1 = 0;
    for (int e = 0; e < NE; e++)
      if (e != i0 && lg[e] > l1) { l1 = lg[e]; i1 = e; }
    float z = expf(l1 - l0);
    topi[t * 2] = i0; topi[t * 2 + 1] = i1;
    topw[t * 2] = 1.f / (1.f + z); topw[t * 2 + 1] = z / (1.f + z);
    atomicAdd(&cnt[i0], 1);
    atomicAdd(&cnt[i1], 1);
  }
}

__global__ void k_scan(int* __restrict__ meta) {
  if (threadIdx.x == 0 && blockIdx.x == 0) {
    int o = 0, nt = 0;
    for (int e = 0; e < NE; e++) {
      meta[16 + e] = o;
      for (int m0 = 0; m0 < meta[e]; m0 += 128) meta[26 + nt++] = (m0 << 3) | e;
      o += meta[e];
    }
    meta[24] = o;
    meta[25] = nt;
  }
}

__global__ void k_fill(const int* __restrict__ topi, const float* __restrict__ topw,
                       int* __restrict__ meta, int* __restrict__ ptok,
                       float* __restrict__ pw) {
  int t = blockIdx.x * blockDim.x + threadIdx.x;
  if (t >= S_LEN) return;
#pragma unroll
  for (int j = 0; j < 2; j++) {
    int e = topi[t * 2 + j];
    int p = atomicAdd(&meta[8 + e], 1);
    ptok[meta[16 + e] + p] = t;
    pw[meta[16 + e] + p] = topw[t * 2 + j];
  }
}

// ---------------- launch ----------------

extern "C" void kernel_launch(void* const* d_in, const int* in_sizes, int n_in,
                              void* d_out, int out_size, void* d_ws, size_t ws_size,
                              hipStream_t stream) {
  (void)in_sizes; (void)n_in; (void)out_size; (void)ws_size;
  const float* x = (const float*)d_in[0];
  const float* ln1w = (const float*)d_in[2];
  const float* ln2w = (const float*)d_in[3];
  const float* wqkv = (const float*)d_in[4];
  const float* wo = (const float*)d_in[5];
  const float* rw = (const float*)d_in[6];
  const float* w1 = (const float*)d_in[7];
  const float* v1 = (const float*)d_in[8];
  const float* w2 = (const float*)d_in[9];
  float* out = (float*)d_out;  // x1 after k_wo_s; MoE adds in place

  char* wsb = (char*)d_ws;
  const size_t MiB = 1u << 20;
  // ---- attention phase ----
  unsigned short* h1Ph = (unsigned short*)(wsb + 0 * MiB);     // 8 (chunks)
  unsigned short* h1Pl = (unsigned short*)(wsb + 8 * MiB);     // 8
  float* qkvb = (float*)(wsb + 16 * MiB);                      // 24
  unsigned short* qh = (unsigned short*)(wsb + 40 * MiB);      // 8
  unsigned short* ql = (unsigned short*)(wsb + 48 * MiB);      // 8
  unsigned short* vPh = (unsigned short*)(wsb + 60 * MiB);     // 2
  unsigned short* vPl = (unsigned short*)(wsb + 62 * MiB);     // 2
  unsigned short* kPh = (unsigned short*)(wsb + 64 * MiB);     // 2
  unsigned short* kPl = (unsigned short*)(wsb + 66 * MiB);     // 2
  unsigned short* atPh = (unsigned short*)(wsb + 68 * MiB);    // 8 (chunks)
  unsigned short* atPl = (unsigned short*)(wsb + 76 * MiB);    // 8
  unsigned short* wqkvPh = (unsigned short*)(wsb + 84 * MiB);  // 12
  unsigned short* wqkvPl = (unsigned short*)(wsb + 96 * MiB);  // 12
  unsigned short* woPh = (unsigned short*)(wsb + 108 * MiB);   // 8
  unsigned short* woPl = (unsigned short*)(wsb + 116 * MiB);   // 8
  // ---- MoE phase (overlays; attention buffers dead) ----
  unsigned short* h2b = (unsigned short*)(wsb + 0 * MiB);      // 8 (over h1Ph)
  unsigned short* g = (unsigned short*)(wsb + 16 * MiB);       // 20 (over qkvb)
  float* h2f = (float*)(wsb + 40 * MiB);                       // 16 (over qh/ql)
  unsigned short* wPa = (unsigned short*)(wsb + 40 * MiB);     // 64 (after router)
  unsigned short* wPb = (unsigned short*)(wsb + 104 * MiB);    // 64
  char* small = wsb + 168 * MiB;
  int* topi = (int*)small;
  float* topw = (float*)(small + 16384);
  int* ptok = (int*)(small + 32768);
  float* pw = (float*)(small + 49152);
  int* meta = (int*)(small + 65536);  // 128 ints

  // ---- pack attention weights ----
  k_pack2<<<dim3(QKV_N / 128, 16, 1), 256, 0, stream>>>(wqkv, QKV_N, 0, QKV_N / 128,
                                                        wqkvPh, wqkvPl);
  k_pack2<<<dim3(DMODEL / 128, 16, 1), 256, 0, stream>>>(wo, DMODEL, 0, DMODEL / 128,
                                                         woPh, woPl);

  // ---- attention sublayer (fp32-emulated) ----
  k_ln<<<S_LEN, 256, 0, stream>>>(x, ln1w, h1Ph, h1Pl, (float*)nullptr, 1);
  k_qkv_s<<<dim3(QKV_N / 128, S_LEN / 128), 256, 0, stream>>>(h1Ph, h1Pl, wqkvPh, wqkvPl,
                                                              qkvb);
  k_rope2<<<S_LEN, 64, 0, stream>>>(qkvb, qh, ql, kPh, kPl);
  k_pack2<<<dim3(1, 16, NKV), 256, 0, stream>>>(qkvb + (NH + NKV) * HD, QKV_N, HD, 1,
                                                vPh, vPl);
  k_flash<<<512, 128, 0, stream>>>(qh, ql, kPh, kPl, vPh, vPl, atPh, atPl);
  k_wo_s<<<dim3(16, 16), 256, 0, stream>>>(atPh, atPl, woPh, woPl, x, out);

  // ---- MoE sublayer ----
  k_ln<<<S_LEN, 256, 0, stream>>>(out, ln2w, h2b, (unsigned short*)nullptr, h2f, 0);
  hipMemsetAsync(meta, 0, 512, stream);
  k_router<<<S_LEN, 256, 0, stream>>>(h2f, rw, topi, topw, meta);
  k_scan<<<1, 64, 0, stream>>>(meta);
  k_fill<<<8, 256, 0, stream>>>(topi, topw, meta, ptok, pw);
  k_pack1<<<dim3(16, 16, NE), 256, 0, stream>>>(w1, FF, (long)DMODEL * FF, 16, wPa);
  k_pack1<<<dim3(16, 16, NE), 256, 0, stream>>>(v1, FF, (long)DMODEL * FF, 16, wPb);
  k_moe1f<<<dim3(16, 40), 512, 0, stream>>>(h2b, ptok, wPa, wPb, meta, g);
  k_pack1<<<dim3(16, 16, NE), 256, 0, stream>>>(w2, DMODEL, (long)FF * DMODEL, 16, wPa);
  k_moe2<<<dim3(16, 40, 2), 256, 0, stream>>>(g, wPa, ptok, pw, meta, out);
}